// Round 10
// baseline (194.343 us; speedup 1.0000x reference)
//
#include <hip/hip_runtime.h>

// B=2, S=2048, E=1024, HEADS=16, HEAD_SIZE=64
// out = softmax((q Wq^T + bq)(k Wk^T + bk)^T / 32) (v Wv^T + bv) Wo^T + bo

typedef unsigned short u16;
typedef __bf16 bf16x8 __attribute__((ext_vector_type(8)));
typedef float f32x4 __attribute__((ext_vector_type(4)));
typedef u16 u16x4 __attribute__((ext_vector_type(4)));

typedef __attribute__((address_space(1))) const unsigned int as1_cu32;
typedef __attribute__((address_space(3))) unsigned int as3_u32;

__device__ __forceinline__ u16 f2bf(float f) {
  unsigned u = __builtin_bit_cast(unsigned, f);
  u += 0x7fffu + ((u >> 16) & 1u);   // RTNE
  return (u16)(u >> 16);
}

__device__ __forceinline__ void gl_lds16(const u16* g, u16* l) {
  // async global->LDS, 16B/lane; LDS dest = wave-uniform base + lane*16
  __builtin_amdgcn_global_load_lds((as1_cu32*)g, (as3_u32*)l, 16, 0, 0);
}

// ---------------- fp32 -> bf16 cast (q,k,v + 4 weights) ----------------
__global__ void cast_kernel(const float* __restrict__ q, const float* __restrict__ k,
                            const float* __restrict__ v, const float* __restrict__ wq,
                            const float* __restrict__ wk, const float* __restrict__ wv,
                            const float* __restrict__ wo,
                            u16* __restrict__ qb, u16* __restrict__ kb, u16* __restrict__ vb,
                            u16* __restrict__ wqb, u16* __restrict__ wkb, u16* __restrict__ wvb,
                            u16* __restrict__ wob) {
  unsigned t = blockIdx.x * 256u + threadIdx.x;  // one float4 (4 elems) per thread
  const float* src; u16* dst; unsigned off;
  if (t < 3u * 1048576u) {            // q,k,v: 4M elems = 1M float4 each
    unsigned which = t >> 20;
    off = t & 1048575u;
    src = which == 0 ? q : (which == 1 ? k : v);
    dst = which == 0 ? qb : (which == 1 ? kb : vb);
  } else {                            // weights: 1M elems = 256K float4 each
    unsigned tw = t - 3u * 1048576u;
    unsigned which = tw >> 18;
    off = tw & 262143u;
    src = which == 0 ? wq : (which == 1 ? wk : (which == 2 ? wv : wo));
    dst = which == 0 ? wqb : (which == 1 ? wkb : (which == 2 ? wvb : wob));
  }
  float4 f = ((const float4*)src)[off];
  u16x4 o;
  o[0] = f2bf(f.x); o[1] = f2bf(f.y); o[2] = f2bf(f.z); o[3] = f2bf(f.w);
  ((u16x4*)dst)[off] = o;
}

// ---------------- NT GEMM: C = scale*(A B^T + bias) ----------------
// M=4096, N=1024, K=1024; 128x128 tile, BK=32, 4 waves 2x2, 16x16x32 MFMA, dbuf LDS.
// MODE: 0 = bf16 row-major out, 1 = f32 row-major out, 2 = bf16 V^T out [b,h,d,s]
__device__ __forceinline__ void gemm_stage(const u16* A, const u16* B,
                                           u16 (&As)[128][32], u16 (&Bs)[128][32],
                                           int m0, int n0, int kt, int w, int l) {
#pragma unroll
  for (int i = 0; i < 2; ++i) {
    int r0 = i * 64 + w * 16;
    gl_lds16(A + (size_t)(m0 + r0 + (l >> 2)) * 1024 + kt * 32 + (l & 3) * 8, &As[r0][0]);
    gl_lds16(B + (size_t)(n0 + r0 + (l >> 2)) * 1024 + kt * 32 + (l & 3) * 8, &Bs[r0][0]);
  }
}

template <int MODE>
__device__ __forceinline__ void gemm_body(const u16* __restrict__ A, const u16* __restrict__ B,
                                          const float* __restrict__ bias, void* __restrict__ Cv,
                                          float scale,
                                          u16 (&As)[2][128][32], u16 (&Bs)[2][128][32]) {
  constexpr int N = 1024, NK = 32;
  const int m0 = blockIdx.x * 128;
  const int n0 = blockIdx.y * 128;
  const int tid = threadIdx.x;
  const int w = tid >> 6, l = tid & 63;
  const int lr = l & 15, lg = l >> 4;
  const int wm = (w >> 1) * 64, wn = (w & 1) * 64;

  f32x4 acc[4][4];
#pragma unroll
  for (int i = 0; i < 4; ++i)
#pragma unroll
    for (int j = 0; j < 4; ++j) acc[i][j] = f32x4{0.f, 0.f, 0.f, 0.f};

  gemm_stage(A, B, As[0], Bs[0], m0, n0, 0, w, l);

  for (int kt = 0; kt < NK; ++kt) {
    const int buf = kt & 1;
    __syncthreads();
    if (kt + 1 < NK) gemm_stage(A, B, As[buf ^ 1], Bs[buf ^ 1], m0, n0, kt + 1, w, l);
    bf16x8 af[4], bfr[4];
#pragma unroll
    for (int i = 0; i < 4; ++i) {
      af[i]  = *(const bf16x8*)&As[buf][wm + i * 16 + lr][lg * 8];
      bfr[i] = *(const bf16x8*)&Bs[buf][wn + i * 16 + lr][lg * 8];
    }
#pragma unroll
    for (int mi = 0; mi < 4; ++mi)
#pragma unroll
      for (int ni = 0; ni < 4; ++ni)
        acc[mi][ni] = __builtin_amdgcn_mfma_f32_16x16x32_bf16(af[mi], bfr[ni], acc[mi][ni], 0, 0, 0);
  }

  float bv[4];
#pragma unroll
  for (int ni = 0; ni < 4; ++ni) bv[ni] = bias[n0 + wn + ni * 16 + lr];
#pragma unroll
  for (int mi = 0; mi < 4; ++mi)
#pragma unroll
    for (int ni = 0; ni < 4; ++ni)
#pragma unroll
      for (int r = 0; r < 4; ++r) {
        const int row = m0 + wm + mi * 16 + lg * 4 + r;
        const int col = n0 + wn + ni * 16 + lr;
        float vv = (acc[mi][ni][r] + bv[ni]) * scale;
        if constexpr (MODE == 1) {
          ((float*)Cv)[(size_t)row * N + col] = vv;
        } else if constexpr (MODE == 0) {
          ((u16*)Cv)[(size_t)row * N + col] = f2bf(vv);
        } else {  // V^T: [b][h*64+d][s]
          ((u16*)Cv)[((size_t)((row >> 11) << 10) + col) * 2048 + (row & 2047)] = f2bf(vv);
        }
      }
}

__global__ __launch_bounds__(256, 2)
void proj_kernel(const u16* __restrict__ qb, const u16* __restrict__ kb, const u16* __restrict__ vb,
                 const u16* __restrict__ wqb, const u16* __restrict__ wkb, const u16* __restrict__ wvb,
                 const float* __restrict__ bq, const float* __restrict__ bk, const float* __restrict__ bvv,
                 u16* __restrict__ qh, u16* __restrict__ kh, u16* __restrict__ vt) {
  __shared__ __align__(16) u16 As[2][128][32];
  __shared__ __align__(16) u16 Bs[2][128][32];
  // Q gets scale log2(e)/32 so attention scores feed exp2 directly
  if (blockIdx.z == 0)      gemm_body<0>(qb, wqb, bq, qh, 1.44269504089f / 32.f, As, Bs);
  else if (blockIdx.z == 1) gemm_body<0>(kb, wkb, bk, kh, 1.0f, As, Bs);
  else                      gemm_body<2>(vb, wvb, bvv, vt, 1.0f, As, Bs);
}

__global__ __launch_bounds__(256, 2)
void outproj_kernel(const u16* __restrict__ attnb, const u16* __restrict__ wob,
                    const float* __restrict__ bo, float* __restrict__ out) {
  __shared__ __align__(16) u16 As[2][128][32];
  __shared__ __align__(16) u16 Bs[2][128][32];
  gemm_body<1>(attnb, wob, bo, out, 1.0f, As, Bs);
}

// ---------------- flash attention: barrier-free, global-direct K/V -----------
// grid (32 bh, 16 qt). 4 waves, wave w: 32 q-rows (2 qh halves). NO LDS staging
// for K/V: the B-fragment patterns are, per (nf,half) pair, 16 rows x 64B
// contiguous -> the half-pair covers full 128B lines (100% line efficiency).
// K/V are L2-resident (512KB/bh; co-resident blocks share bh -> L1 reuse).
// Zero __syncthreads: waves fully independent; only the wave-private P
// round-trip uses LDS (round-4/9 measured-zero-conflict mappings).
__global__ __launch_bounds__(256, 2)
void attn_kernel(const u16* __restrict__ Q, const u16* __restrict__ Kh,
                 const u16* __restrict__ Vt, u16* __restrict__ Ao) {
  constexpr int E = 1024, S = 2048, NT = S / 64;
  const int bh = blockIdx.x, qt = blockIdx.y;
  const int b = bh >> 4, h = bh & 15;
  const int tid = threadIdx.x, w = tid >> 6, l = tid & 63;
  const int lr = l & 15, lg = l >> 4;

  // LDS: only P tiles, [4 w][2 qh][16 q][64 k] bf16 (128 B rows)
  __shared__ __align__(16) char SM[16384];

  const u16* Qp = Q + (size_t)b * S * E + (size_t)h * 64;
  const u16* Kp = Kh + (size_t)b * S * E + (size_t)h * 64;
  const u16* Vp = Vt + (size_t)bh * 64 * S;   // [d][s]

  const int qbase = qt * 128 + w * 32;
  bf16x8 qa[2][2];
#pragma unroll
  for (int qh = 0; qh < 2; ++qh)
#pragma unroll
    for (int hh = 0; hh < 2; ++hh)
      qa[qh][hh] = *(const bf16x8*)(Qp + (size_t)(qbase + qh * 16 + lr) * E + hh * 32 + lg * 8);

  bf16x8 ones;
#pragma unroll
  for (int j = 0; j < 8; ++j) ones[j] = (__bf16)1.0f;

  f32x4 o_acc[2][4];      // [qh][nf]
#pragma unroll
  for (int qh = 0; qh < 2; ++qh)
#pragma unroll
    for (int nf = 0; nf < 4; ++nf) o_acc[qh][nf] = f32x4{0.f, 0.f, 0.f, 0.f};
  f32x4 sum_acc[2] = {f32x4{0.f, 0.f, 0.f, 0.f}, f32x4{0.f, 0.f, 0.f, 0.f}};

  // ---- P-tile LDS byte offsets (round-9 zero-conflict patterns) ----
  const int swz8 = lr & 7;
  const int ptb = w * 4096;                       // per-wave 4KB (2 qh halves)
  const int xrb = (lg & 1) * 4;                   // writer key = xrb + r
  const int cbase = lr >> 3;                      // logical chunk = nf*2 + cbase
  int pwb[4];                                     // + qh*2048 + chunk<<4
#pragma unroll
  for (int r = 0; r < 4; ++r) pwb[r] = ptb + (lg * 4 + r) * 128 + (lr & 7) * 2;
  const int prd0 = ptb + lr * 128 + ((lg ^ swz8) << 4);          // + qh*2048
  const int prd1 = ptb + lr * 128 + (((4 + lg) ^ swz8) << 4);

  // ---- global fragment element-offsets (u32), advanced per iteration ----
  unsigned ko[4], vo[4];
#pragma unroll
  for (int nf = 0; nf < 4; ++nf) {
    ko[nf] = (unsigned)((nf * 16 + lr) * 1024 + lg * 8);   // K[k][e], +65536/iter
    vo[nf] = (unsigned)((nf * 16 + lr) * 2048 + lg * 8);   // V^T[d][k], +64/iter
  }

  for (int t = 0; t < NT; ++t) {
    // issue K then V fragment loads (compiler emits counted vmcnt: QK waits on
    // K only; V stays in flight until PV ~600cy later)
    bf16x8 kf[4][2], vf[4][2];
#pragma unroll
    for (int nf = 0; nf < 4; ++nf) {
      kf[nf][0] = *(const bf16x8*)(Kp + ko[nf]);
      kf[nf][1] = *(const bf16x8*)(Kp + ko[nf] + 32);
    }
#pragma unroll
    for (int nf = 0; nf < 4; ++nf) {
      vf[nf][0] = *(const bf16x8*)(Vp + vo[nf]);
      vf[nf][1] = *(const bf16x8*)(Vp + vo[nf] + 32);
    }

    // QK^T: each K fragment pair feeds both qh halves
    f32x4 sfr[2][4];
    __builtin_amdgcn_s_setprio(1);
#pragma unroll
    for (int nf = 0; nf < 4; ++nf)
#pragma unroll
      for (int qh = 0; qh < 2; ++qh) {
        f32x4 z = f32x4{0.f, 0.f, 0.f, 0.f};
        z = __builtin_amdgcn_mfma_f32_16x16x32_bf16(qa[qh][0], kf[nf][0], z, 0, 0, 0);
        sfr[qh][nf] = __builtin_amdgcn_mfma_f32_16x16x32_bf16(qa[qh][1], kf[nf][1], z, 0, 0, 0);
      }
    __builtin_amdgcn_s_setprio(0);

    // P = exp2(s): scattered b16 writes (zero-conflict pattern), per qh
#pragma unroll
    for (int qh = 0; qh < 2; ++qh)
#pragma unroll
      for (int nf = 0; nf < 4; ++nf)
#pragma unroll
        for (int r = 0; r < 4; ++r) {
          __bf16 pb = (__bf16)exp2f(sfr[qh][nf][r]);
          *(u16*)(SM + pwb[r] + qh * 2048 + (((nf * 2 + cbase) ^ (xrb + r)) << 4)) =
              __builtin_bit_cast(u16, pb);
        }

    // P fragments (wave-private RAW through LDS) + denominators via ones-MFMA
    bf16x8 pa[2][2];
#pragma unroll
    for (int qh = 0; qh < 2; ++qh) {
      pa[qh][0] = *(const bf16x8*)(SM + prd0 + qh * 2048);
      pa[qh][1] = *(const bf16x8*)(SM + prd1 + qh * 2048);
      sum_acc[qh] = __builtin_amdgcn_mfma_f32_16x16x32_bf16(pa[qh][0], ones, sum_acc[qh], 0, 0, 0);
      sum_acc[qh] = __builtin_amdgcn_mfma_f32_16x16x32_bf16(pa[qh][1], ones, sum_acc[qh], 0, 0, 0);
    }

    // PV: each V fragment pair feeds both qh halves
    __builtin_amdgcn_s_setprio(1);
#pragma unroll
    for (int nf = 0; nf < 4; ++nf)
#pragma unroll
      for (int qh = 0; qh < 2; ++qh) {
        o_acc[qh][nf] = __builtin_amdgcn_mfma_f32_16x16x32_bf16(pa[qh][0], vf[nf][0], o_acc[qh][nf], 0, 0, 0);
        o_acc[qh][nf] = __builtin_amdgcn_mfma_f32_16x16x32_bf16(pa[qh][1], vf[nf][1], o_acc[qh][nf], 0, 0, 0);
      }
    __builtin_amdgcn_s_setprio(0);

#pragma unroll
    for (int nf = 0; nf < 4; ++nf) { ko[nf] += 64 * 1024; vo[nf] += 64; }
  }

#pragma unroll
  for (int qh = 0; qh < 2; ++qh)
#pragma unroll
    for (int r = 0; r < 4; ++r) {
      const float inv = 1.0f / sum_acc[qh][r];
      const size_t row = (size_t)b * S + qbase + qh * 16 + lg * 4 + r;
#pragma unroll
      for (int nf = 0; nf < 4; ++nf)
        Ao[row * E + h * 64 + nf * 16 + lr] = f2bf(o_acc[qh][nf][r] * inv);
    }
}

// ---------------- launch ----------------
extern "C" void kernel_launch(void* const* d_in, const int* in_sizes, int n_in,
                              void* d_out, int out_size, void* d_ws, size_t ws_size,
                              hipStream_t stream) {
  const float* q  = (const float*)d_in[0];
  const float* k  = (const float*)d_in[1];
  const float* v  = (const float*)d_in[2];
  const float* Wq = (const float*)d_in[3];
  const float* bq = (const float*)d_in[4];
  const float* Wk = (const float*)d_in[5];
  const float* bk = (const float*)d_in[6];
  const float* Wv = (const float*)d_in[7];
  const float* bv = (const float*)d_in[8];
  const float* Wo = (const float*)d_in[9];
  const float* bo = (const float*)d_in[10];
  float* out = (float*)d_out;

  char* ws = (char*)d_ws;
  u16* qb  = (u16*)(ws);                       // 4M elems, 8MB
  u16* kb  = (u16*)(ws + (8u << 20));
  u16* vb  = (u16*)(ws + (16u << 20));
  u16* wqb = (u16*)(ws + (24u << 20));         // 1M elems, 2MB each
  u16* wkb = (u16*)(ws + (26u << 20));
  u16* wvb = (u16*)(ws + (28u << 20));
  u16* wob = (u16*)(ws + (30u << 20));
  u16* qhp = (u16*)(ws + (32u << 20));         // 8MB each
  u16* khp = (u16*)(ws + (40u << 20));
  u16* vtp = (u16*)(ws + (48u << 20));         // V^T [b,h,d,s]
  u16* attnb = qb;  // reuse: qb dead after projections

  cast_kernel<<<dim3(16384), dim3(256), 0, stream>>>(q, k, v, Wq, Wk, Wv, Wo,
                                                     qb, kb, vb, wqb, wkb, wvb, wob);
  proj_kernel<<<dim3(32, 8, 3), dim3(256), 0, stream>>>(qb, kb, vb, wqb, wkb, wvb,
                                                        bq, bk, bv, qhp, khp, vtp);
  attn_kernel<<<dim3(32, 16), dim3(256), 0, stream>>>(qhp, khp, vtp, attnb);
  outproj_kernel<<<dim3(32, 8), dim3(256), 0, stream>>>(attnb, wob, bo, out);
}

// Round 11
// 140.492 us; speedup vs baseline: 1.3833x; 1.3833x over previous
//
#include <hip/hip_runtime.h>

// B=2, S=2048, E=1024, HEADS=16, HEAD_SIZE=64
// out = softmax((q Wq^T + bq)(k Wk^T + bk)^T / 32) (v Wv^T + bv) Wo^T + bo

typedef unsigned short u16;
typedef __bf16 bf16x8 __attribute__((ext_vector_type(8)));
typedef float f32x4 __attribute__((ext_vector_type(4)));
typedef u16 u16x4 __attribute__((ext_vector_type(4)));

typedef __attribute__((address_space(1))) const unsigned int as1_cu32;
typedef __attribute__((address_space(3))) unsigned int as3_u32;

__device__ __forceinline__ u16 f2bf(float f) {
  unsigned u = __builtin_bit_cast(unsigned, f);
  u += 0x7fffu + ((u >> 16) & 1u);   // RTNE
  return (u16)(u >> 16);
}

__device__ __forceinline__ void gl_lds16(const u16* g, u16* l) {
  // async global->LDS, 16B/lane; LDS dest = wave-uniform base + lane*16
  __builtin_amdgcn_global_load_lds((as1_cu32*)g, (as3_u32*)l, 16, 0, 0);
}

// ---------------- fp32 -> bf16 cast (q,k,v + 4 weights) ----------------
__global__ void cast_kernel(const float* __restrict__ q, const float* __restrict__ k,
                            const float* __restrict__ v, const float* __restrict__ wq,
                            const float* __restrict__ wk, const float* __restrict__ wv,
                            const float* __restrict__ wo,
                            u16* __restrict__ qb, u16* __restrict__ kb, u16* __restrict__ vb,
                            u16* __restrict__ wqb, u16* __restrict__ wkb, u16* __restrict__ wvb,
                            u16* __restrict__ wob) {
  unsigned t = blockIdx.x * 256u + threadIdx.x;  // one float4 (4 elems) per thread
  const float* src; u16* dst; unsigned off;
  if (t < 3u * 1048576u) {            // q,k,v: 4M elems = 1M float4 each
    unsigned which = t >> 20;
    off = t & 1048575u;
    src = which == 0 ? q : (which == 1 ? k : v);
    dst = which == 0 ? qb : (which == 1 ? kb : vb);
  } else {                            // weights: 1M elems = 256K float4 each
    unsigned tw = t - 3u * 1048576u;
    unsigned which = tw >> 18;
    off = tw & 262143u;
    src = which == 0 ? wq : (which == 1 ? wk : (which == 2 ? wv : wo));
    dst = which == 0 ? wqb : (which == 1 ? wkb : (which == 2 ? wvb : wob));
  }
  float4 f = ((const float4*)src)[off];
  u16x4 o;
  o[0] = f2bf(f.x); o[1] = f2bf(f.y); o[2] = f2bf(f.z); o[3] = f2bf(f.w);
  ((u16x4*)dst)[off] = o;
}

// ---------------- NT GEMM: C = scale*(A B^T + bias) ----------------
// M=4096, N=1024, K=1024; 128x128 tile, BK=32, 4 waves 2x2, 16x16x32 MFMA, dbuf LDS.
// MODE: 0 = bf16 row-major out, 1 = f32 row-major out, 2 = bf16 V^T out [b,h,d,s]
__device__ __forceinline__ void gemm_stage(const u16* A, const u16* B,
                                           u16 (&As)[128][32], u16 (&Bs)[128][32],
                                           int m0, int n0, int kt, int w, int l) {
#pragma unroll
  for (int i = 0; i < 2; ++i) {
    int r0 = i * 64 + w * 16;
    gl_lds16(A + (size_t)(m0 + r0 + (l >> 2)) * 1024 + kt * 32 + (l & 3) * 8, &As[r0][0]);
    gl_lds16(B + (size_t)(n0 + r0 + (l >> 2)) * 1024 + kt * 32 + (l & 3) * 8, &Bs[r0][0]);
  }
}

template <int MODE>
__device__ __forceinline__ void gemm_body(const u16* __restrict__ A, const u16* __restrict__ B,
                                          const float* __restrict__ bias, void* __restrict__ Cv,
                                          float scale,
                                          u16 (&As)[2][128][32], u16 (&Bs)[2][128][32]) {
  constexpr int N = 1024, NK = 32;
  const int m0 = blockIdx.x * 128;
  const int n0 = blockIdx.y * 128;
  const int tid = threadIdx.x;
  const int w = tid >> 6, l = tid & 63;
  const int lr = l & 15, lg = l >> 4;
  const int wm = (w >> 1) * 64, wn = (w & 1) * 64;

  f32x4 acc[4][4];
#pragma unroll
  for (int i = 0; i < 4; ++i)
#pragma unroll
    for (int j = 0; j < 4; ++j) acc[i][j] = f32x4{0.f, 0.f, 0.f, 0.f};

  gemm_stage(A, B, As[0], Bs[0], m0, n0, 0, w, l);

  for (int kt = 0; kt < NK; ++kt) {
    const int buf = kt & 1;
    __syncthreads();
    if (kt + 1 < NK) gemm_stage(A, B, As[buf ^ 1], Bs[buf ^ 1], m0, n0, kt + 1, w, l);
    bf16x8 af[4], bfr[4];
#pragma unroll
    for (int i = 0; i < 4; ++i) {
      af[i]  = *(const bf16x8*)&As[buf][wm + i * 16 + lr][lg * 8];
      bfr[i] = *(const bf16x8*)&Bs[buf][wn + i * 16 + lr][lg * 8];
    }
#pragma unroll
    for (int mi = 0; mi < 4; ++mi)
#pragma unroll
      for (int ni = 0; ni < 4; ++ni)
        acc[mi][ni] = __builtin_amdgcn_mfma_f32_16x16x32_bf16(af[mi], bfr[ni], acc[mi][ni], 0, 0, 0);
  }

  float bv[4];
#pragma unroll
  for (int ni = 0; ni < 4; ++ni) bv[ni] = bias[n0 + wn + ni * 16 + lr];
#pragma unroll
  for (int mi = 0; mi < 4; ++mi)
#pragma unroll
    for (int ni = 0; ni < 4; ++ni)
#pragma unroll
      for (int r = 0; r < 4; ++r) {
        const int row = m0 + wm + mi * 16 + lg * 4 + r;
        const int col = n0 + wn + ni * 16 + lr;
        float vv = (acc[mi][ni][r] + bv[ni]) * scale;
        if constexpr (MODE == 1) {
          ((float*)Cv)[(size_t)row * N + col] = vv;
        } else if constexpr (MODE == 0) {
          ((u16*)Cv)[(size_t)row * N + col] = f2bf(vv);
        } else {  // V^T: [b][h*64+d][s]
          ((u16*)Cv)[((size_t)((row >> 11) << 10) + col) * 2048 + (row & 2047)] = f2bf(vv);
        }
      }
}

__global__ __launch_bounds__(256, 2)
void proj_kernel(const u16* __restrict__ qb, const u16* __restrict__ kb, const u16* __restrict__ vb,
                 const u16* __restrict__ wqb, const u16* __restrict__ wkb, const u16* __restrict__ wvb,
                 const float* __restrict__ bq, const float* __restrict__ bk, const float* __restrict__ bvv,
                 u16* __restrict__ qh, u16* __restrict__ kh, u16* __restrict__ vt) {
  __shared__ __align__(16) u16 As[2][128][32];
  __shared__ __align__(16) u16 Bs[2][128][32];
  // Q gets scale log2(e)/32 so attention scores feed exp2 directly
  if (blockIdx.z == 0)      gemm_body<0>(qb, wqb, bq, qh, 1.44269504089f / 32.f, As, Bs);
  else if (blockIdx.z == 1) gemm_body<0>(kb, wkb, bk, kh, 1.0f, As, Bs);
  else                      gemm_body<2>(vb, wvb, bvv, vt, 1.0f, As, Bs);
}

__global__ __launch_bounds__(256, 2)
void outproj_kernel(const u16* __restrict__ attnb, const u16* __restrict__ wob,
                    const float* __restrict__ bo, float* __restrict__ out) {
  __shared__ __align__(16) u16 As[2][128][32];
  __shared__ __align__(16) u16 Bs[2][128][32];
  gemm_body<1>(attnb, wob, bo, out, 1.0f, As, Bs);
}

// ---------------- flash attention: 32 q/wave + K-2-ahead pipeline ------------
// grid (32 bh, 16 qt). 4 waves, wave w owns 32 q-rows (2 qh halves); each K/V
// fragment read feeds both halves (round-9 skeleton, measured 70us / 0 confl).
// NEW: K staged TWO tiles ahead (round-4's verified barrier scheme) so QK(t+1)
// sits between softmax(t) and PV(t) -> every wave interleaves MFMA and
// VALU/TRANS phases instead of block-lockstep phase convoys.
__global__ __launch_bounds__(256, 2)
void attn_kernel(const u16* __restrict__ Q, const u16* __restrict__ Kh,
                 const u16* __restrict__ Vt, u16* __restrict__ Ao) {
  constexpr int E = 1024, S = 2048, NT = S / 64;
  const int bh = blockIdx.x, qt = blockIdx.y;
  const int b = bh >> 4, h = bh & 15;
  const int tid = threadIdx.x, w = tid >> 6, l = tid & 63;
  const int lr = l & 15, lg = l >> 4;

  // LDS arena: [0,16K) Ks[2][64][64]  [16K,32K) Vs[2][64][64]
  //            [32K,48K) PT[4 w][2 qh][16 q][64 k] bf16 (128 B rows)
  __shared__ __align__(16) char SM[49152];

  const u16* Qp = Q + (size_t)b * S * E + (size_t)h * 64;
  const u16* Kp = Kh + (size_t)b * S * E + (size_t)h * 64;
  const u16* Vp = Vt + (size_t)bh * 64 * S;   // [d][s]

  const int qbase = qt * 128 + w * 32;
  bf16x8 qa[2][2];
#pragma unroll
  for (int qh = 0; qh < 2; ++qh)
#pragma unroll
    for (int hh = 0; hh < 2; ++hh)
      qa[qh][hh] = *(const bf16x8*)(Qp + (size_t)(qbase + qh * 16 + lr) * E + hh * 32 + lg * 8);

  bf16x8 ones;
#pragma unroll
  for (int j = 0; j < 8; ++j) ones[j] = (__bf16)1.0f;

  f32x4 o_acc[2][4];      // [qh][nf]
#pragma unroll
  for (int qh = 0; qh < 2; ++qh)
#pragma unroll
    for (int nf = 0; nf < 4; ++nf) o_acc[qh][nf] = f32x4{0.f, 0.f, 0.f, 0.f};
  f32x4 sum_acc[2] = {f32x4{0.f, 0.f, 0.f, 0.f}, f32x4{0.f, 0.f, 0.f, 0.f}};

  // ---- hoisted loop-invariant LDS byte offsets (round-9 patterns) ----
  const int swz8 = lr & 7;
  int fofs0[4], fofs1[4];            // K/V fragment offsets (same tile geometry)
#pragma unroll
  for (int nf = 0; nf < 4; ++nf) {
    fofs0[nf] = (((nf * 16 + lr) * 64) + (lg ^ swz8) * 8) * 2;
    fofs1[nf] = (((nf * 16 + lr) * 64) + ((4 + lg) ^ swz8) * 8) * 2;
  }
  const int ptb = 32768 + w * 4096;               // per-wave 4KB (2 qh halves)
  const int xrb = (lg & 1) * 4;                   // writer key = xrb + r
  const int cbase = lr >> 3;                      // logical chunk = nf*2 + cbase
  int pwb[4];                                     // + qh*2048 + chunk<<4
#pragma unroll
  for (int r = 0; r < 4; ++r) pwb[r] = ptb + (lg * 4 + r) * 128 + (lr & 7) * 2;
  const int prd0 = ptb + lr * 128 + ((lg ^ swz8) << 4);          // + qh*2048
  const int prd1 = ptb + lr * 128 + (((4 + lg) ^ swz8) << 4);

  const int sc = l & 7, srl = l >> 3;
  auto stageK = [&](int buf, int kb) {
#pragma unroll
    for (int i = 0; i < 2; ++i) {
      const int row = i * 32 + w * 8 + srl;
      const int cp = sc ^ (row & 7);
      gl_lds16(Kp + (size_t)(kb + row) * E + cp * 8,
               (u16*)(SM + buf * 8192 + (i * 32 + w * 8) * 128));
    }
  };
  auto stageV = [&](int buf, int kb) {
#pragma unroll
    for (int i = 0; i < 2; ++i) {
      const int row = i * 32 + w * 8 + srl;
      const int cp = sc ^ (row & 7);
      gl_lds16(Vp + (size_t)row * S + kb + cp * 8,
               (u16*)(SM + 16384 + buf * 8192 + (i * 32 + w * 8) * 128));
    }
  };
  auto qk = [&](const char* Kc, f32x4 (&s)[2][4]) {
#pragma unroll
    for (int nf = 0; nf < 4; ++nf) {
      bf16x8 k0 = *(const bf16x8*)(Kc + fofs0[nf]);
      bf16x8 k1 = *(const bf16x8*)(Kc + fofs1[nf]);
#pragma unroll
      for (int qh = 0; qh < 2; ++qh) {
        f32x4 z = f32x4{0.f, 0.f, 0.f, 0.f};
        z = __builtin_amdgcn_mfma_f32_16x16x32_bf16(qa[qh][0], k0, z, 0, 0, 0);
        s[qh][nf] = __builtin_amdgcn_mfma_f32_16x16x32_bf16(qa[qh][1], k1, z, 0, 0, 0);
      }
    }
  };

  // prologue: K0,V0 staged; K1 staged; s(0) computed
  stageK(0, 0); stageV(0, 0);
  __syncthreads();                 // K0, V0 resident
  stageK(1, 64);
  f32x4 sfr[2][4];
  __builtin_amdgcn_s_setprio(1);
  qk(SM, sfr);                     // QK(0) from Ks[0]
  __builtin_amdgcn_s_setprio(0);
  __syncthreads();                 // K1 resident; all waves done reading Ks[0]

  for (int t = 0; t < NT; ++t) {
    const int cur = t & 1;
    // issue stages first: K(t+2) into buf QK(t) finished with; V(t+1)
    if (t + 2 < NT) stageK(cur, (t + 2) * 64);
    if (t + 1 < NT) stageV(cur ^ 1, (t + 1) * 64);

    // softmax(t): P = exp2(sfr), scattered b16 writes (zero-conflict pattern)
#pragma unroll
    for (int qh = 0; qh < 2; ++qh)
#pragma unroll
      for (int nf = 0; nf < 4; ++nf)
#pragma unroll
        for (int r = 0; r < 4; ++r) {
          __bf16 pb = (__bf16)exp2f(sfr[qh][nf][r]);
          *(u16*)(SM + pwb[r] + qh * 2048 + (((nf * 2 + cbase) ^ (xrb + r)) << 4)) =
              __builtin_bit_cast(u16, pb);
        }

    // QK(t+1) from Ks[cur^1] (staged 2 ahead) — independent of softmax/PV(t)
    f32x4 snew[2][4];
    if (t + 1 < NT) {
      __builtin_amdgcn_s_setprio(1);
      qk(SM + (cur ^ 1) * 8192, snew);
      __builtin_amdgcn_s_setprio(0);
    }

    // P fragments (wave-private RAW through LDS) + denominators via ones-MFMA
    bf16x8 pa[2][2];
#pragma unroll
    for (int qh = 0; qh < 2; ++qh) {
      pa[qh][0] = *(const bf16x8*)(SM + prd0 + qh * 2048);
      pa[qh][1] = *(const bf16x8*)(SM + prd1 + qh * 2048);
      sum_acc[qh] = __builtin_amdgcn_mfma_f32_16x16x32_bf16(pa[qh][0], ones, sum_acc[qh], 0, 0, 0);
      sum_acc[qh] = __builtin_amdgcn_mfma_f32_16x16x32_bf16(pa[qh][1], ones, sum_acc[qh], 0, 0, 0);
    }

    // PV(t): each V fragment pair feeds both qh halves
    const char* Vc = SM + 16384 + cur * 8192;
    __builtin_amdgcn_s_setprio(1);
#pragma unroll
    for (int nf = 0; nf < 4; ++nf) {
      bf16x8 vb0 = *(const bf16x8*)(Vc + fofs0[nf]);
      bf16x8 vb1 = *(const bf16x8*)(Vc + fofs1[nf]);
#pragma unroll
      for (int qh = 0; qh < 2; ++qh) {
        o_acc[qh][nf] = __builtin_amdgcn_mfma_f32_16x16x32_bf16(pa[qh][0], vb0, o_acc[qh][nf], 0, 0, 0);
        o_acc[qh][nf] = __builtin_amdgcn_mfma_f32_16x16x32_bf16(pa[qh][1], vb1, o_acc[qh][nf], 0, 0, 0);
      }
    }
    __builtin_amdgcn_s_setprio(0);

    if (t + 1 < NT) {
#pragma unroll
      for (int qh = 0; qh < 2; ++qh)
#pragma unroll
        for (int nf = 0; nf < 4; ++nf) sfr[qh][nf] = snew[qh][nf];
    }
    __syncthreads();   // drains this iter's stages; all waves done reading bufs
  }

#pragma unroll
  for (int qh = 0; qh < 2; ++qh)
#pragma unroll
    for (int r = 0; r < 4; ++r) {
      const float inv = 1.0f / sum_acc[qh][r];
      const size_t row = (size_t)b * S + qbase + qh * 16 + lg * 4 + r;
#pragma unroll
      for (int nf = 0; nf < 4; ++nf)
        Ao[row * E + h * 64 + nf * 16 + lr] = f2bf(o_acc[qh][nf][r] * inv);
    }
}

// ---------------- launch ----------------
extern "C" void kernel_launch(void* const* d_in, const int* in_sizes, int n_in,
                              void* d_out, int out_size, void* d_ws, size_t ws_size,
                              hipStream_t stream) {
  const float* q  = (const float*)d_in[0];
  const float* k  = (const float*)d_in[1];
  const float* v  = (const float*)d_in[2];
  const float* Wq = (const float*)d_in[3];
  const float* bq = (const float*)d_in[4];
  const float* Wk = (const float*)d_in[5];
  const float* bk = (const float*)d_in[6];
  const float* Wv = (const float*)d_in[7];
  const float* bv = (const float*)d_in[8];
  const float* Wo = (const float*)d_in[9];
  const float* bo = (const float*)d_in[10];
  float* out = (float*)d_out;

  char* ws = (char*)d_ws;
  u16* qb  = (u16*)(ws);                       // 4M elems, 8MB
  u16* kb  = (u16*)(ws + (8u << 20));
  u16* vb  = (u16*)(ws + (16u << 20));
  u16* wqb = (u16*)(ws + (24u << 20));         // 1M elems, 2MB each
  u16* wkb = (u16*)(ws + (26u << 20));
  u16* wvb = (u16*)(ws + (28u << 20));
  u16* wob = (u16*)(ws + (30u << 20));
  u16* qhp = (u16*)(ws + (32u << 20));         // 8MB each
  u16* khp = (u16*)(ws + (40u << 20));
  u16* vtp = (u16*)(ws + (48u << 20));         // V^T [b,h,d,s]
  u16* attnb = qb;  // reuse: qb dead after projections

  cast_kernel<<<dim3(16384), dim3(256), 0, stream>>>(q, k, v, Wq, Wk, Wv, Wo,
                                                     qb, kb, vb, wqb, wkb, wvb, wob);
  proj_kernel<<<dim3(32, 8, 3), dim3(256), 0, stream>>>(qb, kb, vb, wqb, wkb, wvb,
                                                        bq, bk, bv, qhp, khp, vtp);
  attn_kernel<<<dim3(32, 16), dim3(256), 0, stream>>>(qhp, khp, vtp, attnb);
  outproj_kernel<<<dim3(32, 8), dim3(256), 0, stream>>>(attnb, wob, bo, out);
}

// Round 12
// 138.951 us; speedup vs baseline: 1.3986x; 1.0111x over previous
//
#include <hip/hip_runtime.h>

// B=2, S=2048, E=1024, HEADS=16, HEAD_SIZE=64
// out = softmax((q Wq^T + bq)(k Wk^T + bk)^T / 32) (v Wv^T + bv) Wo^T + bo

typedef unsigned short u16;
typedef __bf16 bf16x8 __attribute__((ext_vector_type(8)));
typedef float f32x4 __attribute__((ext_vector_type(4)));
typedef u16 u16x4 __attribute__((ext_vector_type(4)));

typedef __attribute__((address_space(1))) const unsigned int as1_cu32;
typedef __attribute__((address_space(3))) unsigned int as3_u32;

__device__ __forceinline__ u16 f2bf(float f) {
  unsigned u = __builtin_bit_cast(unsigned, f);
  u += 0x7fffu + ((u >> 16) & 1u);   // RTNE
  return (u16)(u >> 16);
}

__device__ __forceinline__ void gl_lds16(const u16* g, u16* l) {
  // async global->LDS, 16B/lane; LDS dest = wave-uniform base + lane*16
  __builtin_amdgcn_global_load_lds((as1_cu32*)g, (as3_u32*)l, 16, 0, 0);
}

// ---------------- fp32 -> bf16 cast (q,k,v + 4 weights) ----------------
__global__ void cast_kernel(const float* __restrict__ q, const float* __restrict__ k,
                            const float* __restrict__ v, const float* __restrict__ wq,
                            const float* __restrict__ wk, const float* __restrict__ wv,
                            const float* __restrict__ wo,
                            u16* __restrict__ qb, u16* __restrict__ kb, u16* __restrict__ vb,
                            u16* __restrict__ wqb, u16* __restrict__ wkb, u16* __restrict__ wvb,
                            u16* __restrict__ wob) {
  unsigned t = blockIdx.x * 256u + threadIdx.x;  // one float4 (4 elems) per thread
  const float* src; u16* dst; unsigned off;
  if (t < 3u * 1048576u) {            // q,k,v: 4M elems = 1M float4 each
    unsigned which = t >> 20;
    off = t & 1048575u;
    src = which == 0 ? q : (which == 1 ? k : v);
    dst = which == 0 ? qb : (which == 1 ? kb : vb);
  } else {                            // weights: 1M elems = 256K float4 each
    unsigned tw = t - 3u * 1048576u;
    unsigned which = tw >> 18;
    off = tw & 262143u;
    src = which == 0 ? wq : (which == 1 ? wk : (which == 2 ? wv : wo));
    dst = which == 0 ? wqb : (which == 1 ? wkb : (which == 2 ? wvb : wob));
  }
  float4 f = ((const float4*)src)[off];
  u16x4 o;
  o[0] = f2bf(f.x); o[1] = f2bf(f.y); o[2] = f2bf(f.z); o[3] = f2bf(f.w);
  ((u16x4*)dst)[off] = o;
}

// ---------------- NT GEMM: C = scale*(A B^T + bias) ----------------
// M=4096, N=1024, K=1024; 128x128 tile, BK=32, 4 waves 2x2, 16x16x32 MFMA, dbuf LDS.
// MODE: 0 = bf16 row-major out, 1 = f32 row-major out, 2 = bf16 V^T out [b,h,d,s]
__device__ __forceinline__ void gemm_stage(const u16* A, const u16* B,
                                           u16 (&As)[128][32], u16 (&Bs)[128][32],
                                           int m0, int n0, int kt, int w, int l) {
#pragma unroll
  for (int i = 0; i < 2; ++i) {
    int r0 = i * 64 + w * 16;
    gl_lds16(A + (size_t)(m0 + r0 + (l >> 2)) * 1024 + kt * 32 + (l & 3) * 8, &As[r0][0]);
    gl_lds16(B + (size_t)(n0 + r0 + (l >> 2)) * 1024 + kt * 32 + (l & 3) * 8, &Bs[r0][0]);
  }
}

template <int MODE>
__device__ __forceinline__ void gemm_body(const u16* __restrict__ A, const u16* __restrict__ B,
                                          const float* __restrict__ bias, void* __restrict__ Cv,
                                          float scale,
                                          u16 (&As)[2][128][32], u16 (&Bs)[2][128][32]) {
  constexpr int N = 1024, NK = 32;
  const int m0 = blockIdx.x * 128;
  const int n0 = blockIdx.y * 128;
  const int tid = threadIdx.x;
  const int w = tid >> 6, l = tid & 63;
  const int lr = l & 15, lg = l >> 4;
  const int wm = (w >> 1) * 64, wn = (w & 1) * 64;

  f32x4 acc[4][4];
#pragma unroll
  for (int i = 0; i < 4; ++i)
#pragma unroll
    for (int j = 0; j < 4; ++j) acc[i][j] = f32x4{0.f, 0.f, 0.f, 0.f};

  gemm_stage(A, B, As[0], Bs[0], m0, n0, 0, w, l);

  for (int kt = 0; kt < NK; ++kt) {
    const int buf = kt & 1;
    __syncthreads();
    if (kt + 1 < NK) gemm_stage(A, B, As[buf ^ 1], Bs[buf ^ 1], m0, n0, kt + 1, w, l);
    bf16x8 af[4], bfr[4];
#pragma unroll
    for (int i = 0; i < 4; ++i) {
      af[i]  = *(const bf16x8*)&As[buf][wm + i * 16 + lr][lg * 8];
      bfr[i] = *(const bf16x8*)&Bs[buf][wn + i * 16 + lr][lg * 8];
    }
#pragma unroll
    for (int mi = 0; mi < 4; ++mi)
#pragma unroll
      for (int ni = 0; ni < 4; ++ni)
        acc[mi][ni] = __builtin_amdgcn_mfma_f32_16x16x32_bf16(af[mi], bfr[ni], acc[mi][ni], 0, 0, 0);
  }

  float bv[4];
#pragma unroll
  for (int ni = 0; ni < 4; ++ni) bv[ni] = bias[n0 + wn + ni * 16 + lr];
#pragma unroll
  for (int mi = 0; mi < 4; ++mi)
#pragma unroll
    for (int ni = 0; ni < 4; ++ni)
#pragma unroll
      for (int r = 0; r < 4; ++r) {
        const int row = m0 + wm + mi * 16 + lg * 4 + r;
        const int col = n0 + wn + ni * 16 + lr;
        float vv = (acc[mi][ni][r] + bv[ni]) * scale;
        if constexpr (MODE == 1) {
          ((float*)Cv)[(size_t)row * N + col] = vv;
        } else if constexpr (MODE == 0) {
          ((u16*)Cv)[(size_t)row * N + col] = f2bf(vv);
        } else {  // V^T: [b][h*64+d][s]
          ((u16*)Cv)[((size_t)((row >> 11) << 10) + col) * 2048 + (row & 2047)] = f2bf(vv);
        }
      }
}

__global__ __launch_bounds__(256, 3)
void proj_kernel(const u16* __restrict__ qb, const u16* __restrict__ kb, const u16* __restrict__ vb,
                 const u16* __restrict__ wqb, const u16* __restrict__ wkb, const u16* __restrict__ wvb,
                 const float* __restrict__ bq, const float* __restrict__ bk, const float* __restrict__ bvv,
                 u16* __restrict__ qh, u16* __restrict__ kh, u16* __restrict__ vt) {
  __shared__ __align__(16) u16 As[2][128][32];
  __shared__ __align__(16) u16 Bs[2][128][32];
  // Q gets scale log2(e)/32 so attention scores feed exp2 directly
  if (blockIdx.z == 0)      gemm_body<0>(qb, wqb, bq, qh, 1.44269504089f / 32.f, As, Bs);
  else if (blockIdx.z == 1) gemm_body<0>(kb, wkb, bk, kh, 1.0f, As, Bs);
  else                      gemm_body<2>(vb, wvb, bvv, vt, 1.0f, As, Bs);
}

__global__ __launch_bounds__(256, 2)
void outproj_kernel(const u16* __restrict__ attnb, const u16* __restrict__ wob,
                    const float* __restrict__ bo, float* __restrict__ out) {
  __shared__ __align__(16) u16 As[2][128][32];
  __shared__ __align__(16) u16 Bs[2][128][32];
  gemm_body<1>(attnb, wob, bo, out, 1.0f, As, Bs);
}

// ---------------- flash attention: 32 q-rows per wave (round-9 best) ---------
// grid (32 bh, 16 qt). 4 waves, wave w owns q-rows [qt*128 + w*32, +32) as two
// 16-row halves qh=0,1. Each K/V fragment load from LDS feeds TWO MFMAs.
// P path = measured-zero-conflict mappings (128B rows, 8-chunk XOR,
// writer key (q&7)=(lg&1)*4+r, reader key lr&7), one PT half per qh.
__global__ __launch_bounds__(256, 2)
void attn_kernel(const u16* __restrict__ Q, const u16* __restrict__ Kh,
                 const u16* __restrict__ Vt, u16* __restrict__ Ao) {
  constexpr int E = 1024, S = 2048, NT = S / 64;
  const int bh = blockIdx.x, qt = blockIdx.y;
  const int b = bh >> 4, h = bh & 15;
  const int tid = threadIdx.x, w = tid >> 6, l = tid & 63;
  const int lr = l & 15, lg = l >> 4;

  // LDS arena: [0,16K) Ks[2][64][64]  [16K,32K) Vs[2][64][64]
  //            [32K,48K) PT[4 w][2 qh][16 q][64 k] bf16 (128 B rows)
  __shared__ __align__(16) char SM[49152];

  const u16* Qp = Q + (size_t)b * S * E + (size_t)h * 64;
  const u16* Kp = Kh + (size_t)b * S * E + (size_t)h * 64;
  const u16* Vp = Vt + (size_t)bh * 64 * S;   // [d][s]

  const int qbase = qt * 128 + w * 32;
  bf16x8 qa[2][2];
#pragma unroll
  for (int qh = 0; qh < 2; ++qh)
#pragma unroll
    for (int hh = 0; hh < 2; ++hh)
      qa[qh][hh] = *(const bf16x8*)(Qp + (size_t)(qbase + qh * 16 + lr) * E + hh * 32 + lg * 8);

  bf16x8 ones;
#pragma unroll
  for (int j = 0; j < 8; ++j) ones[j] = (__bf16)1.0f;

  f32x4 o_acc[2][4];      // [qh][nf]
#pragma unroll
  for (int qh = 0; qh < 2; ++qh)
#pragma unroll
    for (int nf = 0; nf < 4; ++nf) o_acc[qh][nf] = f32x4{0.f, 0.f, 0.f, 0.f};
  f32x4 sum_acc[2] = {f32x4{0.f, 0.f, 0.f, 0.f}, f32x4{0.f, 0.f, 0.f, 0.f}};

  // ---- hoisted loop-invariant LDS byte offsets ----
  const int swz8 = lr & 7;
  int fofs0[4], fofs1[4];            // K/V fragment offsets (same tile geometry)
#pragma unroll
  for (int nf = 0; nf < 4; ++nf) {
    fofs0[nf] = (((nf * 16 + lr) * 64) + (lg ^ swz8) * 8) * 2;
    fofs1[nf] = (((nf * 16 + lr) * 64) + ((4 + lg) ^ swz8) * 8) * 2;
  }
  const int ptb = 32768 + w * 4096;               // per-wave 4KB (2 qh halves)
  const int xrb = (lg & 1) * 4;                   // writer key = xrb + r
  const int cbase = lr >> 3;                      // logical chunk = nf*2 + cbase
  int pwb[4];                                     // + qh*2048 + chunk<<4
#pragma unroll
  for (int r = 0; r < 4; ++r) pwb[r] = ptb + (lg * 4 + r) * 128 + (lr & 7) * 2;
  const int prd0 = ptb + lr * 128 + ((lg ^ swz8) << 4);          // + qh*2048
  const int prd1 = ptb + lr * 128 + (((4 + lg) ^ swz8) << 4);

  const int sc = l & 7, srl = l >> 3;
  auto stageK = [&](int buf, int kb) {
#pragma unroll
    for (int i = 0; i < 2; ++i) {
      const int row = i * 32 + w * 8 + srl;
      const int cp = sc ^ (row & 7);
      gl_lds16(Kp + (size_t)(kb + row) * E + cp * 8,
               (u16*)(SM + buf * 8192 + (i * 32 + w * 8) * 128));
    }
  };
  auto stageV = [&](int buf, int kb) {
#pragma unroll
    for (int i = 0; i < 2; ++i) {
      const int row = i * 32 + w * 8 + srl;
      const int cp = sc ^ (row & 7);
      gl_lds16(Vp + (size_t)row * S + kb + cp * 8,
               (u16*)(SM + 16384 + buf * 8192 + (i * 32 + w * 8) * 128));
    }
  };

  stageK(0, 0); stageV(0, 0);
  for (int t = 0; t < NT; ++t) {
    const int cur = t & 1;
    __syncthreads();                           // buf[cur] ready; prior reads drained
    if (t + 1 < NT) { stageK(cur ^ 1, (t + 1) * 64); stageV(cur ^ 1, (t + 1) * 64); }
    const char* Kc = SM + cur * 8192;
    const char* Vc = SM + 16384 + cur * 8192;

    // QK^T: each K fragment pair feeds both qh halves
    f32x4 sfr[2][4];
    __builtin_amdgcn_s_setprio(1);
#pragma unroll
    for (int nf = 0; nf < 4; ++nf) {
      bf16x8 k0 = *(const bf16x8*)(Kc + fofs0[nf]);
      bf16x8 k1 = *(const bf16x8*)(Kc + fofs1[nf]);
#pragma unroll
      for (int qh = 0; qh < 2; ++qh) {
        f32x4 z = f32x4{0.f, 0.f, 0.f, 0.f};
        z = __builtin_amdgcn_mfma_f32_16x16x32_bf16(qa[qh][0], k0, z, 0, 0, 0);
        sfr[qh][nf] = __builtin_amdgcn_mfma_f32_16x16x32_bf16(qa[qh][1], k1, z, 0, 0, 0);
      }
    }
    __builtin_amdgcn_s_setprio(0);

    // P = exp2(s): scattered b16 writes (zero-conflict pattern), per qh
#pragma unroll
    for (int qh = 0; qh < 2; ++qh)
#pragma unroll
      for (int nf = 0; nf < 4; ++nf)
#pragma unroll
        for (int r = 0; r < 4; ++r) {
          __bf16 pb = (__bf16)exp2f(sfr[qh][nf][r]);
          *(u16*)(SM + pwb[r] + qh * 2048 + (((nf * 2 + cbase) ^ (xrb + r)) << 4)) =
              __builtin_bit_cast(u16, pb);
        }

    // P fragments (wave-private RAW through LDS) + denominators via ones-MFMA
    bf16x8 pa[2][2];
#pragma unroll
    for (int qh = 0; qh < 2; ++qh) {
      pa[qh][0] = *(const bf16x8*)(SM + prd0 + qh * 2048);
      pa[qh][1] = *(const bf16x8*)(SM + prd1 + qh * 2048);
      sum_acc[qh] = __builtin_amdgcn_mfma_f32_16x16x32_bf16(pa[qh][0], ones, sum_acc[qh], 0, 0, 0);
      sum_acc[qh] = __builtin_amdgcn_mfma_f32_16x16x32_bf16(pa[qh][1], ones, sum_acc[qh], 0, 0, 0);
    }

    // PV: each V fragment pair feeds both qh halves
    __builtin_amdgcn_s_setprio(1);
#pragma unroll
    for (int nf = 0; nf < 4; ++nf) {
      bf16x8 vb0 = *(const bf16x8*)(Vc + fofs0[nf]);
      bf16x8 vb1 = *(const bf16x8*)(Vc + fofs1[nf]);
#pragma unroll
      for (int qh = 0; qh < 2; ++qh) {
        o_acc[qh][nf] = __builtin_amdgcn_mfma_f32_16x16x32_bf16(pa[qh][0], vb0, o_acc[qh][nf], 0, 0, 0);
        o_acc[qh][nf] = __builtin_amdgcn_mfma_f32_16x16x32_bf16(pa[qh][1], vb1, o_acc[qh][nf], 0, 0, 0);
      }
    }
    __builtin_amdgcn_s_setprio(0);
  }

#pragma unroll
  for (int qh = 0; qh < 2; ++qh)
#pragma unroll
    for (int r = 0; r < 4; ++r) {
      const float inv = 1.0f / sum_acc[qh][r];
      const size_t row = (size_t)b * S + qbase + qh * 16 + lg * 4 + r;
#pragma unroll
      for (int nf = 0; nf < 4; ++nf)
        Ao[row * E + h * 64 + nf * 16 + lr] = f2bf(o_acc[qh][nf][r] * inv);
    }
}

// ---------------- launch ----------------
extern "C" void kernel_launch(void* const* d_in, const int* in_sizes, int n_in,
                              void* d_out, int out_size, void* d_ws, size_t ws_size,
                              hipStream_t stream) {
  const float* q  = (const float*)d_in[0];
  const float* k  = (const float*)d_in[1];
  const float* v  = (const float*)d_in[2];
  const float* Wq = (const float*)d_in[3];
  const float* bq = (const float*)d_in[4];
  const float* Wk = (const float*)d_in[5];
  const float* bk = (const float*)d_in[6];
  const float* Wv = (const float*)d_in[7];
  const float* bv = (const float*)d_in[8];
  const float* Wo = (const float*)d_in[9];
  const float* bo = (const float*)d_in[10];
  float* out = (float*)d_out;

  char* ws = (char*)d_ws;
  u16* qb  = (u16*)(ws);                       // 4M elems, 8MB
  u16* kb  = (u16*)(ws + (8u << 20));
  u16* vb  = (u16*)(ws + (16u << 20));
  u16* wqb = (u16*)(ws + (24u << 20));         // 1M elems, 2MB each
  u16* wkb = (u16*)(ws + (26u << 20));
  u16* wvb = (u16*)(ws + (28u << 20));
  u16* wob = (u16*)(ws + (30u << 20));
  u16* qhp = (u16*)(ws + (32u << 20));         // 8MB each
  u16* khp = (u16*)(ws + (40u << 20));
  u16* vtp = (u16*)(ws + (48u << 20));         // V^T [b,h,d,s]
  u16* attnb = qb;  // reuse: qb dead after projections

  cast_kernel<<<dim3(16384), dim3(256), 0, stream>>>(q, k, v, Wq, Wk, Wv, Wo,
                                                     qb, kb, vb, wqb, wkb, wvb, wob);
  proj_kernel<<<dim3(32, 8, 3), dim3(256), 0, stream>>>(qb, kb, vb, wqb, wkb, wvb,
                                                        bq, bk, bv, qhp, khp, vtp);
  attn_kernel<<<dim3(32, 16), dim3(256), 0, stream>>>(qhp, khp, vtp, attnb);
  outproj_kernel<<<dim3(32, 8), dim3(256), 0, stream>>>(attnb, wob, bo, out);
}

// Round 13
// 133.289 us; speedup vs baseline: 1.4581x; 1.0425x over previous
//
#include <hip/hip_runtime.h>

// B=2, S=2048, E=1024, HEADS=16, HEAD_SIZE=64
// out = softmax((q Wq^T + bq)(k Wk^T + bk)^T / 32) (v Wv^T + bv) Wo^T + bo

typedef unsigned short u16;
typedef __bf16 bf16x8 __attribute__((ext_vector_type(8)));
typedef float f32x4 __attribute__((ext_vector_type(4)));
typedef u16 u16x4 __attribute__((ext_vector_type(4)));
typedef u16 u16x8 __attribute__((ext_vector_type(8)));

typedef __attribute__((address_space(1))) const unsigned int as1_cu32;
typedef __attribute__((address_space(3))) unsigned int as3_u32;

__device__ __forceinline__ u16 f2bf(float f) {
  unsigned u = __builtin_bit_cast(unsigned, f);
  u += 0x7fffu + ((u >> 16) & 1u);   // RTNE
  return (u16)(u >> 16);
}

__device__ __forceinline__ void gl_lds16(const u16* g, u16* l) {
  // async global->LDS, 16B/lane; LDS dest = wave-uniform base + lane*16
  __builtin_amdgcn_global_load_lds((as1_cu32*)g, (as3_u32*)l, 16, 0, 0);
}

// ---------------- fp32 -> bf16 cast (q,k,v + 4 weights) ----------------
__global__ void cast_kernel(const float* __restrict__ q, const float* __restrict__ k,
                            const float* __restrict__ v, const float* __restrict__ wq,
                            const float* __restrict__ wk, const float* __restrict__ wv,
                            const float* __restrict__ wo,
                            u16* __restrict__ qb, u16* __restrict__ kb, u16* __restrict__ vb,
                            u16* __restrict__ wqb, u16* __restrict__ wkb, u16* __restrict__ wvb,
                            u16* __restrict__ wob) {
  unsigned t = blockIdx.x * 256u + threadIdx.x;  // one float4 (4 elems) per thread
  const float* src; u16* dst; unsigned off;
  if (t < 3u * 1048576u) {            // q,k,v: 4M elems = 1M float4 each
    unsigned which = t >> 20;
    off = t & 1048575u;
    src = which == 0 ? q : (which == 1 ? k : v);
    dst = which == 0 ? qb : (which == 1 ? kb : vb);
  } else {                            // weights: 1M elems = 256K float4 each
    unsigned tw = t - 3u * 1048576u;
    unsigned which = tw >> 18;
    off = tw & 262143u;
    src = which == 0 ? wq : (which == 1 ? wk : (which == 2 ? wv : wo));
    dst = which == 0 ? wqb : (which == 1 ? wkb : (which == 2 ? wvb : wob));
  }
  float4 f = ((const float4*)src)[off];
  u16x4 o;
  o[0] = f2bf(f.x); o[1] = f2bf(f.y); o[2] = f2bf(f.z); o[3] = f2bf(f.w);
  ((u16x4*)dst)[off] = o;
}

// ---------------- NT GEMM: C = scale*(A B^T + bias) ----------------
// M=4096, N=1024, K=1024; 128x128 tile, BK=32, 4 waves 2x2, 16x16x32 MFMA, dbuf LDS.
// MODE: 0 = bf16 row-major out, 1 = f32 row-major out,
// MODE 2 = bf16 V^T out [b,h,d,s] via LDS transpose + coalesced 16B stores.
__device__ __forceinline__ void gemm_stage(const u16* A, const u16* B,
                                           u16 (&As)[128][32], u16 (&Bs)[128][32],
                                           int m0, int n0, int kt, int w, int l) {
#pragma unroll
  for (int i = 0; i < 2; ++i) {
    int r0 = i * 64 + w * 16;
    gl_lds16(A + (size_t)(m0 + r0 + (l >> 2)) * 1024 + kt * 32 + (l & 3) * 8, &As[r0][0]);
    gl_lds16(B + (size_t)(n0 + r0 + (l >> 2)) * 1024 + kt * 32 + (l & 3) * 8, &Bs[r0][0]);
  }
}

template <int MODE>
__device__ __forceinline__ void gemm_body(const u16* __restrict__ A, const u16* __restrict__ B,
                                          const float* __restrict__ bias, void* __restrict__ Cv,
                                          float scale, char* SMraw) {
  u16 (*Asp)[128][32] = (u16(*)[128][32])SMraw;            // [2][128][32] = 16KB
  u16 (*Bsp)[128][32] = (u16(*)[128][32])(SMraw + 16384);  // [2][128][32] = 16KB
  constexpr int N = 1024, NK = 32;
  const int m0 = blockIdx.x * 128;
  const int n0 = blockIdx.y * 128;
  const int tid = threadIdx.x;
  const int w = tid >> 6, l = tid & 63;
  const int lr = l & 15, lg = l >> 4;
  const int wm = (w >> 1) * 64, wn = (w & 1) * 64;

  f32x4 acc[4][4];
#pragma unroll
  for (int i = 0; i < 4; ++i)
#pragma unroll
    for (int j = 0; j < 4; ++j) acc[i][j] = f32x4{0.f, 0.f, 0.f, 0.f};

  gemm_stage(A, B, Asp[0], Bsp[0], m0, n0, 0, w, l);

  for (int kt = 0; kt < NK; ++kt) {
    const int buf = kt & 1;
    __syncthreads();
    if (kt + 1 < NK) gemm_stage(A, B, Asp[buf ^ 1], Bsp[buf ^ 1], m0, n0, kt + 1, w, l);
    bf16x8 af[4], bfr[4];
#pragma unroll
    for (int i = 0; i < 4; ++i) {
      af[i]  = *(const bf16x8*)&Asp[buf][wm + i * 16 + lr][lg * 8];
      bfr[i] = *(const bf16x8*)&Bsp[buf][wn + i * 16 + lr][lg * 8];
    }
#pragma unroll
    for (int mi = 0; mi < 4; ++mi)
#pragma unroll
      for (int ni = 0; ni < 4; ++ni)
        acc[mi][ni] = __builtin_amdgcn_mfma_f32_16x16x32_bf16(af[mi], bfr[ni], acc[mi][ni], 0, 0, 0);
  }

  float bv[4];
#pragma unroll
  for (int ni = 0; ni < 4; ++ni) bv[ni] = bias[n0 + wn + ni * 16 + lr];

  if constexpr (MODE != 2) {
#pragma unroll
    for (int mi = 0; mi < 4; ++mi)
#pragma unroll
      for (int ni = 0; ni < 4; ++ni)
#pragma unroll
        for (int r = 0; r < 4; ++r) {
          const int row = m0 + wm + mi * 16 + lg * 4 + r;
          const int col = n0 + wn + ni * 16 + lr;
          float vv = (acc[mi][ni][r] + bv[ni]) * scale;
          if constexpr (MODE == 1) ((float*)Cv)[(size_t)row * N + col] = vv;
          else                     ((u16*)Cv)[(size_t)row * N + col] = f2bf(vv);
        }
  } else {
    // V^T epilogue: transpose 64x64 wave quadrant through LDS (reuse As/Bs),
    // then coalesced 16B stores (8 lanes cover one contiguous 128B d-row).
    __syncthreads();                      // all waves done reading As/Bs
    char* wb = SMraw + w * 8192;          // per-wave [64 d][64 s] bf16, 128B rows
#pragma unroll
    for (int mi = 0; mi < 4; ++mi)
#pragma unroll
      for (int ni = 0; ni < 4; ++ni)
#pragma unroll
        for (int r = 0; r < 4; ++r) {
          const int dl = ni * 16 + lr;
          const int sl = mi * 16 + lg * 4 + r;
          const int phys = (sl >> 3) ^ (lr & 7);   // chunk-XOR keyed by d&7
          *(u16*)(wb + dl * 128 + (phys << 4) + (sl & 7) * 2) =
              f2bf(acc[mi][ni][r] + bv[ni]);
        }
    // intra-wave RAW through LDS; read rows [d][s], store 16B chunks
    const int sc2 = l & 7, srl2 = l >> 3;
    const int rowg = m0 + wm;             // s base (same b for whole quadrant)
#pragma unroll
    for (int i = 0; i < 8; ++i) {
      const int dl = i * 8 + srl2;
      const int phys = sc2 ^ srl2;        // dl&7 == srl2
      u16x8 vrow = *(u16x8*)(wb + dl * 128 + (phys << 4));
      const int colg = n0 + wn + dl;
      u16* dst = (u16*)Cv + ((size_t)((rowg >> 11) << 10) + colg) * 2048 +
                 (rowg & 2047) + sc2 * 8;
      *(u16x8*)dst = vrow;
    }
  }
}

__global__ __launch_bounds__(256, 2)
void proj_kernel(const u16* __restrict__ qb, const u16* __restrict__ kb, const u16* __restrict__ vb,
                 const u16* __restrict__ wqb, const u16* __restrict__ wkb, const u16* __restrict__ wvb,
                 const float* __restrict__ bq, const float* __restrict__ bk, const float* __restrict__ bvv,
                 u16* __restrict__ qh, u16* __restrict__ kh, u16* __restrict__ vt) {
  __shared__ __align__(16) char SM[32768];
  // Q gets scale log2(e)/32 so attention scores feed exp2 directly
  if (blockIdx.z == 0)      gemm_body<0>(qb, wqb, bq, qh, 1.44269504089f / 32.f, SM);
  else if (blockIdx.z == 1) gemm_body<0>(kb, wkb, bk, kh, 1.0f, SM);
  else                      gemm_body<2>(vb, wvb, bvv, vt, 1.0f, SM);
}

__global__ __launch_bounds__(256, 2)
void outproj_kernel(const u16* __restrict__ attnb, const u16* __restrict__ wob,
                    const float* __restrict__ bo, float* __restrict__ out) {
  __shared__ __align__(16) char SM[32768];
  gemm_body<1>(attnb, wob, bo, out, 1.0f, SM);
}

// ---------------- flash attention: 32 q-rows per wave (round-9 best) ---------
// grid (32 bh, 16 qt). 4 waves, wave w owns q-rows [qt*128 + w*32, +32) as two
// 16-row halves qh=0,1. Each K/V fragment load from LDS feeds TWO MFMAs.
// P path = measured-zero-conflict mappings (128B rows, 8-chunk XOR,
// writer key (q&7)=(lg&1)*4+r, reader key lr&7), one PT half per qh.
__global__ __launch_bounds__(256, 2)
void attn_kernel(const u16* __restrict__ Q, const u16* __restrict__ Kh,
                 const u16* __restrict__ Vt, u16* __restrict__ Ao) {
  constexpr int E = 1024, S = 2048, NT = S / 64;
  const int bh = blockIdx.x, qt = blockIdx.y;
  const int b = bh >> 4, h = bh & 15;
  const int tid = threadIdx.x, w = tid >> 6, l = tid & 63;
  const int lr = l & 15, lg = l >> 4;

  // LDS arena: [0,16K) Ks[2][64][64]  [16K,32K) Vs[2][64][64]
  //            [32K,48K) PT[4 w][2 qh][16 q][64 k] bf16 (128 B rows)
  __shared__ __align__(16) char SM[49152];

  const u16* Qp = Q + (size_t)b * S * E + (size_t)h * 64;
  const u16* Kp = Kh + (size_t)b * S * E + (size_t)h * 64;
  const u16* Vp = Vt + (size_t)bh * 64 * S;   // [d][s]

  const int qbase = qt * 128 + w * 32;
  bf16x8 qa[2][2];
#pragma unroll
  for (int qh = 0; qh < 2; ++qh)
#pragma unroll
    for (int hh = 0; hh < 2; ++hh)
      qa[qh][hh] = *(const bf16x8*)(Qp + (size_t)(qbase + qh * 16 + lr) * E + hh * 32 + lg * 8);

  bf16x8 ones;
#pragma unroll
  for (int j = 0; j < 8; ++j) ones[j] = (__bf16)1.0f;

  f32x4 o_acc[2][4];      // [qh][nf]
#pragma unroll
  for (int qh = 0; qh < 2; ++qh)
#pragma unroll
    for (int nf = 0; nf < 4; ++nf) o_acc[qh][nf] = f32x4{0.f, 0.f, 0.f, 0.f};
  f32x4 sum_acc[2] = {f32x4{0.f, 0.f, 0.f, 0.f}, f32x4{0.f, 0.f, 0.f, 0.f}};

  // ---- hoisted loop-invariant LDS byte offsets ----
  const int swz8 = lr & 7;
  int fofs0[4], fofs1[4];            // K/V fragment offsets (same tile geometry)
#pragma unroll
  for (int nf = 0; nf < 4; ++nf) {
    fofs0[nf] = (((nf * 16 + lr) * 64) + (lg ^ swz8) * 8) * 2;
    fofs1[nf] = (((nf * 16 + lr) * 64) + ((4 + lg) ^ swz8) * 8) * 2;
  }
  const int ptb = 32768 + w * 4096;               // per-wave 4KB (2 qh halves)
  const int xrb = (lg & 1) * 4;                   // writer key = xrb + r
  const int cbase = lr >> 3;                      // logical chunk = nf*2 + cbase
  int pwb[4];                                     // + qh*2048 + chunk<<4
#pragma unroll
  for (int r = 0; r < 4; ++r) pwb[r] = ptb + (lg * 4 + r) * 128 + (lr & 7) * 2;
  const int prd0 = ptb + lr * 128 + ((lg ^ swz8) << 4);          // + qh*2048
  const int prd1 = ptb + lr * 128 + (((4 + lg) ^ swz8) << 4);

  const int sc = l & 7, srl = l >> 3;
  auto stageK = [&](int buf, int kb) {
#pragma unroll
    for (int i = 0; i < 2; ++i) {
      const int row = i * 32 + w * 8 + srl;
      const int cp = sc ^ (row & 7);
      gl_lds16(Kp + (size_t)(kb + row) * E + cp * 8,
               (u16*)(SM + buf * 8192 + (i * 32 + w * 8) * 128));
    }
  };
  auto stageV = [&](int buf, int kb) {
#pragma unroll
    for (int i = 0; i < 2; ++i) {
      const int row = i * 32 + w * 8 + srl;
      const int cp = sc ^ (row & 7);
      gl_lds16(Vp + (size_t)row * S + kb + cp * 8,
               (u16*)(SM + 16384 + buf * 8192 + (i * 32 + w * 8) * 128));
    }
  };

  stageK(0, 0); stageV(0, 0);
  for (int t = 0; t < NT; ++t) {
    const int cur = t & 1;
    __syncthreads();                           // buf[cur] ready; prior reads drained
    if (t + 1 < NT) { stageK(cur ^ 1, (t + 1) * 64); stageV(cur ^ 1, (t + 1) * 64); }
    const char* Kc = SM + cur * 8192;
    const char* Vc = SM + 16384 + cur * 8192;

    // QK^T: each K fragment pair feeds both qh halves
    f32x4 sfr[2][4];
    __builtin_amdgcn_s_setprio(1);
#pragma unroll
    for (int nf = 0; nf < 4; ++nf) {
      bf16x8 k0 = *(const bf16x8*)(Kc + fofs0[nf]);
      bf16x8 k1 = *(const bf16x8*)(Kc + fofs1[nf]);
#pragma unroll
      for (int qh = 0; qh < 2; ++qh) {
        f32x4 z = f32x4{0.f, 0.f, 0.f, 0.f};
        z = __builtin_amdgcn_mfma_f32_16x16x32_bf16(qa[qh][0], k0, z, 0, 0, 0);
        sfr[qh][nf] = __builtin_amdgcn_mfma_f32_16x16x32_bf16(qa[qh][1], k1, z, 0, 0, 0);
      }
    }
    __builtin_amdgcn_s_setprio(0);

    // P = exp2(s): scattered b16 writes (zero-conflict pattern), per qh
#pragma unroll
    for (int qh = 0; qh < 2; ++qh)
#pragma unroll
      for (int nf = 0; nf < 4; ++nf)
#pragma unroll
        for (int r = 0; r < 4; ++r) {
          __bf16 pb = (__bf16)exp2f(sfr[qh][nf][r]);
          *(u16*)(SM + pwb[r] + qh * 2048 + (((nf * 2 + cbase) ^ (xrb + r)) << 4)) =
              __builtin_bit_cast(u16, pb);
        }

    // P fragments (wave-private RAW through LDS) + denominators via ones-MFMA
    bf16x8 pa[2][2];
#pragma unroll
    for (int qh = 0; qh < 2; ++qh) {
      pa[qh][0] = *(const bf16x8*)(SM + prd0 + qh * 2048);
      pa[qh][1] = *(const bf16x8*)(SM + prd1 + qh * 2048);
      sum_acc[qh] = __builtin_amdgcn_mfma_f32_16x16x32_bf16(pa[qh][0], ones, sum_acc[qh], 0, 0, 0);
      sum_acc[qh] = __builtin_amdgcn_mfma_f32_16x16x32_bf16(pa[qh][1], ones, sum_acc[qh], 0, 0, 0);
    }

    // PV: each V fragment pair feeds both qh halves
    __builtin_amdgcn_s_setprio(1);
#pragma unroll
    for (int nf = 0; nf < 4; ++nf) {
      bf16x8 vb0 = *(const bf16x8*)(Vc + fofs0[nf]);
      bf16x8 vb1 = *(const bf16x8*)(Vc + fofs1[nf]);
#pragma unroll
      for (int qh = 0; qh < 2; ++qh) {
        o_acc[qh][nf] = __builtin_amdgcn_mfma_f32_16x16x32_bf16(pa[qh][0], vb0, o_acc[qh][nf], 0, 0, 0);
        o_acc[qh][nf] = __builtin_amdgcn_mfma_f32_16x16x32_bf16(pa[qh][1], vb1, o_acc[qh][nf], 0, 0, 0);
      }
    }
    __builtin_amdgcn_s_setprio(0);
  }

#pragma unroll
  for (int qh = 0; qh < 2; ++qh)
#pragma unroll
    for (int r = 0; r < 4; ++r) {
      const float inv = 1.0f / sum_acc[qh][r];
      const size_t row = (size_t)b * S + qbase + qh * 16 + lg * 4 + r;
#pragma unroll
      for (int nf = 0; nf < 4; ++nf)
        Ao[row * E + h * 64 + nf * 16 + lr] = f2bf(o_acc[qh][nf][r] * inv);
    }
}

// ---------------- launch ----------------
extern "C" void kernel_launch(void* const* d_in, const int* in_sizes, int n_in,
                              void* d_out, int out_size, void* d_ws, size_t ws_size,
                              hipStream_t stream) {
  const float* q  = (const float*)d_in[0];
  const float* k  = (const float*)d_in[1];
  const float* v  = (const float*)d_in[2];
  const float* Wq = (const float*)d_in[3];
  const float* bq = (const float*)d_in[4];
  const float* Wk = (const float*)d_in[5];
  const float* bk = (const float*)d_in[6];
  const float* Wv = (const float*)d_in[7];
  const float* bv = (const float*)d_in[8];
  const float* Wo = (const float*)d_in[9];
  const float* bo = (const float*)d_in[10];
  float* out = (float*)d_out;

  char* ws = (char*)d_ws;
  u16* qb  = (u16*)(ws);                       // 4M elems, 8MB
  u16* kb  = (u16*)(ws + (8u << 20));
  u16* vb  = (u16*)(ws + (16u << 20));
  u16* wqb = (u16*)(ws + (24u << 20));         // 1M elems, 2MB each
  u16* wkb = (u16*)(ws + (26u << 20));
  u16* wvb = (u16*)(ws + (28u << 20));
  u16* wob = (u16*)(ws + (30u << 20));
  u16* qhp = (u16*)(ws + (32u << 20));         // 8MB each
  u16* khp = (u16*)(ws + (40u << 20));
  u16* vtp = (u16*)(ws + (48u << 20));         // V^T [b,h,d,s]
  u16* attnb = qb;  // reuse: qb dead after projections

  cast_kernel<<<dim3(16384), dim3(256), 0, stream>>>(q, k, v, Wq, Wk, Wv, Wo,
                                                     qb, kb, vb, wqb, wkb, wvb, wob);
  proj_kernel<<<dim3(32, 8, 3), dim3(256), 0, stream>>>(qb, kb, vb, wqb, wkb, wvb,
                                                        bq, bk, bv, qhp, khp, vtp);
  attn_kernel<<<dim3(32, 16), dim3(256), 0, stream>>>(qhp, khp, vtp, attnb);
  outproj_kernel<<<dim3(32, 8), dim3(256), 0, stream>>>(attnb, wob, bo, out);
}

// Round 14
// 123.165 us; speedup vs baseline: 1.5779x; 1.0822x over previous
//
#include <hip/hip_runtime.h>

// B=2, S=2048, E=1024, HEADS=16, HEAD_SIZE=64
// out = softmax((q Wq^T + bq)(k Wk^T + bk)^T / 32) (v Wv^T + bv) Wo^T + bo

typedef unsigned short u16;
typedef __bf16 bf16x8 __attribute__((ext_vector_type(8)));
typedef float f32x4 __attribute__((ext_vector_type(4)));
typedef u16 u16x4 __attribute__((ext_vector_type(4)));
typedef u16 u16x8 __attribute__((ext_vector_type(8)));

typedef __attribute__((address_space(1))) const unsigned int as1_cu32;
typedef __attribute__((address_space(3))) unsigned int as3_u32;

__device__ __forceinline__ u16 f2bf(float f) {
  unsigned u = __builtin_bit_cast(unsigned, f);
  u += 0x7fffu + ((u >> 16) & 1u);   // RTNE
  return (u16)(u >> 16);
}

__device__ __forceinline__ void gl_lds16(const u16* g, u16* l) {
  // async global->LDS, 16B/lane; LDS dest = wave-uniform base + lane*16
  __builtin_amdgcn_global_load_lds((as1_cu32*)g, (as3_u32*)l, 16, 0, 0);
}

// ---------------- fp32 -> bf16 cast (q,k,v + 4 weights) ----------------
__global__ void cast_kernel(const float* __restrict__ q, const float* __restrict__ k,
                            const float* __restrict__ v, const float* __restrict__ wq,
                            const float* __restrict__ wk, const float* __restrict__ wv,
                            const float* __restrict__ wo,
                            u16* __restrict__ qb, u16* __restrict__ kb, u16* __restrict__ vb,
                            u16* __restrict__ wqb, u16* __restrict__ wkb, u16* __restrict__ wvb,
                            u16* __restrict__ wob) {
  unsigned t = blockIdx.x * 256u + threadIdx.x;  // one float4 (4 elems) per thread
  const float* src; u16* dst; unsigned off;
  if (t < 3u * 1048576u) {            // q,k,v: 4M elems = 1M float4 each
    unsigned which = t >> 20;
    off = t & 1048575u;
    src = which == 0 ? q : (which == 1 ? k : v);
    dst = which == 0 ? qb : (which == 1 ? kb : vb);
  } else {                            // weights: 1M elems = 256K float4 each
    unsigned tw = t - 3u * 1048576u;
    unsigned which = tw >> 18;
    off = tw & 262143u;
    src = which == 0 ? wq : (which == 1 ? wk : (which == 2 ? wv : wo));
    dst = which == 0 ? wqb : (which == 1 ? wkb : (which == 2 ? wvb : wob));
  }
  float4 f = ((const float4*)src)[off];
  u16x4 o;
  o[0] = f2bf(f.x); o[1] = f2bf(f.y); o[2] = f2bf(f.z); o[3] = f2bf(f.w);
  ((u16x4*)dst)[off] = o;
}

// ---------------- NT GEMM: C = scale*(A B^T + bias) ----------------
// M=4096, N=1024, K=1024; 128x128 tile, BK=32, 4 waves 2x2, 16x16x32 MFMA, dbuf LDS.
// MODE: 0 = bf16 row-major out, 1 = f32 row-major out,
// MODE 2 = bf16 V^T out [b,h,d,s] via LDS transpose + coalesced 16B stores.
__device__ __forceinline__ void gemm_stage(const u16* A, const u16* B,
                                           u16 (&As)[128][32], u16 (&Bs)[128][32],
                                           int m0, int n0, int kt, int w, int l) {
#pragma unroll
  for (int i = 0; i < 2; ++i) {
    int r0 = i * 64 + w * 16;
    gl_lds16(A + (size_t)(m0 + r0 + (l >> 2)) * 1024 + kt * 32 + (l & 3) * 8, &As[r0][0]);
    gl_lds16(B + (size_t)(n0 + r0 + (l >> 2)) * 1024 + kt * 32 + (l & 3) * 8, &Bs[r0][0]);
  }
}

template <int MODE>
__device__ __forceinline__ void gemm_body(const u16* __restrict__ A, const u16* __restrict__ B,
                                          const float* __restrict__ bias, void* __restrict__ Cv,
                                          float scale, char* SMraw) {
  u16 (*Asp)[128][32] = (u16(*)[128][32])SMraw;            // [2][128][32] = 16KB
  u16 (*Bsp)[128][32] = (u16(*)[128][32])(SMraw + 16384);  // [2][128][32] = 16KB
  constexpr int N = 1024, NK = 32;
  const int m0 = blockIdx.x * 128;
  const int n0 = blockIdx.y * 128;
  const int tid = threadIdx.x;
  const int w = tid >> 6, l = tid & 63;
  const int lr = l & 15, lg = l >> 4;
  const int wm = (w >> 1) * 64, wn = (w & 1) * 64;

  f32x4 acc[4][4];
#pragma unroll
  for (int i = 0; i < 4; ++i)
#pragma unroll
    for (int j = 0; j < 4; ++j) acc[i][j] = f32x4{0.f, 0.f, 0.f, 0.f};

  gemm_stage(A, B, Asp[0], Bsp[0], m0, n0, 0, w, l);

  for (int kt = 0; kt < NK; ++kt) {
    const int buf = kt & 1;
    __syncthreads();
    if (kt + 1 < NK) gemm_stage(A, B, Asp[buf ^ 1], Bsp[buf ^ 1], m0, n0, kt + 1, w, l);
    bf16x8 af[4], bfr[4];
#pragma unroll
    for (int i = 0; i < 4; ++i) {
      af[i]  = *(const bf16x8*)&Asp[buf][wm + i * 16 + lr][lg * 8];
      bfr[i] = *(const bf16x8*)&Bsp[buf][wn + i * 16 + lr][lg * 8];
    }
#pragma unroll
    for (int mi = 0; mi < 4; ++mi)
#pragma unroll
      for (int ni = 0; ni < 4; ++ni)
        acc[mi][ni] = __builtin_amdgcn_mfma_f32_16x16x32_bf16(af[mi], bfr[ni], acc[mi][ni], 0, 0, 0);
  }

  float bv[4];
#pragma unroll
  for (int ni = 0; ni < 4; ++ni) bv[ni] = bias[n0 + wn + ni * 16 + lr];

  if constexpr (MODE != 2) {
#pragma unroll
    for (int mi = 0; mi < 4; ++mi)
#pragma unroll
      for (int ni = 0; ni < 4; ++ni)
#pragma unroll
        for (int r = 0; r < 4; ++r) {
          const int row = m0 + wm + mi * 16 + lg * 4 + r;
          const int col = n0 + wn + ni * 16 + lr;
          float vv = (acc[mi][ni][r] + bv[ni]) * scale;
          if constexpr (MODE == 1) ((float*)Cv)[(size_t)row * N + col] = vv;
          else                     ((u16*)Cv)[(size_t)row * N + col] = f2bf(vv);
        }
  } else {
    // V^T epilogue: transpose 64x64 wave quadrant through LDS (reuse As/Bs),
    // then coalesced 16B stores (8 lanes cover one contiguous 128B d-row).
    __syncthreads();                      // all waves done reading As/Bs
    char* wb = SMraw + w * 8192;          // per-wave [64 d][64 s] bf16, 128B rows
#pragma unroll
    for (int mi = 0; mi < 4; ++mi)
#pragma unroll
      for (int ni = 0; ni < 4; ++ni)
#pragma unroll
        for (int r = 0; r < 4; ++r) {
          const int dl = ni * 16 + lr;
          const int sl = mi * 16 + lg * 4 + r;
          const int phys = (sl >> 3) ^ (lr & 7);   // chunk-XOR keyed by d&7
          *(u16*)(wb + dl * 128 + (phys << 4) + (sl & 7) * 2) =
              f2bf(acc[mi][ni][r] + bv[ni]);
        }
    // intra-wave RAW through LDS; read rows [d][s], store 16B chunks
    const int sc2 = l & 7, srl2 = l >> 3;
    const int rowg = m0 + wm;             // s base (same b for whole quadrant)
#pragma unroll
    for (int i = 0; i < 8; ++i) {
      const int dl = i * 8 + srl2;
      const int phys = sc2 ^ srl2;        // dl&7 == srl2
      u16x8 vrow = *(u16x8*)(wb + dl * 128 + (phys << 4));
      const int colg = n0 + wn + dl;
      u16* dst = (u16*)Cv + ((size_t)((rowg >> 11) << 10) + colg) * 2048 +
                 (rowg & 2047) + sc2 * 8;
      *(u16x8*)dst = vrow;
    }
  }
}

__global__ __launch_bounds__(256, 2)
void proj_kernel(const u16* __restrict__ qb, const u16* __restrict__ kb, const u16* __restrict__ vb,
                 const u16* __restrict__ wqb, const u16* __restrict__ wkb, const u16* __restrict__ wvb,
                 const float* __restrict__ bq, const float* __restrict__ bk, const float* __restrict__ bvv,
                 u16* __restrict__ qh, u16* __restrict__ kh, u16* __restrict__ vt) {
  __shared__ __align__(16) char SM[32768];
  // Q gets scale log2(e)/32 so attention scores feed exp2 directly
  if (blockIdx.z == 0)      gemm_body<0>(qb, wqb, bq, qh, 1.44269504089f / 32.f, SM);
  else if (blockIdx.z == 1) gemm_body<0>(kb, wkb, bk, kh, 1.0f, SM);
  else                      gemm_body<2>(vb, wvb, bvv, vt, 1.0f, SM);
}

__global__ __launch_bounds__(256, 2)
void outproj_kernel(const u16* __restrict__ attnb, const u16* __restrict__ wob,
                    const float* __restrict__ bo, float* __restrict__ out) {
  __shared__ __align__(16) char SM[32768];
  gemm_body<1>(attnb, wob, bo, out, 1.0f, SM);
}

// ---------------- flash attention: in-register P (swapped QK + row-permuted K)
// grid (32 bh, 16 qt). 4 waves, wave w owns 32 q-rows (2 qh halves).
// QK computed as mfma(K, Q) -> C col = lane = q: each lane's 16 scores are all
// for ONE q-row = the PV A-frag ownership. K-tile staged with row bit-permute
// k = [b5 b3 b2 b4 b1 b0] so lane-local k-quads become the NATURAL contiguous
// mapping kappa(lg,j) = win*32 + lg*8 + j -> V's conflict-free b128 reads match
// unchanged. P = exp2(sfr) built directly into MFMA A-frags; NO P LDS traffic.
// Output C-layout lands identically to round-9 (q in (lg,r), d in lr).
__global__ __launch_bounds__(256, 2)
void attn_kernel(const u16* __restrict__ Q, const u16* __restrict__ Kh,
                 const u16* __restrict__ Vt, u16* __restrict__ Ao) {
  constexpr int E = 1024, S = 2048, NT = S / 64;
  const int bh = blockIdx.x, qt = blockIdx.y;
  const int b = bh >> 4, h = bh & 15;
  const int tid = threadIdx.x, w = tid >> 6, l = tid & 63;
  const int lr = l & 15, lg = l >> 4;

  // LDS arena: [0,16K) Ks[2][64][64]  [16K,32K) Vs[2][64][64]
  __shared__ __align__(16) char SM[32768];

  const u16* Qp = Q + (size_t)b * S * E + (size_t)h * 64;
  const u16* Kp = Kh + (size_t)b * S * E + (size_t)h * 64;
  const u16* Vp = Vt + (size_t)bh * 64 * S;   // [d][s]

  const int qbase = qt * 128 + w * 32;
  bf16x8 qa[2][2];
#pragma unroll
  for (int qh = 0; qh < 2; ++qh)
#pragma unroll
    for (int hh = 0; hh < 2; ++hh)
      qa[qh][hh] = *(const bf16x8*)(Qp + (size_t)(qbase + qh * 16 + lr) * E + hh * 32 + lg * 8);

  bf16x8 ones;
#pragma unroll
  for (int j = 0; j < 8; ++j) ones[j] = (__bf16)1.0f;

  f32x4 o_acc[2][4];      // [qh][nf]  : O[q=lg*4+r][d=nf*16+lr]
#pragma unroll
  for (int qh = 0; qh < 2; ++qh)
#pragma unroll
    for (int nf = 0; nf < 4; ++nf) o_acc[qh][nf] = f32x4{0.f, 0.f, 0.f, 0.f};
  f32x4 sum_acc[2] = {f32x4{0.f, 0.f, 0.f, 0.f}, f32x4{0.f, 0.f, 0.f, 0.f}};

  // ---- hoisted loop-invariant LDS byte offsets ----
  const int swz8 = lr & 7;
  int fofs0[4], fofs1[4];            // K/V fragment offsets (same tile geometry)
#pragma unroll
  for (int nf = 0; nf < 4; ++nf) {
    fofs0[nf] = (((nf * 16 + lr) * 64) + (lg ^ swz8) * 8) * 2;
    fofs1[nf] = (((nf * 16 + lr) * 64) + ((4 + lg) ^ swz8) * 8) * 2;
  }

  const int sc = l & 7, srl = l >> 3;
  // K staged-row bit-permute: staged row r' holds global k = [b5 b3 b2 b4 b1 b0]
  auto kperm = [](int r) {
    return (r & 35) | ((r & 12) << 1) | ((r & 16) >> 2);
  };
  auto stageK = [&](int buf, int kb) {
#pragma unroll
    for (int i = 0; i < 2; ++i) {
      const int row = i * 32 + w * 8 + srl;
      const int cp = sc ^ (row & 7);
      gl_lds16(Kp + (size_t)(kb + kperm(row)) * E + cp * 8,
               (u16*)(SM + buf * 8192 + (i * 32 + w * 8) * 128));
    }
  };
  auto stageV = [&](int buf, int kb) {
#pragma unroll
    for (int i = 0; i < 2; ++i) {
      const int row = i * 32 + w * 8 + srl;
      const int cp = sc ^ (row & 7);
      gl_lds16(Vp + (size_t)row * S + kb + cp * 8,
               (u16*)(SM + 16384 + buf * 8192 + (i * 32 + w * 8) * 128));
    }
  };

  stageK(0, 0); stageV(0, 0);
  for (int t = 0; t < NT; ++t) {
    const int cur = t & 1;
    __syncthreads();                           // buf[cur] ready; prior reads drained
    if (t + 1 < NT) { stageK(cur ^ 1, (t + 1) * 64); stageV(cur ^ 1, (t + 1) * 64); }
    const char* Kc = SM + cur * 8192;
    const char* Vc = SM + 16384 + cur * 8192;

    // swapped QK^T: sfr[qh][nf], lane holds S[k'][q = qh*16 + lr] where the
    // staged-row permute makes lane-local quads contiguous: k of sfr[nf][r]
    // = (nf>>1)*32 + lg*8 + (nf&1)*4 + r
    f32x4 sfr[2][4];
    __builtin_amdgcn_s_setprio(1);
#pragma unroll
    for (int nf = 0; nf < 4; ++nf) {
      bf16x8 k0 = *(const bf16x8*)(Kc + fofs0[nf]);
      bf16x8 k1 = *(const bf16x8*)(Kc + fofs1[nf]);
#pragma unroll
      for (int qh = 0; qh < 2; ++qh) {
        f32x4 z = f32x4{0.f, 0.f, 0.f, 0.f};
        z = __builtin_amdgcn_mfma_f32_16x16x32_bf16(k0, qa[qh][0], z, 0, 0, 0);
        sfr[qh][nf] = __builtin_amdgcn_mfma_f32_16x16x32_bf16(k1, qa[qh][1], z, 0, 0, 0);
      }
    }
    __builtin_amdgcn_s_setprio(0);

    // P = exp2(s) packed straight into MFMA A-frags (no LDS):
    // pa0[qh] = k-window 0..31 (nf0 elems 0-3, nf1 elems 4-7); pa1 = 32..63
    bf16x8 pa0[2], pa1[2];
#pragma unroll
    for (int qh = 0; qh < 2; ++qh)
#pragma unroll
      for (int r = 0; r < 4; ++r) {
        pa0[qh][r]     = (__bf16)exp2f(sfr[qh][0][r]);
        pa0[qh][4 + r] = (__bf16)exp2f(sfr[qh][1][r]);
        pa1[qh][r]     = (__bf16)exp2f(sfr[qh][2][r]);
        pa1[qh][4 + r] = (__bf16)exp2f(sfr[qh][3][r]);
      }

    // denominators via ones-MFMA (sums all 32 k-slots per window)
#pragma unroll
    for (int qh = 0; qh < 2; ++qh) {
      sum_acc[qh] = __builtin_amdgcn_mfma_f32_16x16x32_bf16(pa0[qh], ones, sum_acc[qh], 0, 0, 0);
      sum_acc[qh] = __builtin_amdgcn_mfma_f32_16x16x32_bf16(pa1[qh], ones, sum_acc[qh], 0, 0, 0);
    }

    // PV: V b128 frags (conflict-free, same fofs), each feeds both qh halves
    __builtin_amdgcn_s_setprio(1);
#pragma unroll
    for (int nf = 0; nf < 4; ++nf) {
      bf16x8 vb0 = *(const bf16x8*)(Vc + fofs0[nf]);
      bf16x8 vb1 = *(const bf16x8*)(Vc + fofs1[nf]);
#pragma unroll
      for (int qh = 0; qh < 2; ++qh) {
        o_acc[qh][nf] = __builtin_amdgcn_mfma_f32_16x16x32_bf16(pa0[qh], vb0, o_acc[qh][nf], 0, 0, 0);
        o_acc[qh][nf] = __builtin_amdgcn_mfma_f32_16x16x32_bf16(pa1[qh], vb1, o_acc[qh][nf], 0, 0, 0);
      }
    }
    __builtin_amdgcn_s_setprio(0);
  }

#pragma unroll
  for (int qh = 0; qh < 2; ++qh)
#pragma unroll
    for (int r = 0; r < 4; ++r) {
      const float inv = 1.0f / sum_acc[qh][r];
      const size_t row = (size_t)b * S + qbase + qh * 16 + lg * 4 + r;
#pragma unroll
      for (int nf = 0; nf < 4; ++nf)
        Ao[row * E + h * 64 + nf * 16 + lr] = f2bf(o_acc[qh][nf][r] * inv);
    }
}

// ---------------- launch ----------------
extern "C" void kernel_launch(void* const* d_in, const int* in_sizes, int n_in,
                              void* d_out, int out_size, void* d_ws, size_t ws_size,
                              hipStream_t stream) {
  const float* q  = (const float*)d_in[0];
  const float* k  = (const float*)d_in[1];
  const float* v  = (const float*)d_in[2];
  const float* Wq = (const float*)d_in[3];
  const float* bq = (const float*)d_in[4];
  const float* Wk = (const float*)d_in[5];
  const float* bk = (const float*)d_in[6];
  const float* Wv = (const float*)d_in[7];
  const float* bv = (const float*)d_in[8];
  const float* Wo = (const float*)d_in[9];
  const float* bo = (const float*)d_in[10];
  float* out = (float*)d_out;

  char* ws = (char*)d_ws;
  u16* qb  = (u16*)(ws);                       // 4M elems, 8MB
  u16* kb  = (u16*)(ws + (8u << 20));
  u16* vb  = (u16*)(ws + (16u << 20));
  u16* wqb = (u16*)(ws + (24u << 20));         // 1M elems, 2MB each
  u16* wkb = (u16*)(ws + (26u << 20));
  u16* wvb = (u16*)(ws + (28u << 20));
  u16* wob = (u16*)(ws + (30u << 20));
  u16* qhp = (u16*)(ws + (32u << 20));         // 8MB each
  u16* khp = (u16*)(ws + (40u << 20));
  u16* vtp = (u16*)(ws + (48u << 20));         // V^T [b,h,d,s]
  u16* attnb = qb;  // reuse: qb dead after projections

  cast_kernel<<<dim3(16384), dim3(256), 0, stream>>>(q, k, v, Wq, Wk, Wv, Wo,
                                                     qb, kb, vb, wqb, wkb, wvb, wob);
  proj_kernel<<<dim3(32, 8, 3), dim3(256), 0, stream>>>(qb, kb, vb, wqb, wkb, wvb,
                                                        bq, bk, bv, qhp, khp, vtp);
  attn_kernel<<<dim3(32, 16), dim3(256), 0, stream>>>(qhp, khp, vtp, attnb);
  outproj_kernel<<<dim3(32, 8), dim3(256), 0, stream>>>(attnb, wob, bo, out);
}

// Round 15
// 107.520 us; speedup vs baseline: 1.8075x; 1.1455x over previous
//
#include <hip/hip_runtime.h>

// B=2, S=2048, E=1024, HEADS=16, HEAD_SIZE=64
// out = softmax((q Wq^T + bq)(k Wk^T + bk)^T / 32) (v Wv^T + bv) Wo^T + bo

typedef unsigned short u16;
typedef __bf16 bf16x8 __attribute__((ext_vector_type(8)));
typedef float f32x4 __attribute__((ext_vector_type(4)));
typedef u16 u16x4 __attribute__((ext_vector_type(4)));
typedef u16 u16x8 __attribute__((ext_vector_type(8)));

typedef __attribute__((address_space(1))) const unsigned int as1_cu32;
typedef __attribute__((address_space(3))) unsigned int as3_u32;

#if __has_builtin(__builtin_amdgcn_exp2f)
#define EXP2(x) __builtin_amdgcn_exp2f(x)   // raw v_exp_f32 (inputs are normal-range)
#else
#define EXP2(x) exp2f(x)
#endif

__device__ __forceinline__ u16 f2bf(float f) {
  unsigned u = __builtin_bit_cast(unsigned, f);
  u += 0x7fffu + ((u >> 16) & 1u);   // RTNE
  return (u16)(u >> 16);
}

__device__ __forceinline__ void gl_lds16(const u16* g, u16* l) {
  // async global->LDS, 16B/lane; LDS dest = wave-uniform base + lane*16
  __builtin_amdgcn_global_load_lds((as1_cu32*)g, (as3_u32*)l, 16, 0, 0);
}

// ---------------- fp32 -> bf16 cast (q,k,v + 4 weights) ----------------
__global__ void cast_kernel(const float* __restrict__ q, const float* __restrict__ k,
                            const float* __restrict__ v, const float* __restrict__ wq,
                            const float* __restrict__ wk, const float* __restrict__ wv,
                            const float* __restrict__ wo,
                            u16* __restrict__ qb, u16* __restrict__ kb, u16* __restrict__ vb,
                            u16* __restrict__ wqb, u16* __restrict__ wkb, u16* __restrict__ wvb,
                            u16* __restrict__ wob) {
  unsigned t = blockIdx.x * 256u + threadIdx.x;  // one float4 (4 elems) per thread
  const float* src; u16* dst; unsigned off;
  if (t < 3u * 1048576u) {            // q,k,v: 4M elems = 1M float4 each
    unsigned which = t >> 20;
    off = t & 1048575u;
    src = which == 0 ? q : (which == 1 ? k : v);
    dst = which == 0 ? qb : (which == 1 ? kb : vb);
  } else {                            // weights: 1M elems = 256K float4 each
    unsigned tw = t - 3u * 1048576u;
    unsigned which = tw >> 18;
    off = tw & 262143u;
    src = which == 0 ? wq : (which == 1 ? wk : (which == 2 ? wv : wo));
    dst = which == 0 ? wqb : (which == 1 ? wkb : (which == 2 ? wvb : wob));
  }
  float4 f = ((const float4*)src)[off];
  u16x4 o;
  o[0] = f2bf(f.x); o[1] = f2bf(f.y); o[2] = f2bf(f.z); o[3] = f2bf(f.w);
  ((u16x4*)dst)[off] = o;
}

// ---------------- NT GEMM: C = scale*(A B^T + bias) ----------------
// BM x 128 tile, BK=32, 4 waves, 16x16x32 MFMA, dbuf LDS.
// BM=128: waves 2x2 (64x64 each). BM=64: waves 2x2 (32x64 each).
// MODE: 0 = bf16 row-major out, 1 = f32 row-major out,
// MODE 2 = bf16 V^T out [b,h,d,s] via LDS transpose + coalesced 16B stores.
template <int BM>
__device__ __forceinline__ void gemm_stage(const u16* A, const u16* B,
                                           u16 (&As)[BM][32], u16 (&Bs)[128][32],
                                           int m0, int n0, int kt, int w, int l) {
#pragma unroll
  for (int i = 0; i < BM / 64; ++i) {
    int r0 = i * 64 + w * 16;
    gl_lds16(A + (size_t)(m0 + r0 + (l >> 2)) * 1024 + kt * 32 + (l & 3) * 8, &As[r0][0]);
  }
#pragma unroll
  for (int i = 0; i < 2; ++i) {
    int r0 = i * 64 + w * 16;
    gl_lds16(B + (size_t)(n0 + r0 + (l >> 2)) * 1024 + kt * 32 + (l & 3) * 8, &Bs[r0][0]);
  }
}

template <int MODE, int BM>
__device__ __forceinline__ void gemm_body(const u16* __restrict__ A, const u16* __restrict__ B,
                                          const float* __restrict__ bias, void* __restrict__ Cv,
                                          float scale, char* SMraw) {
  constexpr int MI = BM / 32;                              // M frags per wave
  u16 (*Asp)[BM][32] = (u16(*)[BM][32])SMraw;              // [2][BM][32]
  u16 (*Bsp)[128][32] = (u16(*)[128][32])(SMraw + BM * 128);
  constexpr int N = 1024, NK = 32;
  const int m0 = blockIdx.x * BM;
  const int n0 = blockIdx.y * 128;
  const int tid = threadIdx.x;
  const int w = tid >> 6, l = tid & 63;
  const int lr = l & 15, lg = l >> 4;
  const int wm = (w >> 1) * (BM / 2), wn = (w & 1) * 64;

  f32x4 acc[MI][4];
#pragma unroll
  for (int i = 0; i < MI; ++i)
#pragma unroll
    for (int j = 0; j < 4; ++j) acc[i][j] = f32x4{0.f, 0.f, 0.f, 0.f};

  gemm_stage<BM>(A, B, Asp[0], Bsp[0], m0, n0, 0, w, l);

  for (int kt = 0; kt < NK; ++kt) {
    const int buf = kt & 1;
    __syncthreads();
    if (kt + 1 < NK) gemm_stage<BM>(A, B, Asp[buf ^ 1], Bsp[buf ^ 1], m0, n0, kt + 1, w, l);
    bf16x8 af[MI], bfr[4];
#pragma unroll
    for (int i = 0; i < MI; ++i)
      af[i] = *(const bf16x8*)&Asp[buf][wm + i * 16 + lr][lg * 8];
#pragma unroll
    for (int i = 0; i < 4; ++i)
      bfr[i] = *(const bf16x8*)&Bsp[buf][wn + i * 16 + lr][lg * 8];
#pragma unroll
    for (int mi = 0; mi < MI; ++mi)
#pragma unroll
      for (int ni = 0; ni < 4; ++ni)
        acc[mi][ni] = __builtin_amdgcn_mfma_f32_16x16x32_bf16(af[mi], bfr[ni], acc[mi][ni], 0, 0, 0);
  }

  float bv[4];
#pragma unroll
  for (int ni = 0; ni < 4; ++ni) bv[ni] = bias[n0 + wn + ni * 16 + lr];

  if constexpr (MODE != 2) {
#pragma unroll
    for (int mi = 0; mi < MI; ++mi)
#pragma unroll
      for (int ni = 0; ni < 4; ++ni)
#pragma unroll
        for (int r = 0; r < 4; ++r) {
          const int row = m0 + wm + mi * 16 + lg * 4 + r;
          const int col = n0 + wn + ni * 16 + lr;
          float vv = (acc[mi][ni][r] + bv[ni]) * scale;
          if constexpr (MODE == 1) ((float*)Cv)[(size_t)row * N + col] = vv;
          else                     ((u16*)Cv)[(size_t)row * N + col] = f2bf(vv);
        }
  } else {
    // V^T epilogue (BM=128 only): transpose 64x64 wave quadrant through LDS,
    // then coalesced 16B stores (8 lanes cover one contiguous 128B d-row).
    __syncthreads();                      // all waves done reading As/Bs
    char* wb = SMraw + w * 8192;          // per-wave [64 d][64 s] bf16, 128B rows
#pragma unroll
    for (int mi = 0; mi < MI; ++mi)
#pragma unroll
      for (int ni = 0; ni < 4; ++ni)
#pragma unroll
        for (int r = 0; r < 4; ++r) {
          const int dl = ni * 16 + lr;
          const int sl = mi * 16 + lg * 4 + r;
          const int phys = (sl >> 3) ^ (lr & 7);   // chunk-XOR keyed by d&7
          *(u16*)(wb + dl * 128 + (phys << 4) + (sl & 7) * 2) =
              f2bf(acc[mi][ni][r] + bv[ni]);
        }
    // intra-wave RAW through LDS; read rows [d][s], store 16B chunks
    const int sc2 = l & 7, srl2 = l >> 3;
    const int rowg = m0 + wm;             // s base (same b for whole quadrant)
#pragma unroll
    for (int i = 0; i < 8; ++i) {
      const int dl = i * 8 + srl2;
      const int phys = sc2 ^ srl2;        // dl&7 == srl2
      u16x8 vrow = *(u16x8*)(wb + dl * 128 + (phys << 4));
      const int colg = n0 + wn + dl;
      u16* dst = (u16*)Cv + ((size_t)((rowg >> 11) << 10) + colg) * 2048 +
                 (rowg & 2047) + sc2 * 8;
      *(u16x8*)dst = vrow;
    }
  }
}

__global__ __launch_bounds__(256, 2)
void proj_kernel(const u16* __restrict__ qb, const u16* __restrict__ kb, const u16* __restrict__ vb,
                 const u16* __restrict__ wqb, const u16* __restrict__ wkb, const u16* __restrict__ wvb,
                 const float* __restrict__ bq, const float* __restrict__ bk, const float* __restrict__ bvv,
                 u16* __restrict__ qh, u16* __restrict__ kh, u16* __restrict__ vt) {
  __shared__ __align__(16) char SM[32768];
  // Q gets scale log2(e)/32 so attention scores feed exp2 directly
  if (blockIdx.z == 0)      gemm_body<0, 128>(qb, wqb, bq, qh, 1.44269504089f / 32.f, SM);
  else if (blockIdx.z == 1) gemm_body<0, 128>(kb, wkb, bk, kh, 1.0f, SM);
  else                      gemm_body<2, 128>(vb, wvb, bvv, vt, 1.0f, SM);
}

__global__ __launch_bounds__(256, 2)
void outproj_kernel(const u16* __restrict__ attnb, const u16* __restrict__ wob,
                    const float* __restrict__ bo, float* __restrict__ out) {
  __shared__ __align__(16) char SM[24576];   // As 8KB + Bs 16KB
  gemm_body<1, 64>(attnb, wob, bo, out, 1.0f, SM);
}

// ---------------- flash attention: in-register P (swapped QK + row-permuted K)
// grid (32 bh, 16 qt). 4 waves, wave w owns 32 q-rows (2 qh halves).
// QK computed as mfma(K, Q) -> C col = lane = q: each lane's 16 scores are all
// for ONE q-row = the PV A-frag ownership. K-tile staged with row bit-permute
// k = [b5 b3 b2 b4 b1 b0] so lane-local k-quads become the NATURAL contiguous
// mapping kappa(lg,j) = win*32 + lg*8 + j -> V's conflict-free b128 reads match
// unchanged. P = exp2(sfr) built directly into MFMA A-frags; NO P LDS traffic.
__global__ __launch_bounds__(256, 2)
void attn_kernel(const u16* __restrict__ Q, const u16* __restrict__ Kh,
                 const u16* __restrict__ Vt, u16* __restrict__ Ao) {
  constexpr int E = 1024, S = 2048, NT = S / 64;
  const int bh = blockIdx.x, qt = blockIdx.y;
  const int b = bh >> 4, h = bh & 15;
  const int tid = threadIdx.x, w = tid >> 6, l = tid & 63;
  const int lr = l & 15, lg = l >> 4;

  // LDS arena: [0,16K) Ks[2][64][64]  [16K,32K) Vs[2][64][64]
  __shared__ __align__(16) char SM[32768];

  const u16* Qp = Q + (size_t)b * S * E + (size_t)h * 64;
  const u16* Kp = Kh + (size_t)b * S * E + (size_t)h * 64;
  const u16* Vp = Vt + (size_t)bh * 64 * S;   // [d][s]

  const int qbase = qt * 128 + w * 32;
  bf16x8 qa[2][2];
#pragma unroll
  for (int qh = 0; qh < 2; ++qh)
#pragma unroll
    for (int hh = 0; hh < 2; ++hh)
      qa[qh][hh] = *(const bf16x8*)(Qp + (size_t)(qbase + qh * 16 + lr) * E + hh * 32 + lg * 8);

  bf16x8 ones;
#pragma unroll
  for (int j = 0; j < 8; ++j) ones[j] = (__bf16)1.0f;

  f32x4 o_acc[2][4];      // [qh][nf]  : O[q=lg*4+r][d=nf*16+lr]
#pragma unroll
  for (int qh = 0; qh < 2; ++qh)
#pragma unroll
    for (int nf = 0; nf < 4; ++nf) o_acc[qh][nf] = f32x4{0.f, 0.f, 0.f, 0.f};
  f32x4 sum_acc[2] = {f32x4{0.f, 0.f, 0.f, 0.f}, f32x4{0.f, 0.f, 0.f, 0.f}};

  // ---- hoisted loop-invariant LDS byte offsets ----
  const int swz8 = lr & 7;
  int fofs0[4], fofs1[4];            // K/V fragment offsets (same tile geometry)
#pragma unroll
  for (int nf = 0; nf < 4; ++nf) {
    fofs0[nf] = (((nf * 16 + lr) * 64) + (lg ^ swz8) * 8) * 2;
    fofs1[nf] = (((nf * 16 + lr) * 64) + ((4 + lg) ^ swz8) * 8) * 2;
  }

  const int sc = l & 7, srl = l >> 3;
  // K staged-row bit-permute: staged row r' holds global k = [b5 b3 b2 b4 b1 b0]
  auto kperm = [](int r) {
    return (r & 35) | ((r & 12) << 1) | ((r & 16) >> 2);
  };
  auto stageK = [&](int buf, int kb) {
#pragma unroll
    for (int i = 0; i < 2; ++i) {
      const int row = i * 32 + w * 8 + srl;
      const int cp = sc ^ (row & 7);
      gl_lds16(Kp + (size_t)(kb + kperm(row)) * E + cp * 8,
               (u16*)(SM + buf * 8192 + (i * 32 + w * 8) * 128));
    }
  };
  auto stageV = [&](int buf, int kb) {
#pragma unroll
    for (int i = 0; i < 2; ++i) {
      const int row = i * 32 + w * 8 + srl;
      const int cp = sc ^ (row & 7);
      gl_lds16(Vp + (size_t)row * S + kb + cp * 8,
               (u16*)(SM + 16384 + buf * 8192 + (i * 32 + w * 8) * 128));
    }
  };

  stageK(0, 0); stageV(0, 0);
  for (int t = 0; t < NT; ++t) {
    const int cur = t & 1;
    __syncthreads();                           // buf[cur] ready; prior reads drained
    if (t + 1 < NT) { stageK(cur ^ 1, (t + 1) * 64); stageV(cur ^ 1, (t + 1) * 64); }
    const char* Kc = SM + cur * 8192;
    const char* Vc = SM + 16384 + cur * 8192;

    // swapped QK^T: sfr[qh][nf], lane holds S[k'][q = qh*16 + lr]; staged-row
    // permute makes lane-local quads contiguous: k of sfr[nf][r]
    // = (nf>>1)*32 + lg*8 + (nf&1)*4 + r
    f32x4 sfr[2][4];
    __builtin_amdgcn_s_setprio(1);
#pragma unroll
    for (int nf = 0; nf < 4; ++nf) {
      bf16x8 k0 = *(const bf16x8*)(Kc + fofs0[nf]);
      bf16x8 k1 = *(const bf16x8*)(Kc + fofs1[nf]);
#pragma unroll
      for (int qh = 0; qh < 2; ++qh) {
        f32x4 z = f32x4{0.f, 0.f, 0.f, 0.f};
        z = __builtin_amdgcn_mfma_f32_16x16x32_bf16(k0, qa[qh][0], z, 0, 0, 0);
        sfr[qh][nf] = __builtin_amdgcn_mfma_f32_16x16x32_bf16(k1, qa[qh][1], z, 0, 0, 0);
      }
    }
    __builtin_amdgcn_s_setprio(0);

    // P = exp2(s) packed straight into MFMA A-frags (no LDS):
    // pa0[qh] = k-window 0..31 (nf0 elems 0-3, nf1 elems 4-7); pa1 = 32..63
    bf16x8 pa0[2], pa1[2];
#pragma unroll
    for (int qh = 0; qh < 2; ++qh)
#pragma unroll
      for (int r = 0; r < 4; ++r) {
        pa0[qh][r]     = (__bf16)EXP2(sfr[qh][0][r]);
        pa0[qh][4 + r] = (__bf16)EXP2(sfr[qh][1][r]);
        pa1[qh][r]     = (__bf16)EXP2(sfr[qh][2][r]);
        pa1[qh][4 + r] = (__bf16)EXP2(sfr[qh][3][r]);
      }

    // denominators via ones-MFMA (sums all 32 k-slots per window)
#pragma unroll
    for (int qh = 0; qh < 2; ++qh) {
      sum_acc[qh] = __builtin_amdgcn_mfma_f32_16x16x32_bf16(pa0[qh], ones, sum_acc[qh], 0, 0, 0);
      sum_acc[qh] = __builtin_amdgcn_mfma_f32_16x16x32_bf16(pa1[qh], ones, sum_acc[qh], 0, 0, 0);
    }

    // PV: V b128 frags (conflict-free, same fofs), each feeds both qh halves
    __builtin_amdgcn_s_setprio(1);
#pragma unroll
    for (int nf = 0; nf < 4; ++nf) {
      bf16x8 vb0 = *(const bf16x8*)(Vc + fofs0[nf]);
      bf16x8 vb1 = *(const bf16x8*)(Vc + fofs1[nf]);
#pragma unroll
      for (int qh = 0; qh < 2; ++qh) {
        o_acc[qh][nf] = __builtin_amdgcn_mfma_f32_16x16x32_bf16(pa0[qh], vb0, o_acc[qh][nf], 0, 0, 0);
        o_acc[qh][nf] = __builtin_amdgcn_mfma_f32_16x16x32_bf16(pa1[qh], vb1, o_acc[qh][nf], 0, 0, 0);
      }
    }
    __builtin_amdgcn_s_setprio(0);
  }

#pragma unroll
  for (int qh = 0; qh < 2; ++qh)
#pragma unroll
    for (int r = 0; r < 4; ++r) {
      const float inv = 1.0f / sum_acc[qh][r];
      const size_t row = (size_t)b * S + qbase + qh * 16 + lg * 4 + r;
#pragma unroll
      for (int nf = 0; nf < 4; ++nf)
        Ao[row * E + h * 64 + nf * 16 + lr] = f2bf(o_acc[qh][nf][r] * inv);
    }
}

// ---------------- launch ----------------
extern "C" void kernel_launch(void* const* d_in, const int* in_sizes, int n_in,
                              void* d_out, int out_size, void* d_ws, size_t ws_size,
                              hipStream_t stream) {
  const float* q  = (const float*)d_in[0];
  const float* k  = (const float*)d_in[1];
  const float* v  = (const float*)d_in[2];
  const float* Wq = (const float*)d_in[3];
  const float* bq = (const float*)d_in[4];
  const float* Wk = (const float*)d_in[5];
  const float* bk = (const float*)d_in[6];
  const float* Wv = (const float*)d_in[7];
  const float* bv = (const float*)d_in[8];
  const float* Wo = (const float*)d_in[9];
  const float* bo = (const float*)d_in[10];
  float* out = (float*)d_out;

  char* ws = (char*)d_ws;
  u16* qb  = (u16*)(ws);                       // 4M elems, 8MB
  u16* kb  = (u16*)(ws + (8u << 20));
  u16* vb  = (u16*)(ws + (16u << 20));
  u16* wqb = (u16*)(ws + (24u << 20));         // 1M elems, 2MB each
  u16* wkb = (u16*)(ws + (26u << 20));
  u16* wvb = (u16*)(ws + (28u << 20));
  u16* wob = (u16*)(ws + (30u << 20));
  u16* qhp = (u16*)(ws + (32u << 20));         // 8MB each
  u16* khp = (u16*)(ws + (40u << 20));
  u16* vtp = (u16*)(ws + (48u << 20));         // V^T [b,h,d,s]
  u16* attnb = qb;  // reuse: qb dead after projections

  cast_kernel<<<dim3(16384), dim3(256), 0, stream>>>(q, k, v, Wq, Wk, Wv, Wo,
                                                     qb, kb, vb, wqb, wkb, wvb, wob);
  proj_kernel<<<dim3(32, 8, 3), dim3(256), 0, stream>>>(qb, kb, vb, wqb, wkb, wvb,
                                                        bq, bk, bv, qhp, khp, vtp);
  attn_kernel<<<dim3(32, 16), dim3(256), 0, stream>>>(qhp, khp, vtp, attnb);
  outproj_kernel<<<dim3(64, 8), dim3(256), 0, stream>>>(attnb, wob, bo, out);
}

// Round 16
// 105.261 us; speedup vs baseline: 1.8463x; 1.0215x over previous
//
#include <hip/hip_runtime.h>

// B=2, S=2048, E=1024, HEADS=16, HEAD_SIZE=64
// out = softmax((q Wq^T + bq)(k Wk^T + bk)^T / 32) (v Wv^T + bv) Wo^T + bo

typedef unsigned short u16;
typedef __bf16 bf16x8 __attribute__((ext_vector_type(8)));
typedef float f32x4 __attribute__((ext_vector_type(4)));
typedef u16 u16x4 __attribute__((ext_vector_type(4)));
typedef u16 u16x8 __attribute__((ext_vector_type(8)));

typedef __attribute__((address_space(1))) const unsigned int as1_cu32;
typedef __attribute__((address_space(3))) unsigned int as3_u32;

#if __has_builtin(__builtin_amdgcn_exp2f)
#define EXP2(x) __builtin_amdgcn_exp2f(x)   // raw v_exp_f32 (inputs are normal-range)
#else
#define EXP2(x) exp2f(x)
#endif

__device__ __forceinline__ u16 f2bf(float f) {
  unsigned u = __builtin_bit_cast(unsigned, f);
  u += 0x7fffu + ((u >> 16) & 1u);   // RTNE
  return (u16)(u >> 16);
}

__device__ __forceinline__ void gl_lds16(const u16* g, u16* l) {
  // async global->LDS, 16B/lane; LDS dest = wave-uniform base + lane*16
  __builtin_amdgcn_global_load_lds((as1_cu32*)g, (as3_u32*)l, 16, 0, 0);
}

// ---------------- fp32 -> bf16 cast (4 weight matrices only) ----------------
__global__ void cast_kernel(const float* __restrict__ wq, const float* __restrict__ wk,
                            const float* __restrict__ wv, const float* __restrict__ wo,
                            u16* __restrict__ wqb, u16* __restrict__ wkb,
                            u16* __restrict__ wvb, u16* __restrict__ wob) {
  unsigned t = blockIdx.x * 256u + threadIdx.x;  // 1M float4 = 4 x 256K
  unsigned which = t >> 18, off = t & 262143u;
  const float* src = which == 0 ? wq : (which == 1 ? wk : (which == 2 ? wv : wo));
  u16* dst = which == 0 ? wqb : (which == 1 ? wkb : (which == 2 ? wvb : wob));
  float4 f = ((const float4*)src)[off];
  u16x4 o;
  o[0] = f2bf(f.x); o[1] = f2bf(f.y); o[2] = f2bf(f.z); o[3] = f2bf(f.w);
  ((u16x4*)dst)[off] = o;
}

// ---------------- NT GEMM: C = scale*(A B^T + bias) ----------------
// BM x 128 tile, BK=32, 4 waves, 16x16x32 MFMA, dbuf LDS.
// AF32: A staged as fp32 (128B rows, 8x16B units XOR-swizzled via pre-swizzled
// source), fragments read as 2x ds_read_b128 f32 and converted to bf16 in-reg.
// MODE: 0 = bf16 row-major out, 1 = f32 row-major out,
// MODE 2 = bf16 V^T out [b,h,d,s] via LDS transpose + coalesced 16B stores.
template <int MODE, int BM, bool AF32>
__device__ __forceinline__ void gemm_body(const void* __restrict__ Av, const u16* __restrict__ B,
                                          const float* __restrict__ bias, void* __restrict__ Cv,
                                          float scale, char* SMraw) {
  constexpr int MI = BM / 32;                              // M frags per wave
  constexpr int ABUF = AF32 ? (BM * 128) : (BM * 64);      // bytes per A buffer
  char* ASM = SMraw;
  char* BSM = SMraw + 2 * ABUF;                            // [2][128][64B]
  constexpr int N = 1024, NK = 32;
  const int m0 = blockIdx.x * BM;
  const int n0 = blockIdx.y * 128;
  const int tid = threadIdx.x;
  const int w = tid >> 6, l = tid & 63;
  const int lr = l & 15, lg = l >> 4;
  const int wm = (w >> 1) * (BM / 2), wn = (w & 1) * 64;

  auto stage = [&](int buf, int kt) {
    if constexpr (AF32) {
      const float* A = (const float*)Av;
#pragma unroll
      for (int i = 0; i < BM / 32; ++i) {     // 8 rows x 128B per issue
        const int row = i * 32 + w * 8 + (l >> 3);
        const int cp = (l & 7) ^ (row & 7);   // pre-swizzled source unit
        gl_lds16((const u16*)(A + (size_t)(m0 + row) * 1024 + kt * 32 + cp * 4),
                 (u16*)(ASM + buf * ABUF + (i * 32 + w * 8) * 128));
      }
    } else {
      const u16* A = (const u16*)Av;
#pragma unroll
      for (int i = 0; i < BM / 64; ++i) {
        const int r0 = i * 64 + w * 16;
        gl_lds16(A + (size_t)(m0 + r0 + (l >> 2)) * 1024 + kt * 32 + (l & 3) * 8,
                 (u16*)(ASM + buf * ABUF + r0 * 64));
      }
    }
#pragma unroll
    for (int i = 0; i < 2; ++i) {
      const int r0 = i * 64 + w * 16;
      gl_lds16(B + (size_t)(n0 + r0 + (l >> 2)) * 1024 + kt * 32 + (l & 3) * 8,
               (u16*)(BSM + buf * 8192 + r0 * 64));
    }
  };

  f32x4 acc[MI][4];
#pragma unroll
  for (int i = 0; i < MI; ++i)
#pragma unroll
    for (int j = 0; j < 4; ++j) acc[i][j] = f32x4{0.f, 0.f, 0.f, 0.f};

  stage(0, 0);

  for (int kt = 0; kt < NK; ++kt) {
    const int buf = kt & 1;
    __syncthreads();
    if (kt + 1 < NK) stage(buf ^ 1, kt + 1);
    bf16x8 af[MI], bfr[4];
    if constexpr (AF32) {
      const char* Ab = ASM + buf * ABUF;
#pragma unroll
      for (int i = 0; i < MI; ++i) {
        const int arow = wm + i * 16 + lr;
        const char* base = Ab + arow * 128;
        f32x4 a0 = *(const f32x4*)(base + (((lg * 2) ^ (arow & 7)) << 4));
        f32x4 a1 = *(const f32x4*)(base + (((lg * 2 + 1) ^ (arow & 7)) << 4));
#pragma unroll
        for (int j = 0; j < 4; ++j) { af[i][j] = (__bf16)a0[j]; af[i][4 + j] = (__bf16)a1[j]; }
      }
    } else {
#pragma unroll
      for (int i = 0; i < MI; ++i)
        af[i] = *(const bf16x8*)(ASM + buf * ABUF + (wm + i * 16 + lr) * 64 + lg * 16);
    }
#pragma unroll
    for (int i = 0; i < 4; ++i)
      bfr[i] = *(const bf16x8*)(BSM + buf * 8192 + (wn + i * 16 + lr) * 64 + lg * 16);
#pragma unroll
    for (int mi = 0; mi < MI; ++mi)
#pragma unroll
      for (int ni = 0; ni < 4; ++ni)
        acc[mi][ni] = __builtin_amdgcn_mfma_f32_16x16x32_bf16(af[mi], bfr[ni], acc[mi][ni], 0, 0, 0);
  }

  float bv[4];
#pragma unroll
  for (int ni = 0; ni < 4; ++ni) bv[ni] = bias[n0 + wn + ni * 16 + lr];

  if constexpr (MODE != 2) {
#pragma unroll
    for (int mi = 0; mi < MI; ++mi)
#pragma unroll
      for (int ni = 0; ni < 4; ++ni)
#pragma unroll
        for (int r = 0; r < 4; ++r) {
          const int row = m0 + wm + mi * 16 + lg * 4 + r;
          const int col = n0 + wn + ni * 16 + lr;
          float vv = (acc[mi][ni][r] + bv[ni]) * scale;
          if constexpr (MODE == 1) ((float*)Cv)[(size_t)row * N + col] = vv;
          else                     ((u16*)Cv)[(size_t)row * N + col] = f2bf(vv);
        }
  } else {
    // V^T epilogue: transpose 64x64 wave quadrant through LDS (reuse arena),
    // then coalesced 16B stores (8 lanes cover one contiguous 128B d-row).
    __syncthreads();                      // all waves done reading As/Bs
    char* wb = SMraw + w * 8192;          // per-wave [64 d][64 s] bf16, 128B rows
#pragma unroll
    for (int mi = 0; mi < MI; ++mi)
#pragma unroll
      for (int ni = 0; ni < 4; ++ni)
#pragma unroll
        for (int r = 0; r < 4; ++r) {
          const int dl = ni * 16 + lr;
          const int sl = mi * 16 + lg * 4 + r;
          const int phys = (sl >> 3) ^ (lr & 7);   // chunk-XOR keyed by d&7
          *(u16*)(wb + dl * 128 + (phys << 4) + (sl & 7) * 2) =
              f2bf(acc[mi][ni][r] + bv[ni]);
        }
    // intra-wave RAW through LDS; read rows [d][s], store 16B chunks
    const int sc2 = l & 7, srl2 = l >> 3;
    const int rowg = m0 + wm;             // s base (same b for whole quadrant)
#pragma unroll
    for (int i = 0; i < 8; ++i) {
      const int dl = i * 8 + srl2;
      const int phys = sc2 ^ srl2;        // dl&7 == srl2
      u16x8 vrow = *(u16x8*)(wb + dl * 128 + (phys << 4));
      const int colg = n0 + wn + dl;
      u16* dst = (u16*)Cv + ((size_t)((rowg >> 11) << 10) + colg) * 2048 +
                 (rowg & 2047) + sc2 * 8;
      *(u16x8*)dst = vrow;
    }
  }
}

__global__ __launch_bounds__(256, 2)
void proj_kernel(const float* __restrict__ q, const float* __restrict__ k, const float* __restrict__ v,
                 const u16* __restrict__ wqb, const u16* __restrict__ wkb, const u16* __restrict__ wvb,
                 const float* __restrict__ bq, const float* __restrict__ bk, const float* __restrict__ bvv,
                 u16* __restrict__ qh, u16* __restrict__ kh, u16* __restrict__ vt) {
  __shared__ __align__(16) char SM[49152];   // A-fp32 32KB + B 16KB
  // Q gets scale log2(e)/32 so attention scores feed exp2 directly
  if (blockIdx.z == 0)      gemm_body<0, 128, true>(q, wqb, bq, qh, 1.44269504089f / 32.f, SM);
  else if (blockIdx.z == 1) gemm_body<0, 128, true>(k, wkb, bk, kh, 1.0f, SM);
  else                      gemm_body<2, 128, true>(v, wvb, bvv, vt, 1.0f, SM);
}

__global__ __launch_bounds__(256, 2)
void outproj_kernel(const u16* __restrict__ attnb, const u16* __restrict__ wob,
                    const float* __restrict__ bo, float* __restrict__ out) {
  __shared__ __align__(16) char SM[24576];   // As 8KB + Bs 16KB
  gemm_body<1, 64, false>(attnb, wob, bo, out, 1.0f, SM);
}

// ---------------- flash attention: in-register P (swapped QK + row-permuted K)
// grid (32 bh, 16 qt). 4 waves, wave w owns 32 q-rows (2 qh halves).
// QK computed as mfma(K, Q) -> C col = lane = q: each lane's 16 scores are all
// for ONE q-row = the PV A-frag ownership. K-tile staged with row bit-permute
// k = [b5 b3 b2 b4 b1 b0] so lane-local k-quads become the NATURAL contiguous
// mapping kappa(lg,j) = win*32 + lg*8 + j -> V's conflict-free b128 reads match
// unchanged. P = exp2(sfr) built directly into MFMA A-frags; NO P LDS traffic.
__global__ __launch_bounds__(256, 2)
void attn_kernel(const u16* __restrict__ Q, const u16* __restrict__ Kh,
                 const u16* __restrict__ Vt, u16* __restrict__ Ao) {
  constexpr int E = 1024, S = 2048, NT = S / 64;
  const int bh = blockIdx.x, qt = blockIdx.y;
  const int b = bh >> 4, h = bh & 15;
  const int tid = threadIdx.x, w = tid >> 6, l = tid & 63;
  const int lr = l & 15, lg = l >> 4;

  // LDS arena: [0,16K) Ks[2][64][64]  [16K,32K) Vs[2][64][64]
  __shared__ __align__(16) char SM[32768];

  const u16* Qp = Q + (size_t)b * S * E + (size_t)h * 64;
  const u16* Kp = Kh + (size_t)b * S * E + (size_t)h * 64;
  const u16* Vp = Vt + (size_t)bh * 64 * S;   // [d][s]

  const int qbase = qt * 128 + w * 32;
  bf16x8 qa[2][2];
#pragma unroll
  for (int qh = 0; qh < 2; ++qh)
#pragma unroll
    for (int hh = 0; hh < 2; ++hh)
      qa[qh][hh] = *(const bf16x8*)(Qp + (size_t)(qbase + qh * 16 + lr) * E + hh * 32 + lg * 8);

  bf16x8 ones;
#pragma unroll
  for (int j = 0; j < 8; ++j) ones[j] = (__bf16)1.0f;

  f32x4 o_acc[2][4];      // [qh][nf]  : O[q=lg*4+r][d=nf*16+lr]
#pragma unroll
  for (int qh = 0; qh < 2; ++qh)
#pragma unroll
    for (int nf = 0; nf < 4; ++nf) o_acc[qh][nf] = f32x4{0.f, 0.f, 0.f, 0.f};
  f32x4 sum_acc[2] = {f32x4{0.f, 0.f, 0.f, 0.f}, f32x4{0.f, 0.f, 0.f, 0.f}};

  // ---- hoisted loop-invariant LDS byte offsets ----
  const int swz8 = lr & 7;
  int fofs0[4], fofs1[4];            // K/V fragment offsets (same tile geometry)
#pragma unroll
  for (int nf = 0; nf < 4; ++nf) {
    fofs0[nf] = (((nf * 16 + lr) * 64) + (lg ^ swz8) * 8) * 2;
    fofs1[nf] = (((nf * 16 + lr) * 64) + ((4 + lg) ^ swz8) * 8) * 2;
  }

  const int sc = l & 7, srl = l >> 3;
  // K staged-row bit-permute: staged row r' holds global k = [b5 b3 b2 b4 b1 b0]
  auto kperm = [](int r) {
    return (r & 35) | ((r & 12) << 1) | ((r & 16) >> 2);
  };
  auto stageK = [&](int buf, int kb) {
#pragma unroll
    for (int i = 0; i < 2; ++i) {
      const int row = i * 32 + w * 8 + srl;
      const int cp = sc ^ (row & 7);
      gl_lds16(Kp + (size_t)(kb + kperm(row)) * E + cp * 8,
               (u16*)(SM + buf * 8192 + (i * 32 + w * 8) * 128));
    }
  };
  auto stageV = [&](int buf, int kb) {
#pragma unroll
    for (int i = 0; i < 2; ++i) {
      const int row = i * 32 + w * 8 + srl;
      const int cp = sc ^ (row & 7);
      gl_lds16(Vp + (size_t)row * S + kb + cp * 8,
               (u16*)(SM + 16384 + buf * 8192 + (i * 32 + w * 8) * 128));
    }
  };

  stageK(0, 0); stageV(0, 0);
  for (int t = 0; t < NT; ++t) {
    const int cur = t & 1;
    __syncthreads();                           // buf[cur] ready; prior reads drained
    if (t + 1 < NT) { stageK(cur ^ 1, (t + 1) * 64); stageV(cur ^ 1, (t + 1) * 64); }
    const char* Kc = SM + cur * 8192;
    const char* Vc = SM + 16384 + cur * 8192;

    // swapped QK^T: sfr[qh][nf], lane holds S[k'][q = qh*16 + lr]; staged-row
    // permute makes lane-local quads contiguous: k of sfr[nf][r]
    // = (nf>>1)*32 + lg*8 + (nf&1)*4 + r
    f32x4 sfr[2][4];
    __builtin_amdgcn_s_setprio(1);
#pragma unroll
    for (int nf = 0; nf < 4; ++nf) {
      bf16x8 k0 = *(const bf16x8*)(Kc + fofs0[nf]);
      bf16x8 k1 = *(const bf16x8*)(Kc + fofs1[nf]);
#pragma unroll
      for (int qh = 0; qh < 2; ++qh) {
        f32x4 z = f32x4{0.f, 0.f, 0.f, 0.f};
        z = __builtin_amdgcn_mfma_f32_16x16x32_bf16(k0, qa[qh][0], z, 0, 0, 0);
        sfr[qh][nf] = __builtin_amdgcn_mfma_f32_16x16x32_bf16(k1, qa[qh][1], z, 0, 0, 0);
      }
    }
    __builtin_amdgcn_s_setprio(0);

    // P = exp2(s) packed straight into MFMA A-frags (no LDS):
    // pa0[qh] = k-window 0..31 (nf0 elems 0-3, nf1 elems 4-7); pa1 = 32..63
    bf16x8 pa0[2], pa1[2];
#pragma unroll
    for (int qh = 0; qh < 2; ++qh)
#pragma unroll
      for (int r = 0; r < 4; ++r) {
        pa0[qh][r]     = (__bf16)EXP2(sfr[qh][0][r]);
        pa0[qh][4 + r] = (__bf16)EXP2(sfr[qh][1][r]);
        pa1[qh][r]     = (__bf16)EXP2(sfr[qh][2][r]);
        pa1[qh][4 + r] = (__bf16)EXP2(sfr[qh][3][r]);
      }

    // denominators via ones-MFMA (sums all 32 k-slots per window)
#pragma unroll
    for (int qh = 0; qh < 2; ++qh) {
      sum_acc[qh] = __builtin_amdgcn_mfma_f32_16x16x32_bf16(pa0[qh], ones, sum_acc[qh], 0, 0, 0);
      sum_acc[qh] = __builtin_amdgcn_mfma_f32_16x16x32_bf16(pa1[qh], ones, sum_acc[qh], 0, 0, 0);
    }

    // PV: V b128 frags (conflict-free, same fofs), each feeds both qh halves
    __builtin_amdgcn_s_setprio(1);
#pragma unroll
    for (int nf = 0; nf < 4; ++nf) {
      bf16x8 vb0 = *(const bf16x8*)(Vc + fofs0[nf]);
      bf16x8 vb1 = *(const bf16x8*)(Vc + fofs1[nf]);
#pragma unroll
      for (int qh = 0; qh < 2; ++qh) {
        o_acc[qh][nf] = __builtin_amdgcn_mfma_f32_16x16x32_bf16(pa0[qh], vb0, o_acc[qh][nf], 0, 0, 0);
        o_acc[qh][nf] = __builtin_amdgcn_mfma_f32_16x16x32_bf16(pa1[qh], vb1, o_acc[qh][nf], 0, 0, 0);
      }
    }
    __builtin_amdgcn_s_setprio(0);
  }

#pragma unroll
  for (int qh = 0; qh < 2; ++qh)
#pragma unroll
    for (int r = 0; r < 4; ++r) {
      const float inv = 1.0f / sum_acc[qh][r];
      const size_t row = (size_t)b * S + qbase + qh * 16 + lg * 4 + r;
#pragma unroll
      for (int nf = 0; nf < 4; ++nf)
        Ao[row * E + h * 64 + nf * 16 + lr] = f2bf(o_acc[qh][nf][r] * inv);
    }
}

// ---------------- launch ----------------
extern "C" void kernel_launch(void* const* d_in, const int* in_sizes, int n_in,
                              void* d_out, int out_size, void* d_ws, size_t ws_size,
                              hipStream_t stream) {
  const float* q  = (const float*)d_in[0];
  const float* k  = (const float*)d_in[1];
  const float* v  = (const float*)d_in[2];
  const float* Wq = (const float*)d_in[3];
  const float* bq = (const float*)d_in[4];
  const float* Wk = (const float*)d_in[5];
  const float* bk = (const float*)d_in[6];
  const float* Wv = (const float*)d_in[7];
  const float* bv = (const float*)d_in[8];
  const float* Wo = (const float*)d_in[9];
  const float* bo = (const float*)d_in[10];
  float* out = (float*)d_out;

  char* ws = (char*)d_ws;
  u16* attnb = (u16*)(ws);                     // 8MB (attn output, bf16)
  u16* wqb = (u16*)(ws + (24u << 20));         // 1M elems, 2MB each
  u16* wkb = (u16*)(ws + (26u << 20));
  u16* wvb = (u16*)(ws + (28u << 20));
  u16* wob = (u16*)(ws + (30u << 20));
  u16* qhp = (u16*)(ws + (32u << 20));         // 8MB each
  u16* khp = (u16*)(ws + (40u << 20));
  u16* vtp = (u16*)(ws + (48u << 20));         // V^T [b,h,d,s]

  cast_kernel<<<dim3(4096), dim3(256), 0, stream>>>(Wq, Wk, Wv, Wo, wqb, wkb, wvb, wob);
  proj_kernel<<<dim3(32, 8, 3), dim3(256), 0, stream>>>(q, k, v, wqb, wkb, wvb,
                                                        bq, bk, bv, qhp, khp, vtp);
  attn_kernel<<<dim3(32, 16), dim3(256), 0, stream>>>(qhp, khp, vtp, attnb);
  outproj_kernel<<<dim3(64, 8), dim3(256), 0, stream>>>(attnb, wob, bo, out);
}

// Round 17
// 105.176 us; speedup vs baseline: 1.8478x; 1.0008x over previous
//
#include <hip/hip_runtime.h>

// B=2, S=2048, E=1024, HEADS=16, HEAD_SIZE=64
// out = softmax((q Wq^T + bq)(k Wk^T + bk)^T / 32) (v Wv^T + bv) Wo^T + bo

typedef unsigned short u16;
typedef __bf16 bf16x8 __attribute__((ext_vector_type(8)));
typedef float f32x4 __attribute__((ext_vector_type(4)));
typedef u16 u16x4 __attribute__((ext_vector_type(4)));
typedef u16 u16x8 __attribute__((ext_vector_type(8)));

typedef __attribute__((address_space(1))) const unsigned int as1_cu32;
typedef __attribute__((address_space(3))) unsigned int as3_u32;

#if __has_builtin(__builtin_amdgcn_exp2f)
#define EXP2(x) __builtin_amdgcn_exp2f(x)   // raw v_exp_f32 (inputs are normal-range)
#else
#define EXP2(x) exp2f(x)
#endif

__device__ __forceinline__ u16 f2bf(float f) {
  unsigned u = __builtin_bit_cast(unsigned, f);
  u += 0x7fffu + ((u >> 16) & 1u);   // RTNE
  return (u16)(u >> 16);
}

__device__ __forceinline__ u16 bfc(float f) {   // RTNE via v_cvt (same bits as f2bf)
  return __builtin_bit_cast(u16, (__bf16)f);
}

__device__ __forceinline__ void gl_lds16(const u16* g, u16* l) {
  // async global->LDS, 16B/lane; LDS dest = wave-uniform base + lane*16
  __builtin_amdgcn_global_load_lds((as1_cu32*)g, (as3_u32*)l, 16, 0, 0);
}

// ---------------- fp32 -> bf16 cast (4 weight matrices only) ----------------
__global__ void cast_kernel(const float* __restrict__ wq, const float* __restrict__ wk,
                            const float* __restrict__ wv, const float* __restrict__ wo,
                            u16* __restrict__ wqb, u16* __restrict__ wkb,
                            u16* __restrict__ wvb, u16* __restrict__ wob) {
  unsigned t = blockIdx.x * 256u + threadIdx.x;  // 1M float4 = 4 x 256K
  unsigned which = t >> 18, off = t & 262143u;
  const float* src = which == 0 ? wq : (which == 1 ? wk : (which == 2 ? wv : wo));
  u16* dst = which == 0 ? wqb : (which == 1 ? wkb : (which == 2 ? wvb : wob));
  float4 f = ((const float4*)src)[off];
  u16x4 o;
  o[0] = f2bf(f.x); o[1] = f2bf(f.y); o[2] = f2bf(f.z); o[3] = f2bf(f.w);
  ((u16x4*)dst)[off] = o;
}

// ---------------- NT GEMM: C = scale*(A B^T + bias) ----------------
// BM x 128 tile, BK=32, 4 waves, 16x16x32 MFMA, dbuf LDS (bf16 layout).
// AREG: A source is fp32; staged via regs (dwordx4 loads issued early, RTNE
// cvt to bf16, ds_write_b128 late) into the SAME bf16 LDS layout.
// MODE: 0 = bf16 row-major out, 1 = f32 row-major out,
// MODE 2 = bf16 V^T out [b,h,d,s] via LDS transpose + coalesced 16B stores.
template <int MODE, int BM, bool AREG>
__device__ __forceinline__ void gemm_body(const void* __restrict__ Av, const u16* __restrict__ B,
                                          const float* __restrict__ bias, void* __restrict__ Cv,
                                          float scale, char* SMraw) {
  constexpr int MI = BM / 32;                              // M frags per wave
  constexpr int ABUF = BM * 64;                            // bytes per A buffer (bf16)
  char* ASM = SMraw;
  char* BSM = SMraw + 2 * ABUF;                            // [2][128][64B]
  constexpr int N = 1024, NK = 32;
  const int m0 = blockIdx.x * BM;
  const int n0 = blockIdx.y * 128;
  const int tid = threadIdx.x;
  const int w = tid >> 6, l = tid & 63;
  const int lr = l & 15, lg = l >> 4;
  const int wm = (w >> 1) * (BM / 2), wn = (w & 1) * 64;

  auto stageB = [&](int buf, int kt) {
#pragma unroll
    for (int i = 0; i < 2; ++i) {
      const int r0 = i * 64 + w * 16;
      gl_lds16(B + (size_t)(n0 + r0 + (l >> 2)) * 1024 + kt * 32 + (l & 3) * 8,
               (u16*)(BSM + buf * 8192 + r0 * 64));
    }
  };
  auto stageA_dma = [&](int buf, int kt) {   // bf16 A source (outproj)
    const u16* A = (const u16*)Av;
#pragma unroll
    for (int i = 0; i < BM / 64; ++i) {
      const int r0 = i * 64 + w * 16;
      gl_lds16(A + (size_t)(m0 + r0 + (l >> 2)) * 1024 + kt * 32 + (l & 3) * 8,
               (u16*)(ASM + buf * ABUF + r0 * 64));
    }
  };
  // fp32 A: issue loads early...
  f32x4 ar[BM / 64][2];
  auto stageA_load = [&](int kt) {
    const float* A = (const float*)Av;
#pragma unroll
    for (int i = 0; i < BM / 64; ++i) {
      const float* src = A + (size_t)(m0 + i * 64 + w * 16 + (l >> 2)) * 1024 + kt * 32 + (l & 3) * 8;
      ar[i][0] = *(const f32x4*)src;
      ar[i][1] = *(const f32x4*)(src + 4);
    }
  };
  // ...convert + write late (same linear bf16 layout gl_lds would produce)
  auto stageA_write = [&](int buf) {
#pragma unroll
    for (int i = 0; i < BM / 64; ++i) {
      u16x8 v;
#pragma unroll
      for (int j = 0; j < 4; ++j) { v[j] = bfc(ar[i][0][j]); v[4 + j] = bfc(ar[i][1][j]); }
      *(u16x8*)(ASM + buf * ABUF + (i * 64 + w * 16 + (l >> 2)) * 64 + (l & 3) * 16) = v;
    }
  };

  f32x4 acc[MI][4];
#pragma unroll
  for (int i = 0; i < MI; ++i)
#pragma unroll
    for (int j = 0; j < 4; ++j) acc[i][j] = f32x4{0.f, 0.f, 0.f, 0.f};

  if constexpr (AREG) { stageA_load(0); stageA_write(0); }
  else                stageA_dma(0, 0);
  stageB(0, 0);

  for (int kt = 0; kt < NK; ++kt) {
    const int buf = kt & 1;
    __syncthreads();
    if (kt + 1 < NK) {
      if constexpr (AREG) stageA_load(kt + 1);   // issue early; HBM/L2 latency
      else                stageA_dma(buf ^ 1, kt + 1);
      stageB(buf ^ 1, kt + 1);
    }
    bf16x8 af[MI], bfr[4];
#pragma unroll
    for (int i = 0; i < MI; ++i)
      af[i] = *(const bf16x8*)(ASM + buf * ABUF + (wm + i * 16 + lr) * 64 + lg * 16);
#pragma unroll
    for (int i = 0; i < 4; ++i)
      bfr[i] = *(const bf16x8*)(BSM + buf * 8192 + (wn + i * 16 + lr) * 64 + lg * 16);
#pragma unroll
    for (int mi = 0; mi < MI; ++mi)
#pragma unroll
      for (int ni = 0; ni < 4; ++ni)
        acc[mi][ni] = __builtin_amdgcn_mfma_f32_16x16x32_bf16(af[mi], bfr[ni], acc[mi][ni], 0, 0, 0);
    if (kt + 1 < NK) {
      if constexpr (AREG) stageA_write(buf ^ 1);  // write late, under MFMA shadow
    }
  }

  float bv[4];
#pragma unroll
  for (int ni = 0; ni < 4; ++ni) bv[ni] = bias[n0 + wn + ni * 16 + lr];

  if constexpr (MODE != 2) {
#pragma unroll
    for (int mi = 0; mi < MI; ++mi)
#pragma unroll
      for (int ni = 0; ni < 4; ++ni)
#pragma unroll
        for (int r = 0; r < 4; ++r) {
          const int row = m0 + wm + mi * 16 + lg * 4 + r;
          const int col = n0 + wn + ni * 16 + lr;
          float vv = (acc[mi][ni][r] + bv[ni]) * scale;
          if constexpr (MODE == 1) ((float*)Cv)[(size_t)row * N + col] = vv;
          else                     ((u16*)Cv)[(size_t)row * N + col] = f2bf(vv);
        }
  } else {
    // V^T epilogue: transpose 64x64 wave quadrant through LDS (reuse arena),
    // then coalesced 16B stores (8 lanes cover one contiguous 128B d-row).
    __syncthreads();                      // all waves done reading As/Bs
    char* wb = SMraw + w * 8192;          // per-wave [64 d][64 s] bf16, 128B rows
#pragma unroll
    for (int mi = 0; mi < MI; ++mi)
#pragma unroll
      for (int ni = 0; ni < 4; ++ni)
#pragma unroll
        for (int r = 0; r < 4; ++r) {
          const int dl = ni * 16 + lr;
          const int sl = mi * 16 + lg * 4 + r;
          const int phys = (sl >> 3) ^ (lr & 7);   // chunk-XOR keyed by d&7
          *(u16*)(wb + dl * 128 + (phys << 4) + (sl & 7) * 2) =
              f2bf(acc[mi][ni][r] + bv[ni]);
        }
    // intra-wave RAW through LDS; read rows [d][s], store 16B chunks
    const int sc2 = l & 7, srl2 = l >> 3;
    const int rowg = m0 + wm;             // s base (same b for whole quadrant)
#pragma unroll
    for (int i = 0; i < 8; ++i) {
      const int dl = i * 8 + srl2;
      const int phys = sc2 ^ srl2;        // dl&7 == srl2
      u16x8 vrow = *(u16x8*)(wb + dl * 128 + (phys << 4));
      const int colg = n0 + wn + dl;
      u16* dst = (u16*)Cv + ((size_t)((rowg >> 11) << 10) + colg) * 2048 +
                 (rowg & 2047) + sc2 * 8;
      *(u16x8*)dst = vrow;
    }
  }
}

__global__ __launch_bounds__(256, 2)
void proj_kernel(const float* __restrict__ q, const float* __restrict__ k, const float* __restrict__ v,
                 const u16* __restrict__ wqb, const u16* __restrict__ wkb, const u16* __restrict__ wvb,
                 const float* __restrict__ bq, const float* __restrict__ bk, const float* __restrict__ bvv,
                 u16* __restrict__ qh, u16* __restrict__ kh, u16* __restrict__ vt) {
  __shared__ __align__(16) char SM[32768];   // A bf16 16KB + B 16KB
  // Q gets scale log2(e)/32 so attention scores feed exp2 directly
  if (blockIdx.z == 0)      gemm_body<0, 128, true>(q, wqb, bq, qh, 1.44269504089f / 32.f, SM);
  else if (blockIdx.z == 1) gemm_body<0, 128, true>(k, wkb, bk, kh, 1.0f, SM);
  else                      gemm_body<2, 128, true>(v, wvb, bvv, vt, 1.0f, SM);
}

__global__ __launch_bounds__(256, 2)
void outproj_kernel(const u16* __restrict__ attnb, const u16* __restrict__ wob,
                    const float* __restrict__ bo, float* __restrict__ out) {
  __shared__ __align__(16) char SM[24576];   // As 8KB + Bs 16KB
  gemm_body<1, 64, false>(attnb, wob, bo, out, 1.0f, SM);
}

// ---------------- flash attention: in-register P (swapped QK + row-permuted K)
// grid (32 bh, 16 qt). 4 waves, wave w owns 32 q-rows (2 qh halves).
// QK computed as mfma(K, Q) -> C col = lane = q: each lane's 16 scores are all
// for ONE q-row = the PV A-frag ownership. K-tile staged with row bit-permute
// k = [b5 b3 b2 b4 b1 b0] so lane-local k-quads become the NATURAL contiguous
// mapping kappa(lg,j) = win*32 + lg*8 + j -> V's conflict-free b128 reads match
// unchanged. P = exp2(sfr) built directly into MFMA A-frags; NO P LDS traffic.
__global__ __launch_bounds__(256, 2)
void attn_kernel(const u16* __restrict__ Q, const u16* __restrict__ Kh,
                 const u16* __restrict__ Vt, u16* __restrict__ Ao) {
  constexpr int E = 1024, S = 2048, NT = S / 64;
  const int bh = blockIdx.x, qt = blockIdx.y;
  const int b = bh >> 4, h = bh & 15;
  const int tid = threadIdx.x, w = tid >> 6, l = tid & 63;
  const int lr = l & 15, lg = l >> 4;

  // LDS arena: [0,16K) Ks[2][64][64]  [16K,32K) Vs[2][64][64]
  __shared__ __align__(16) char SM[32768];

  const u16* Qp = Q + (size_t)b * S * E + (size_t)h * 64;
  const u16* Kp = Kh + (size_t)b * S * E + (size_t)h * 64;
  const u16* Vp = Vt + (size_t)bh * 64 * S;   // [d][s]

  const int qbase = qt * 128 + w * 32;
  bf16x8 qa[2][2];
#pragma unroll
  for (int qh = 0; qh < 2; ++qh)
#pragma unroll
    for (int hh = 0; hh < 2; ++hh)
      qa[qh][hh] = *(const bf16x8*)(Qp + (size_t)(qbase + qh * 16 + lr) * E + hh * 32 + lg * 8);

  bf16x8 ones;
#pragma unroll
  for (int j = 0; j < 8; ++j) ones[j] = (__bf16)1.0f;

  f32x4 o_acc[2][4];      // [qh][nf]  : O[q=lg*4+r][d=nf*16+lr]
#pragma unroll
  for (int qh = 0; qh < 2; ++qh)
#pragma unroll
    for (int nf = 0; nf < 4; ++nf) o_acc[qh][nf] = f32x4{0.f, 0.f, 0.f, 0.f};
  f32x4 sum_acc[2] = {f32x4{0.f, 0.f, 0.f, 0.f}, f32x4{0.f, 0.f, 0.f, 0.f}};

  // ---- hoisted loop-invariant LDS byte offsets ----
  const int swz8 = lr & 7;
  int fofs0[4], fofs1[4];            // K/V fragment offsets (same tile geometry)
#pragma unroll
  for (int nf = 0; nf < 4; ++nf) {
    fofs0[nf] = (((nf * 16 + lr) * 64) + (lg ^ swz8) * 8) * 2;
    fofs1[nf] = (((nf * 16 + lr) * 64) + ((4 + lg) ^ swz8) * 8) * 2;
  }

  const int sc = l & 7, srl = l >> 3;
  // K staged-row bit-permute: staged row r' holds global k = [b5 b3 b2 b4 b1 b0]
  auto kperm = [](int r) {
    return (r & 35) | ((r & 12) << 1) | ((r & 16) >> 2);
  };
  auto stageK = [&](int buf, int kb) {
#pragma unroll
    for (int i = 0; i < 2; ++i) {
      const int row = i * 32 + w * 8 + srl;
      const int cp = sc ^ (row & 7);
      gl_lds16(Kp + (size_t)(kb + kperm(row)) * E + cp * 8,
               (u16*)(SM + buf * 8192 + (i * 32 + w * 8) * 128));
    }
  };
  auto stageV = [&](int buf, int kb) {
#pragma unroll
    for (int i = 0; i < 2; ++i) {
      const int row = i * 32 + w * 8 + srl;
      const int cp = sc ^ (row & 7);
      gl_lds16(Vp + (size_t)row * S + kb + cp * 8,
               (u16*)(SM + 16384 + buf * 8192 + (i * 32 + w * 8) * 128));
    }
  };

  stageK(0, 0); stageV(0, 0);
  for (int t = 0; t < NT; ++t) {
    const int cur = t & 1;
    __syncthreads();                           // buf[cur] ready; prior reads drained
    if (t + 1 < NT) { stageK(cur ^ 1, (t + 1) * 64); stageV(cur ^ 1, (t + 1) * 64); }
    const char* Kc = SM + cur * 8192;
    const char* Vc = SM + 16384 + cur * 8192;

    // swapped QK^T: sfr[qh][nf], lane holds S[k'][q = qh*16 + lr]; staged-row
    // permute makes lane-local quads contiguous: k of sfr[nf][r]
    // = (nf>>1)*32 + lg*8 + (nf&1)*4 + r
    f32x4 sfr[2][4];
    __builtin_amdgcn_s_setprio(1);
#pragma unroll
    for (int nf = 0; nf < 4; ++nf) {
      bf16x8 k0 = *(const bf16x8*)(Kc + fofs0[nf]);
      bf16x8 k1 = *(const bf16x8*)(Kc + fofs1[nf]);
#pragma unroll
      for (int qh = 0; qh < 2; ++qh) {
        f32x4 z = f32x4{0.f, 0.f, 0.f, 0.f};
        z = __builtin_amdgcn_mfma_f32_16x16x32_bf16(k0, qa[qh][0], z, 0, 0, 0);
        sfr[qh][nf] = __builtin_amdgcn_mfma_f32_16x16x32_bf16(k1, qa[qh][1], z, 0, 0, 0);
      }
    }
    __builtin_amdgcn_s_setprio(0);

    // P = exp2(s) packed straight into MFMA A-frags (no LDS):
    // pa0[qh] = k-window 0..31 (nf0 elems 0-3, nf1 elems 4-7); pa1 = 32..63
    bf16x8 pa0[2], pa1[2];
#pragma unroll
    for (int qh = 0; qh < 2; ++qh)
#pragma unroll
      for (int r = 0; r < 4; ++r) {
        pa0[qh][r]     = (__bf16)EXP2(sfr[qh][0][r]);
        pa0[qh][4 + r] = (__bf16)EXP2(sfr[qh][1][r]);
        pa1[qh][r]     = (__bf16)EXP2(sfr[qh][2][r]);
        pa1[qh][4 + r] = (__bf16)EXP2(sfr[qh][3][r]);
      }

    // denominators via ones-MFMA (sums all 32 k-slots per window)
#pragma unroll
    for (int qh = 0; qh < 2; ++qh) {
      sum_acc[qh] = __builtin_amdgcn_mfma_f32_16x16x32_bf16(pa0[qh], ones, sum_acc[qh], 0, 0, 0);
      sum_acc[qh] = __builtin_amdgcn_mfma_f32_16x16x32_bf16(pa1[qh], ones, sum_acc[qh], 0, 0, 0);
    }

    // PV: V b128 frags (conflict-free, same fofs), each feeds both qh halves
    __builtin_amdgcn_s_setprio(1);
#pragma unroll
    for (int nf = 0; nf < 4; ++nf) {
      bf16x8 vb0 = *(const bf16x8*)(Vc + fofs0[nf]);
      bf16x8 vb1 = *(const bf16x8*)(Vc + fofs1[nf]);
#pragma unroll
      for (int qh = 0; qh < 2; ++qh) {
        o_acc[qh][nf] = __builtin_amdgcn_mfma_f32_16x16x32_bf16(pa0[qh], vb0, o_acc[qh][nf], 0, 0, 0);
        o_acc[qh][nf] = __builtin_amdgcn_mfma_f32_16x16x32_bf16(pa1[qh], vb1, o_acc[qh][nf], 0, 0, 0);
      }
    }
    __builtin_amdgcn_s_setprio(0);
  }

#pragma unroll
  for (int qh = 0; qh < 2; ++qh)
#pragma unroll
    for (int r = 0; r < 4; ++r) {
      const float inv = 1.0f / sum_acc[qh][r];
      const size_t row = (size_t)b * S + qbase + qh * 16 + lg * 4 + r;
#pragma unroll
      for (int nf = 0; nf < 4; ++nf)
        Ao[row * E + h * 64 + nf * 16 + lr] = f2bf(o_acc[qh][nf][r] * inv);
    }
}

// ---------------- launch ----------------
extern "C" void kernel_launch(void* const* d_in, const int* in_sizes, int n_in,
                              void* d_out, int out_size, void* d_ws, size_t ws_size,
                              hipStream_t stream) {
  const float* q  = (const float*)d_in[0];
  const float* k  = (const float*)d_in[1];
  const float* v  = (const float*)d_in[2];
  const float* Wq = (const float*)d_in[3];
  const float* bq = (const float*)d_in[4];
  const float* Wk = (const float*)d_in[5];
  const float* bk = (const float*)d_in[6];
  const float* Wv = (const float*)d_in[7];
  const float* bv = (const float*)d_in[8];
  const float* Wo = (const float*)d_in[9];
  const float* bo = (const float*)d_in[10];
  float* out = (float*)d_out;

  char* ws = (char*)d_ws;
  u16* attnb = (u16*)(ws);                     // 8MB (attn output, bf16)
  u16* wqb = (u16*)(ws + (24u << 20));         // 1M elems, 2MB each
  u16* wkb = (u16*)(ws + (26u << 20));
  u16* wvb = (u16*)(ws + (28u << 20));
  u16* wob = (u16*)(ws + (30u << 20));
  u16* qhp = (u16*)(ws + (32u << 20));         // 8MB each
  u16* khp = (u16*)(ws + (40u << 20));
  u16* vtp = (u16*)(ws + (48u << 20));         // V^T [b,h,d,s]

  cast_kernel<<<dim3(4096), dim3(256), 0, stream>>>(Wq, Wk, Wv, Wo, wqb, wkb, wvb, wob);
  proj_kernel<<<dim3(32, 8, 3), dim3(256), 0, stream>>>(q, k, v, wqb, wkb, wvb,
                                                        bq, bk, bv, qhp, khp, vtp);
  attn_kernel<<<dim3(32, 16), dim3(256), 0, stream>>>(qhp, khp, vtp, attnb);
  outproj_kernel<<<dim3(64, 8), dim3(256), 0, stream>>>(attnb, wob, bo, out);
}

// Round 18
// 104.243 us; speedup vs baseline: 1.8643x; 1.0090x over previous
//
#include <hip/hip_runtime.h>

// B=2, S=2048, E=1024, HEADS=16, HEAD_SIZE=64
// out = softmax((q Wq^T + bq)(k Wk^T + bk)^T / 32) (v Wv^T + bv) Wo^T + bo

typedef unsigned short u16;
typedef __bf16 bf16x8 __attribute__((ext_vector_type(8)));
typedef float f32x4 __attribute__((ext_vector_type(4)));
typedef u16 u16x4 __attribute__((ext_vector_type(4)));
typedef u16 u16x8 __attribute__((ext_vector_type(8)));

typedef __attribute__((address_space(1))) const unsigned int as1_cu32;
typedef __attribute__((address_space(3))) unsigned int as3_u32;

#if __has_builtin(__builtin_amdgcn_exp2f)
#define EXP2(x) __builtin_amdgcn_exp2f(x)   // raw v_exp_f32 (inputs are normal-range)
#else
#define EXP2(x) exp2f(x)
#endif

__device__ __forceinline__ u16 f2bf(float f) {
  unsigned u = __builtin_bit_cast(unsigned, f);
  u += 0x7fffu + ((u >> 16) & 1u);   // RTNE
  return (u16)(u >> 16);
}

__device__ __forceinline__ u16 bfc(float f) {   // RTNE via v_cvt (same bits as f2bf)
  return __builtin_bit_cast(u16, (__bf16)f);
}

__device__ __forceinline__ void gl_lds16(const u16* g, u16* l) {
  // async global->LDS, 16B/lane; LDS dest = wave-uniform base + lane*16
  __builtin_amdgcn_global_load_lds((as1_cu32*)g, (as3_u32*)l, 16, 0, 0);
}

// GEMM tile layout (bank-conflict-free): logical [R rows][32 k] bf16 packed as
// [R/2 LDS rows][128B]; LDS row j = global rows {2j, 2j+1}, 8 x 16B chunks,
// phys_chunk = ((grow&1)*4 + kchunk) ^ (j&7).  Frag/stage access = 2-way max.
__device__ __forceinline__ int tofs(int grow, int kchunk) {
  const int j = grow >> 1;
  return j * 128 + ((((grow & 1) * 4 + kchunk) ^ (j & 7)) << 4);
}

// ---------------- fp32 -> bf16 cast (4 weight matrices only) ----------------
__global__ void cast_kernel(const float* __restrict__ wq, const float* __restrict__ wk,
                            const float* __restrict__ wv, const float* __restrict__ wo,
                            u16* __restrict__ wqb, u16* __restrict__ wkb,
                            u16* __restrict__ wvb, u16* __restrict__ wob) {
  unsigned t = blockIdx.x * 256u + threadIdx.x;  // 1M float4 = 4 x 256K
  unsigned which = t >> 18, off = t & 262143u;
  const float* src = which == 0 ? wq : (which == 1 ? wk : (which == 2 ? wv : wo));
  u16* dst = which == 0 ? wqb : (which == 1 ? wkb : (which == 2 ? wvb : wob));
  float4 f = ((const float4*)src)[off];
  u16x4 o;
  o[0] = f2bf(f.x); o[1] = f2bf(f.y); o[2] = f2bf(f.z); o[3] = f2bf(f.w);
  ((u16x4*)dst)[off] = o;
}

// ---------------- NT GEMM: C = scale*(A B^T + bias) ----------------
// BM x 128 tile, BK=32, 4 waves, 16x16x32 MFMA, dbuf LDS (swizzled layout).
// AREG: A source is fp32; staged via regs (dwordx4 loads issued early, RTNE
// cvt to bf16, ds_write_b128 late) into the swizzled layout.
// MODE: 0 = bf16 row-major out, 1 = f32 row-major out,
// MODE 2 = bf16 V^T out [b,h,d,s] via LDS transpose + coalesced 16B stores.
template <int MODE, int BM, bool AREG>
__device__ __forceinline__ void gemm_body(const void* __restrict__ Av, const u16* __restrict__ B,
                                          const float* __restrict__ bias, void* __restrict__ Cv,
                                          float scale, char* SMraw) {
  constexpr int MI = BM / 32;                              // M frags per wave
  constexpr int ABUF = BM * 64;                            // bytes per A buffer (bf16)
  char* ASM = SMraw;
  char* BSM = SMraw + 2 * ABUF;                            // [2][8KB]
  constexpr int N = 1024, NK = 32;
  const int m0 = blockIdx.x * BM;
  const int n0 = blockIdx.y * 128;
  const int tid = threadIdx.x;
  const int w = tid >> 6, l = tid & 63;
  const int lr = l & 15, lg = l >> 4;
  const int wm = (w >> 1) * (BM / 2), wn = (w & 1) * 64;

  // DMA staging: linear 1KB per wave-issue; source pre-swizzled (inverse map)
  const int jof = l >> 3, pc = l & 7;
  auto stage_dma = [&](char* dstbase, const u16* Op, int o0, int r0, int kt) {
    const int j = (r0 >> 1) + jof;
    const int lc = pc ^ (j & 7);
    const int g = 2 * j + (lc >> 2);
    gl_lds16(Op + (size_t)(o0 + g) * 1024 + kt * 32 + (lc & 3) * 8,
             (u16*)(dstbase + (r0 >> 1) * 128));
  };
  auto stageB = [&](int buf, int kt) {
#pragma unroll
    for (int i = 0; i < 2; ++i)
      stage_dma(BSM + buf * 8192, B, n0, i * 64 + w * 16, kt);
  };
  auto stageA_dma = [&](int buf, int kt) {   // bf16 A source (outproj)
#pragma unroll
    for (int i = 0; i < BM / 64; ++i)
      stage_dma(ASM + buf * ABUF, (const u16*)Av, m0, i * 64 + w * 16, kt);
  };
  // fp32 A: issue loads early...
  f32x4 ar[BM / 64][2];
  auto stageA_load = [&](int kt) {
    const float* A = (const float*)Av;
#pragma unroll
    for (int i = 0; i < BM / 64; ++i) {
      const float* src = A + (size_t)(m0 + i * 64 + w * 16 + (l >> 2)) * 1024 + kt * 32 + (l & 3) * 8;
      ar[i][0] = *(const f32x4*)src;
      ar[i][1] = *(const f32x4*)(src + 4);
    }
  };
  // ...convert + write late into the swizzled layout
  auto stageA_write = [&](int buf) {
#pragma unroll
    for (int i = 0; i < BM / 64; ++i) {
      u16x8 v;
#pragma unroll
      for (int j = 0; j < 4; ++j) { v[j] = bfc(ar[i][0][j]); v[4 + j] = bfc(ar[i][1][j]); }
      *(u16x8*)(ASM + buf * ABUF + tofs(i * 64 + w * 16 + (l >> 2), l & 3)) = v;
    }
  };

  // hoisted frag byte-offsets (kchunk = lg)
  int afo[MI], bfo[4];
#pragma unroll
  for (int i = 0; i < MI; ++i) afo[i] = tofs(wm + i * 16 + lr, lg);
#pragma unroll
  for (int i = 0; i < 4; ++i) bfo[i] = tofs(wn + i * 16 + lr, lg);

  f32x4 acc[MI][4];
#pragma unroll
  for (int i = 0; i < MI; ++i)
#pragma unroll
    for (int j = 0; j < 4; ++j) acc[i][j] = f32x4{0.f, 0.f, 0.f, 0.f};

  if constexpr (AREG) { stageA_load(0); stageA_write(0); }
  else                stageA_dma(0, 0);
  stageB(0, 0);

  for (int kt = 0; kt < NK; ++kt) {
    const int buf = kt & 1;
    __syncthreads();
    if (kt + 1 < NK) {
      if constexpr (AREG) stageA_load(kt + 1);   // issue early; HBM/L2 latency
      else                stageA_dma(buf ^ 1, kt + 1);
      stageB(buf ^ 1, kt + 1);
    }
    bf16x8 af[MI], bfr[4];
#pragma unroll
    for (int i = 0; i < MI; ++i)
      af[i] = *(const bf16x8*)(ASM + buf * ABUF + afo[i]);
#pragma unroll
    for (int i = 0; i < 4; ++i)
      bfr[i] = *(const bf16x8*)(BSM + buf * 8192 + bfo[i]);
#pragma unroll
    for (int mi = 0; mi < MI; ++mi)
#pragma unroll
      for (int ni = 0; ni < 4; ++ni)
        acc[mi][ni] = __builtin_amdgcn_mfma_f32_16x16x32_bf16(af[mi], bfr[ni], acc[mi][ni], 0, 0, 0);
    if (kt + 1 < NK) {
      if constexpr (AREG) stageA_write(buf ^ 1);  // write late, under MFMA shadow
    }
  }

  float bv[4];
#pragma unroll
  for (int ni = 0; ni < 4; ++ni) bv[ni] = bias[n0 + wn + ni * 16 + lr];

  if constexpr (MODE != 2) {
#pragma unroll
    for (int mi = 0; mi < MI; ++mi)
#pragma unroll
      for (int ni = 0; ni < 4; ++ni)
#pragma unroll
        for (int r = 0; r < 4; ++r) {
          const int row = m0 + wm + mi * 16 + lg * 4 + r;
          const int col = n0 + wn + ni * 16 + lr;
          float vv = (acc[mi][ni][r] + bv[ni]) * scale;
          if constexpr (MODE == 1) ((float*)Cv)[(size_t)row * N + col] = vv;
          else                     ((u16*)Cv)[(size_t)row * N + col] = f2bf(vv);
        }
  } else {
    // V^T epilogue: transpose 64x64 wave quadrant through LDS (reuse arena),
    // then coalesced 16B stores (8 lanes cover one contiguous 128B d-row).
    __syncthreads();                      // all waves done reading As/Bs
    char* wb = SMraw + w * 8192;          // per-wave [64 d][64 s] bf16, 128B rows
#pragma unroll
    for (int mi = 0; mi < MI; ++mi)
#pragma unroll
      for (int ni = 0; ni < 4; ++ni)
#pragma unroll
        for (int r = 0; r < 4; ++r) {
          const int dl = ni * 16 + lr;
          const int sl = mi * 16 + lg * 4 + r;
          const int phys = (sl >> 3) ^ (lr & 7);   // chunk-XOR keyed by d&7
          *(u16*)(wb + dl * 128 + (phys << 4) + (sl & 7) * 2) =
              f2bf(acc[mi][ni][r] + bv[ni]);
        }
    // intra-wave RAW through LDS; read rows [d][s], store 16B chunks
    const int sc2 = l & 7, srl2 = l >> 3;
    const int rowg = m0 + wm;             // s base (same b for whole quadrant)
#pragma unroll
    for (int i = 0; i < 8; ++i) {
      const int dl = i * 8 + srl2;
      const int phys = sc2 ^ srl2;        // dl&7 == srl2
      u16x8 vrow = *(u16x8*)(wb + dl * 128 + (phys << 4));
      const int colg = n0 + wn + dl;
      u16* dst = (u16*)Cv + ((size_t)((rowg >> 11) << 10) + colg) * 2048 +
                 (rowg & 2047) + sc2 * 8;
      *(u16x8*)dst = vrow;
    }
  }
}

__global__ __launch_bounds__(256, 2)
void proj_kernel(const float* __restrict__ q, const float* __restrict__ k, const float* __restrict__ v,
                 const u16* __restrict__ wqb, const u16* __restrict__ wkb, const u16* __restrict__ wvb,
                 const float* __restrict__ bq, const float* __restrict__ bk, const float* __restrict__ bvv,
                 u16* __restrict__ qh, u16* __restrict__ kh, u16* __restrict__ vt) {
  __shared__ __align__(16) char SM[32768];   // A bf16 16KB + B 16KB
  // Q gets scale log2(e)/32 so attention scores feed exp2 directly
  if (blockIdx.z == 0)      gemm_body<0, 128, true>(q, wqb, bq, qh, 1.44269504089f / 32.f, SM);
  else if (blockIdx.z == 1) gemm_body<0, 128, true>(k, wkb, bk, kh, 1.0f, SM);
  else                      gemm_body<2, 128, true>(v, wvb, bvv, vt, 1.0f, SM);
}

__global__ __launch_bounds__(256, 2)
void outproj_kernel(const u16* __restrict__ attnb, const u16* __restrict__ wob,
                    const float* __restrict__ bo, float* __restrict__ out) {
  __shared__ __align__(16) char SM[24576];   // As 8KB + Bs 16KB
  gemm_body<1, 64, false>(attnb, wob, bo, out, 1.0f, SM);
}

// ---------------- flash attention: in-register P (swapped QK + row-permuted K)
// grid (32 bh, 16 qt). 4 waves, wave w owns 32 q-rows (2 qh halves).
// QK computed as mfma(K, Q) -> C col = lane = q: each lane's 16 scores are all
// for ONE q-row = the PV A-frag ownership. K-tile staged with row bit-permute
// k = [b5 b3 b2 b4 b1 b0] so lane-local k-quads become the NATURAL contiguous
// mapping kappa(lg,j) = win*32 + lg*8 + j -> V's conflict-free b128 reads match
// unchanged. P = exp2(sfr) built directly into MFMA A-frags; NO P LDS traffic.
__global__ __launch_bounds__(256, 2)
void attn_kernel(const u16* __restrict__ Q, const u16* __restrict__ Kh,
                 const u16* __restrict__ Vt, u16* __restrict__ Ao) {
  constexpr int E = 1024, S = 2048, NT = S / 64;
  const int bh = blockIdx.x, qt = blockIdx.y;
  const int b = bh >> 4, h = bh & 15;
  const int tid = threadIdx.x, w = tid >> 6, l = tid & 63;
  const int lr = l & 15, lg = l >> 4;

  // LDS arena: [0,16K) Ks[2][64][64]  [16K,32K) Vs[2][64][64]
  __shared__ __align__(16) char SM[32768];

  const u16* Qp = Q + (size_t)b * S * E + (size_t)h * 64;
  const u16* Kp = Kh + (size_t)b * S * E + (size_t)h * 64;
  const u16* Vp = Vt + (size_t)bh * 64 * S;   // [d][s]

  const int qbase = qt * 128 + w * 32;
  bf16x8 qa[2][2];
#pragma unroll
  for (int qh = 0; qh < 2; ++qh)
#pragma unroll
    for (int hh = 0; hh < 2; ++hh)
      qa[qh][hh] = *(const bf16x8*)(Qp + (size_t)(qbase + qh * 16 + lr) * E + hh * 32 + lg * 8);

  bf16x8 ones;
#pragma unroll
  for (int j = 0; j < 8; ++j) ones[j] = (__bf16)1.0f;

  f32x4 o_acc[2][4];      // [qh][nf]  : O[q=lg*4+r][d=nf*16+lr]
#pragma unroll
  for (int qh = 0; qh < 2; ++qh)
#pragma unroll
    for (int nf = 0; nf < 4; ++nf) o_acc[qh][nf] = f32x4{0.f, 0.f, 0.f, 0.f};
  f32x4 sum_acc[2] = {f32x4{0.f, 0.f, 0.f, 0.f}, f32x4{0.f, 0.f, 0.f, 0.f}};

  // ---- hoisted loop-invariant LDS byte offsets ----
  const int swz8 = lr & 7;
  int fofs0[4], fofs1[4];            // K/V fragment offsets (same tile geometry)
#pragma unroll
  for (int nf = 0; nf < 4; ++nf) {
    fofs0[nf] = (((nf * 16 + lr) * 64) + (lg ^ swz8) * 8) * 2;
    fofs1[nf] = (((nf * 16 + lr) * 64) + ((4 + lg) ^ swz8) * 8) * 2;
  }

  const int sc = l & 7, srl = l >> 3;
  // K staged-row bit-permute: staged row r' holds global k = [b5 b3 b2 b4 b1 b0]
  auto kperm = [](int r) {
    return (r & 35) | ((r & 12) << 1) | ((r & 16) >> 2);
  };
  auto stageK = [&](int buf, int kb) {
#pragma unroll
    for (int i = 0; i < 2; ++i) {
      const int row = i * 32 + w * 8 + srl;
      const int cp = sc ^ (row & 7);
      gl_lds16(Kp + (size_t)(kb + kperm(row)) * E + cp * 8,
               (u16*)(SM + buf * 8192 + (i * 32 + w * 8) * 128));
    }
  };
  auto stageV = [&](int buf, int kb) {
#pragma unroll
    for (int i = 0; i < 2; ++i) {
      const int row = i * 32 + w * 8 + srl;
      const int cp = sc ^ (row & 7);
      gl_lds16(Vp + (size_t)row * S + kb + cp * 8,
               (u16*)(SM + 16384 + buf * 8192 + (i * 32 + w * 8) * 128));
    }
  };

  stageK(0, 0); stageV(0, 0);
  for (int t = 0; t < NT; ++t) {
    const int cur = t & 1;
    __syncthreads();                           // buf[cur] ready; prior reads drained
    if (t + 1 < NT) { stageK(cur ^ 1, (t + 1) * 64); stageV(cur ^ 1, (t + 1) * 64); }
    const char* Kc = SM + cur * 8192;
    const char* Vc = SM + 16384 + cur * 8192;

    // swapped QK^T: sfr[qh][nf], lane holds S[k'][q = qh*16 + lr]; staged-row
    // permute makes lane-local quads contiguous: k of sfr[nf][r]
    // = (nf>>1)*32 + lg*8 + (nf&1)*4 + r
    f32x4 sfr[2][4];
    __builtin_amdgcn_s_setprio(1);
#pragma unroll
    for (int nf = 0; nf < 4; ++nf) {
      bf16x8 k0 = *(const bf16x8*)(Kc + fofs0[nf]);
      bf16x8 k1 = *(const bf16x8*)(Kc + fofs1[nf]);
#pragma unroll
      for (int qh = 0; qh < 2; ++qh) {
        f32x4 z = f32x4{0.f, 0.f, 0.f, 0.f};
        z = __builtin_amdgcn_mfma_f32_16x16x32_bf16(k0, qa[qh][0], z, 0, 0, 0);
        sfr[qh][nf] = __builtin_amdgcn_mfma_f32_16x16x32_bf16(k1, qa[qh][1], z, 0, 0, 0);
      }
    }
    __builtin_amdgcn_s_setprio(0);

    // P = exp2(s) packed straight into MFMA A-frags (no LDS):
    // pa0[qh] = k-window 0..31 (nf0 elems 0-3, nf1 elems 4-7); pa1 = 32..63
    bf16x8 pa0[2], pa1[2];
#pragma unroll
    for (int qh = 0; qh < 2; ++qh)
#pragma unroll
      for (int r = 0; r < 4; ++r) {
        pa0[qh][r]     = (__bf16)EXP2(sfr[qh][0][r]);
        pa0[qh][4 + r] = (__bf16)EXP2(sfr[qh][1][r]);
        pa1[qh][r]     = (__bf16)EXP2(sfr[qh][2][r]);
        pa1[qh][4 + r] = (__bf16)EXP2(sfr[qh][3][r]);
      }

    // denominators via ones-MFMA (sums all 32 k-slots per window)
#pragma unroll
    for (int qh = 0; qh < 2; ++qh) {
      sum_acc[qh] = __builtin_amdgcn_mfma_f32_16x16x32_bf16(pa0[qh], ones, sum_acc[qh], 0, 0, 0);
      sum_acc[qh] = __builtin_amdgcn_mfma_f32_16x16x32_bf16(pa1[qh], ones, sum_acc[qh], 0, 0, 0);
    }

    // PV: V b128 frags (conflict-free, same fofs), each feeds both qh halves
    __builtin_amdgcn_s_setprio(1);
#pragma unroll
    for (int nf = 0; nf < 4; ++nf) {
      bf16x8 vb0 = *(const bf16x8*)(Vc + fofs0[nf]);
      bf16x8 vb1 = *(const bf16x8*)(Vc + fofs1[nf]);
#pragma unroll
      for (int qh = 0; qh < 2; ++qh) {
        o_acc[qh][nf] = __builtin_amdgcn_mfma_f32_16x16x32_bf16(pa0[qh], vb0, o_acc[qh][nf], 0, 0, 0);
        o_acc[qh][nf] = __builtin_amdgcn_mfma_f32_16x16x32_bf16(pa1[qh], vb1, o_acc[qh][nf], 0, 0, 0);
      }
    }
    __builtin_amdgcn_s_setprio(0);
  }

#pragma unroll
  for (int qh = 0; qh < 2; ++qh)
#pragma unroll
    for (int r = 0; r < 4; ++r) {
      const float inv = 1.0f / sum_acc[qh][r];
      const size_t row = (size_t)b * S + qbase + qh * 16 + lg * 4 + r;
#pragma unroll
      for (int nf = 0; nf < 4; ++nf)
        Ao[row * E + h * 64 + nf * 16 + lr] = f2bf(o_acc[qh][nf][r] * inv);
    }
}

// ---------------- launch ----------------
extern "C" void kernel_launch(void* const* d_in, const int* in_sizes, int n_in,
                              void* d_out, int out_size, void* d_ws, size_t ws_size,
                              hipStream_t stream) {
  const float* q  = (const float*)d_in[0];
  const float* k  = (const float*)d_in[1];
  const float* v  = (const float*)d_in[2];
  const float* Wq = (const float*)d_in[3];
  const float* bq = (const float*)d_in[4];
  const float* Wk = (const float*)d_in[5];
  const float* bk = (const float*)d_in[6];
  const float* Wv = (const float*)d_in[7];
  const float* bv = (const float*)d_in[8];
  const float* Wo = (const float*)d_in[9];
  const float* bo = (const float*)d_in[10];
  float* out = (float*)d_out;

  char* ws = (char*)d_ws;
  u16* attnb = (u16*)(ws);                     // 8MB (attn output, bf16)
  u16* wqb = (u16*)(ws + (24u << 20));         // 1M elems, 2MB each
  u16* wkb = (u16*)(ws + (26u << 20));
  u16* wvb = (u16*)(ws + (28u << 20));
  u16* wob = (u16*)(ws + (30u << 20));
  u16* qhp = (u16*)(ws + (32u << 20));         // 8MB each
  u16* khp = (u16*)(ws + (40u << 20));
  u16* vtp = (u16*)(ws + (48u << 20));         // V^T [b,h,d,s]

  cast_kernel<<<dim3(4096), dim3(256), 0, stream>>>(Wq, Wk, Wv, Wo, wqb, wkb, wvb, wob);
  proj_kernel<<<dim3(32, 8, 3), dim3(256), 0, stream>>>(q, k, v, wqb, wkb, wvb,
                                                        bq, bk, bv, qhp, khp, vtp);
  attn_kernel<<<dim3(32, 16), dim3(256), 0, stream>>>(qhp, khp, vtp, attnb);
  outproj_kernel<<<dim3(64, 8), dim3(256), 0, stream>>>(attnb, wob, bo, out);
}

// Round 19
// 103.993 us; speedup vs baseline: 1.8688x; 1.0024x over previous
//
#include <hip/hip_runtime.h>

// B=2, S=2048, E=1024, HEADS=16, HEAD_SIZE=64
// out = softmax((q Wq^T + bq)(k Wk^T + bk)^T / 32) (v Wv^T + bv) Wo^T + bo

typedef unsigned short u16;
typedef __bf16 bf16x8 __attribute__((ext_vector_type(8)));
typedef float f32x4 __attribute__((ext_vector_type(4)));
typedef u16 u16x4 __attribute__((ext_vector_type(4)));
typedef u16 u16x8 __attribute__((ext_vector_type(8)));

typedef __attribute__((address_space(1))) const unsigned int as1_cu32;
typedef __attribute__((address_space(3))) unsigned int as3_u32;

#if __has_builtin(__builtin_amdgcn_exp2f)
#define EXP2(x) __builtin_amdgcn_exp2f(x)   // raw v_exp_f32 (inputs are normal-range)
#else
#define EXP2(x) exp2f(x)
#endif

__device__ __forceinline__ u16 f2bf(float f) {
  unsigned u = __builtin_bit_cast(unsigned, f);
  u += 0x7fffu + ((u >> 16) & 1u);   // RTNE
  return (u16)(u >> 16);
}

__device__ __forceinline__ u16 bfc(float f) {   // RTNE via v_cvt (same bits as f2bf)
  return __builtin_bit_cast(u16, (__bf16)f);
}

__device__ __forceinline__ void gl_lds16(const u16* g, u16* l) {
  // async global->LDS, 16B/lane; LDS dest = wave-uniform base + lane*16
  __builtin_amdgcn_global_load_lds((as1_cu32*)g, (as3_u32*)l, 16, 0, 0);
}

// GEMM tile layout (bank-conflict-free): logical [R rows][32 k] bf16 packed as
// [R/2 LDS rows][128B]; LDS row j = global rows {2j, 2j+1}, 8 x 16B chunks,
// phys_chunk = ((grow&1)*4 + kchunk) ^ (j&7).  Frag/stage access = 2-way max.
__device__ __forceinline__ int tofs(int grow, int kchunk) {
  const int j = grow >> 1;
  return j * 128 + ((((grow & 1) * 4 + kchunk) ^ (j & 7)) << 4);
}

// ---------------- fp32 -> bf16 cast (4 weight matrices only) ----------------
__global__ void cast_kernel(const float* __restrict__ wq, const float* __restrict__ wk,
                            const float* __restrict__ wv, const float* __restrict__ wo,
                            u16* __restrict__ wqb, u16* __restrict__ wkb,
                            u16* __restrict__ wvb, u16* __restrict__ wob) {
  unsigned t = blockIdx.x * 256u + threadIdx.x;  // 1M float4 = 4 x 256K
  unsigned which = t >> 18, off = t & 262143u;
  const float* src = which == 0 ? wq : (which == 1 ? wk : (which == 2 ? wv : wo));
  u16* dst = which == 0 ? wqb : (which == 1 ? wkb : (which == 2 ? wvb : wob));
  float4 f = ((const float4*)src)[off];
  u16x4 o;
  o[0] = f2bf(f.x); o[1] = f2bf(f.y); o[2] = f2bf(f.z); o[3] = f2bf(f.w);
  ((u16x4*)dst)[off] = o;
}

// ---------------- NT GEMM: C = scale*(A B^T + bias) ----------------
// BM x 128 tile, BK=32, 4 waves, 16x16x32 MFMA, dbuf LDS (swizzled layout).
// AREG: A source is fp32; staged via regs (dwordx4 loads issued early, RTNE
// cvt to bf16, ds_write_b128 late) into the swizzled layout.
// MODE: 0 = bf16 row-major out, 1 = f32 row-major out,
// MODE 2 = bf16 V^T out [b,h,d,s] via LDS transpose + coalesced 16B stores.
template <int MODE, int BM, bool AREG>
__device__ __forceinline__ void gemm_body(const void* __restrict__ Av, const u16* __restrict__ B,
                                          const float* __restrict__ bias, void* __restrict__ Cv,
                                          float scale, char* SMraw) {
  constexpr int MI = BM / 32;                              // M frags per wave
  constexpr int ABUF = BM * 64;                            // bytes per A buffer (bf16)
  char* ASM = SMraw;
  char* BSM = SMraw + 2 * ABUF;                            // [2][8KB]
  constexpr int N = 1024, NK = 32;
  const int m0 = blockIdx.x * BM;
  const int n0 = blockIdx.y * 128;
  const int tid = threadIdx.x;
  const int w = tid >> 6, l = tid & 63;
  const int lr = l & 15, lg = l >> 4;
  const int wm = (w >> 1) * (BM / 2), wn = (w & 1) * 64;

  // DMA staging: linear 1KB per wave-issue; source pre-swizzled (inverse map)
  const int jof = l >> 3, pc = l & 7;
  auto stage_dma = [&](char* dstbase, const u16* Op, int o0, int r0, int kt) {
    const int j = (r0 >> 1) + jof;
    const int lc = pc ^ (j & 7);
    const int g = 2 * j + (lc >> 2);
    gl_lds16(Op + (size_t)(o0 + g) * 1024 + kt * 32 + (lc & 3) * 8,
             (u16*)(dstbase + (r0 >> 1) * 128));
  };
  auto stageB = [&](int buf, int kt) {
#pragma unroll
    for (int i = 0; i < 2; ++i)
      stage_dma(BSM + buf * 8192, B, n0, i * 64 + w * 16, kt);
  };
  auto stageA_dma = [&](int buf, int kt) {   // bf16 A source (outproj)
#pragma unroll
    for (int i = 0; i < BM / 64; ++i)
      stage_dma(ASM + buf * ABUF, (const u16*)Av, m0, i * 64 + w * 16, kt);
  };
  // fp32 A: issue loads early...
  f32x4 ar[BM / 64][2];
  auto stageA_load = [&](int kt) {
    const float* A = (const float*)Av;
#pragma unroll
    for (int i = 0; i < BM / 64; ++i) {
      const float* src = A + (size_t)(m0 + i * 64 + w * 16 + (l >> 2)) * 1024 + kt * 32 + (l & 3) * 8;
      ar[i][0] = *(const f32x4*)src;
      ar[i][1] = *(const f32x4*)(src + 4);
    }
  };
  // ...convert + write late into the swizzled layout
  auto stageA_write = [&](int buf) {
#pragma unroll
    for (int i = 0; i < BM / 64; ++i) {
      u16x8 v;
#pragma unroll
      for (int j = 0; j < 4; ++j) { v[j] = bfc(ar[i][0][j]); v[4 + j] = bfc(ar[i][1][j]); }
      *(u16x8*)(ASM + buf * ABUF + tofs(i * 64 + w * 16 + (l >> 2), l & 3)) = v;
    }
  };

  // hoisted frag byte-offsets (kchunk = lg)
  int afo[MI], bfo[4];
#pragma unroll
  for (int i = 0; i < MI; ++i) afo[i] = tofs(wm + i * 16 + lr, lg);
#pragma unroll
  for (int i = 0; i < 4; ++i) bfo[i] = tofs(wn + i * 16 + lr, lg);

  f32x4 acc[MI][4];
#pragma unroll
  for (int i = 0; i < MI; ++i)
#pragma unroll
    for (int j = 0; j < 4; ++j) acc[i][j] = f32x4{0.f, 0.f, 0.f, 0.f};

  if constexpr (AREG) { stageA_load(0); stageA_write(0); }
  else                stageA_dma(0, 0);
  stageB(0, 0);

  for (int kt = 0; kt < NK; ++kt) {
    const int buf = kt & 1;
    __syncthreads();
    if (kt + 1 < NK) {
      if constexpr (AREG) stageA_load(kt + 1);   // issue early; HBM/L2 latency
      else                stageA_dma(buf ^ 1, kt + 1);
      stageB(buf ^ 1, kt + 1);
    }
    bf16x8 af[MI], bfr[4];
#pragma unroll
    for (int i = 0; i < MI; ++i)
      af[i] = *(const bf16x8*)(ASM + buf * ABUF + afo[i]);
#pragma unroll
    for (int i = 0; i < 4; ++i)
      bfr[i] = *(const bf16x8*)(BSM + buf * 8192 + bfo[i]);
#pragma unroll
    for (int mi = 0; mi < MI; ++mi)
#pragma unroll
      for (int ni = 0; ni < 4; ++ni)
        acc[mi][ni] = __builtin_amdgcn_mfma_f32_16x16x32_bf16(af[mi], bfr[ni], acc[mi][ni], 0, 0, 0);
    if (kt + 1 < NK) {
      if constexpr (AREG) stageA_write(buf ^ 1);  // write late, under MFMA shadow
    }
  }

  float bv[4];
#pragma unroll
  for (int ni = 0; ni < 4; ++ni) bv[ni] = bias[n0 + wn + ni * 16 + lr];

  if constexpr (MODE != 2) {
#pragma unroll
    for (int mi = 0; mi < MI; ++mi)
#pragma unroll
      for (int ni = 0; ni < 4; ++ni)
#pragma unroll
        for (int r = 0; r < 4; ++r) {
          const int row = m0 + wm + mi * 16 + lg * 4 + r;
          const int col = n0 + wn + ni * 16 + lr;
          float vv = (acc[mi][ni][r] + bv[ni]) * scale;
          if constexpr (MODE == 1) ((float*)Cv)[(size_t)row * N + col] = vv;
          else                     ((u16*)Cv)[(size_t)row * N + col] = f2bf(vv);
        }
  } else {
    // V^T epilogue: transpose 64x64 wave quadrant through LDS (reuse arena),
    // then coalesced 16B stores (8 lanes cover one contiguous 128B d-row).
    __syncthreads();                      // all waves done reading As/Bs
    char* wb = SMraw + w * 8192;          // per-wave [64 d][64 s] bf16, 128B rows
#pragma unroll
    for (int mi = 0; mi < MI; ++mi)
#pragma unroll
      for (int ni = 0; ni < 4; ++ni)
#pragma unroll
        for (int r = 0; r < 4; ++r) {
          const int dl = ni * 16 + lr;
          const int sl = mi * 16 + lg * 4 + r;
          const int phys = (sl >> 3) ^ (lr & 7);   // chunk-XOR keyed by d&7
          *(u16*)(wb + dl * 128 + (phys << 4) + (sl & 7) * 2) =
              f2bf(acc[mi][ni][r] + bv[ni]);
        }
    // intra-wave RAW through LDS; read rows [d][s], store 16B chunks
    const int sc2 = l & 7, srl2 = l >> 3;
    const int rowg = m0 + wm;             // s base (same b for whole quadrant)
#pragma unroll
    for (int i = 0; i < 8; ++i) {
      const int dl = i * 8 + srl2;
      const int phys = sc2 ^ srl2;        // dl&7 == srl2
      u16x8 vrow = *(u16x8*)(wb + dl * 128 + (phys << 4));
      const int colg = n0 + wn + dl;
      u16* dst = (u16*)Cv + ((size_t)((rowg >> 11) << 10) + colg) * 2048 +
                 (rowg & 2047) + sc2 * 8;
      *(u16x8*)dst = vrow;
    }
  }
}

__global__ __launch_bounds__(256, 3)
void proj_kernel(const float* __restrict__ q, const float* __restrict__ k, const float* __restrict__ v,
                 const u16* __restrict__ wqb, const u16* __restrict__ wkb, const u16* __restrict__ wvb,
                 const float* __restrict__ bq, const float* __restrict__ bk, const float* __restrict__ bvv,
                 u16* __restrict__ qh, u16* __restrict__ kh, u16* __restrict__ vt) {
  __shared__ __align__(16) char SM[32768];   // A bf16 16KB + B 16KB
  // Q gets scale log2(e)/32 so attention scores feed exp2 directly
  if (blockIdx.z == 0)      gemm_body<0, 128, true>(q, wqb, bq, qh, 1.44269504089f / 32.f, SM);
  else if (blockIdx.z == 1) gemm_body<0, 128, true>(k, wkb, bk, kh, 1.0f, SM);
  else                      gemm_body<2, 128, true>(v, wvb, bvv, vt, 1.0f, SM);
}

__global__ __launch_bounds__(256, 2)
void outproj_kernel(const u16* __restrict__ attnb, const u16* __restrict__ wob,
                    const float* __restrict__ bo, float* __restrict__ out) {
  __shared__ __align__(16) char SM[24576];   // As 8KB + Bs 16KB
  gemm_body<1, 64, false>(attnb, wob, bo, out, 1.0f, SM);
}

// ---------------- flash attention: in-register P (swapped QK + row-permuted K)
// grid (32 bh, 16 qt). 4 waves, wave w owns 32 q-rows (2 qh halves).
// QK computed as mfma(K, Q) -> C col = lane = q: each lane's 16 scores are all
// for ONE q-row = the PV A-frag ownership. K-tile staged with row bit-permute
// k = [b5 b3 b2 b4 b1 b0] so lane-local k-quads become the NATURAL contiguous
// mapping kappa(lg,j) = win*32 + lg*8 + j -> V's conflict-free b128 reads match
// unchanged. P = exp2(sfr) built directly into MFMA A-frags; NO P LDS traffic.
__global__ __launch_bounds__(256, 2)
void attn_kernel(const u16* __restrict__ Q, const u16* __restrict__ Kh,
                 const u16* __restrict__ Vt, u16* __restrict__ Ao) {
  constexpr int E = 1024, S = 2048, NT = S / 64;
  const int bh = blockIdx.x, qt = blockIdx.y;
  const int b = bh >> 4, h = bh & 15;
  const int tid = threadIdx.x, w = tid >> 6, l = tid & 63;
  const int lr = l & 15, lg = l >> 4;

  // LDS arena: [0,16K) Ks[2][64][64]  [16K,32K) Vs[2][64][64]
  __shared__ __align__(16) char SM[32768];

  const u16* Qp = Q + (size_t)b * S * E + (size_t)h * 64;
  const u16* Kp = Kh + (size_t)b * S * E + (size_t)h * 64;
  const u16* Vp = Vt + (size_t)bh * 64 * S;   // [d][s]

  const int qbase = qt * 128 + w * 32;
  bf16x8 qa[2][2];
#pragma unroll
  for (int qh = 0; qh < 2; ++qh)
#pragma unroll
    for (int hh = 0; hh < 2; ++hh)
      qa[qh][hh] = *(const bf16x8*)(Qp + (size_t)(qbase + qh * 16 + lr) * E + hh * 32 + lg * 8);

  bf16x8 ones;
#pragma unroll
  for (int j = 0; j < 8; ++j) ones[j] = (__bf16)1.0f;

  f32x4 o_acc[2][4];      // [qh][nf]  : O[q=lg*4+r][d=nf*16+lr]
#pragma unroll
  for (int qh = 0; qh < 2; ++qh)
#pragma unroll
    for (int nf = 0; nf < 4; ++nf) o_acc[qh][nf] = f32x4{0.f, 0.f, 0.f, 0.f};
  f32x4 sum_acc[2] = {f32x4{0.f, 0.f, 0.f, 0.f}, f32x4{0.f, 0.f, 0.f, 0.f}};

  // ---- hoisted loop-invariant LDS byte offsets ----
  const int swz8 = lr & 7;
  int fofs0[4], fofs1[4];            // K/V fragment offsets (same tile geometry)
#pragma unroll
  for (int nf = 0; nf < 4; ++nf) {
    fofs0[nf] = (((nf * 16 + lr) * 64) + (lg ^ swz8) * 8) * 2;
    fofs1[nf] = (((nf * 16 + lr) * 64) + ((4 + lg) ^ swz8) * 8) * 2;
  }

  const int sc = l & 7, srl = l >> 3;
  // K staged-row bit-permute: staged row r' holds global k = [b5 b3 b2 b4 b1 b0]
  auto kperm = [](int r) {
    return (r & 35) | ((r & 12) << 1) | ((r & 16) >> 2);
  };
  auto stageK = [&](int buf, int kb) {
#pragma unroll
    for (int i = 0; i < 2; ++i) {
      const int row = i * 32 + w * 8 + srl;
      const int cp = sc ^ (row & 7);
      gl_lds16(Kp + (size_t)(kb + kperm(row)) * E + cp * 8,
               (u16*)(SM + buf * 8192 + (i * 32 + w * 8) * 128));
    }
  };
  auto stageV = [&](int buf, int kb) {
#pragma unroll
    for (int i = 0; i < 2; ++i) {
      const int row = i * 32 + w * 8 + srl;
      const int cp = sc ^ (row & 7);
      gl_lds16(Vp + (size_t)row * S + kb + cp * 8,
               (u16*)(SM + 16384 + buf * 8192 + (i * 32 + w * 8) * 128));
    }
  };

  stageK(0, 0); stageV(0, 0);
  for (int t = 0; t < NT; ++t) {
    const int cur = t & 1;
    __syncthreads();                           // buf[cur] ready; prior reads drained
    if (t + 1 < NT) { stageK(cur ^ 1, (t + 1) * 64); stageV(cur ^ 1, (t + 1) * 64); }
    const char* Kc = SM + cur * 8192;
    const char* Vc = SM + 16384 + cur * 8192;

    // swapped QK^T: sfr[qh][nf], lane holds S[k'][q = qh*16 + lr]; staged-row
    // permute makes lane-local quads contiguous: k of sfr[nf][r]
    // = (nf>>1)*32 + lg*8 + (nf&1)*4 + r
    f32x4 sfr[2][4];
    __builtin_amdgcn_s_setprio(1);
#pragma unroll
    for (int nf = 0; nf < 4; ++nf) {
      bf16x8 k0 = *(const bf16x8*)(Kc + fofs0[nf]);
      bf16x8 k1 = *(const bf16x8*)(Kc + fofs1[nf]);
#pragma unroll
      for (int qh = 0; qh < 2; ++qh) {
        f32x4 z = f32x4{0.f, 0.f, 0.f, 0.f};
        z = __builtin_amdgcn_mfma_f32_16x16x32_bf16(k0, qa[qh][0], z, 0, 0, 0);
        sfr[qh][nf] = __builtin_amdgcn_mfma_f32_16x16x32_bf16(k1, qa[qh][1], z, 0, 0, 0);
      }
    }
    __builtin_amdgcn_s_setprio(0);

    // P = exp2(s) packed straight into MFMA A-frags (no LDS):
    // pa0[qh] = k-window 0..31 (nf0 elems 0-3, nf1 elems 4-7); pa1 = 32..63
    bf16x8 pa0[2], pa1[2];
#pragma unroll
    for (int qh = 0; qh < 2; ++qh)
#pragma unroll
      for (int r = 0; r < 4; ++r) {
        pa0[qh][r]     = (__bf16)EXP2(sfr[qh][0][r]);
        pa0[qh][4 + r] = (__bf16)EXP2(sfr[qh][1][r]);
        pa1[qh][r]     = (__bf16)EXP2(sfr[qh][2][r]);
        pa1[qh][4 + r] = (__bf16)EXP2(sfr[qh][3][r]);
      }

    // denominators via ones-MFMA (sums all 32 k-slots per window)
#pragma unroll
    for (int qh = 0; qh < 2; ++qh) {
      sum_acc[qh] = __builtin_amdgcn_mfma_f32_16x16x32_bf16(pa0[qh], ones, sum_acc[qh], 0, 0, 0);
      sum_acc[qh] = __builtin_amdgcn_mfma_f32_16x16x32_bf16(pa1[qh], ones, sum_acc[qh], 0, 0, 0);
    }

    // PV: V b128 frags (conflict-free, same fofs), each feeds both qh halves
    __builtin_amdgcn_s_setprio(1);
#pragma unroll
    for (int nf = 0; nf < 4; ++nf) {
      bf16x8 vb0 = *(const bf16x8*)(Vc + fofs0[nf]);
      bf16x8 vb1 = *(const bf16x8*)(Vc + fofs1[nf]);
#pragma unroll
      for (int qh = 0; qh < 2; ++qh) {
        o_acc[qh][nf] = __builtin_amdgcn_mfma_f32_16x16x32_bf16(pa0[qh], vb0, o_acc[qh][nf], 0, 0, 0);
        o_acc[qh][nf] = __builtin_amdgcn_mfma_f32_16x16x32_bf16(pa1[qh], vb1, o_acc[qh][nf], 0, 0, 0);
      }
    }
    __builtin_amdgcn_s_setprio(0);
  }

#pragma unroll
  for (int qh = 0; qh < 2; ++qh)
#pragma unroll
    for (int r = 0; r < 4; ++r) {
      const float inv = 1.0f / sum_acc[qh][r];
      const size_t row = (size_t)b * S + qbase + qh * 16 + lg * 4 + r;
#pragma unroll
      for (int nf = 0; nf < 4; ++nf)
        Ao[row * E + h * 64 + nf * 16 + lr] = f2bf(o_acc[qh][nf][r] * inv);
    }
}

// ---------------- launch ----------------
extern "C" void kernel_launch(void* const* d_in, const int* in_sizes, int n_in,
                              void* d_out, int out_size, void* d_ws, size_t ws_size,
                              hipStream_t stream) {
  const float* q  = (const float*)d_in[0];
  const float* k  = (const float*)d_in[1];
  const float* v  = (const float*)d_in[2];
  const float* Wq = (const float*)d_in[3];
  const float* bq = (const float*)d_in[4];
  const float* Wk = (const float*)d_in[5];
  const float* bk = (const float*)d_in[6];
  const float* Wv = (const float*)d_in[7];
  const float* bv = (const float*)d_in[8];
  const float* Wo = (const float*)d_in[9];
  const float* bo = (const float*)d_in[10];
  float* out = (float*)d_out;

  char* ws = (char*)d_ws;
  u16* attnb = (u16*)(ws);                     // 8MB (attn output, bf16)
  u16* wqb = (u16*)(ws + (24u << 20));         // 1M elems, 2MB each
  u16* wkb = (u16*)(ws + (26u << 20));
  u16* wvb = (u16*)(ws + (28u << 20));
  u16* wob = (u16*)(ws + (30u << 20));
  u16* qhp = (u16*)(ws + (32u << 20));         // 8MB each
  u16* khp = (u16*)(ws + (40u << 20));
  u16* vtp = (u16*)(ws + (48u << 20));         // V^T [b,h,d,s]

  cast_kernel<<<dim3(4096), dim3(256), 0, stream>>>(Wq, Wk, Wv, Wo, wqb, wkb, wvb, wob);
  proj_kernel<<<dim3(32, 8, 3), dim3(256), 0, stream>>>(q, k, v, wqb, wkb, wvb,
                                                        bq, bk, bv, qhp, khp, vtp);
  attn_kernel<<<dim3(32, 16), dim3(256), 0, stream>>>(qhp, khp, vtp, attnb);
  outproj_kernel<<<dim3(64, 8), dim3(256), 0, stream>>>(attnb, wob, bo, out);
}